// Round 7
// baseline (1499.446 us; speedup 1.0000x reference)
//
#include <hip/hip_runtime.h>

typedef unsigned int u32;
typedef unsigned long long u64;
typedef unsigned short u16;

#define DEVFN static __device__ __forceinline__

constexpr int NPTS = 16384;  // points per batch
constexpr int NC = 512;      // centers per batch
// B=8, K=32, FEAT=256

typedef __attribute__((ext_vector_type(8))) short bf16x8;
typedef __attribute__((ext_vector_type(4))) float f32x4;

#define MFMA16(a, b, c) __builtin_amdgcn_mfma_f32_16x16x32_bf16(a, b, c, 0, 0, 0)

DEVFN u16 bf16rne(float f) {
  u32 b = __float_as_uint(f);
  u32 r = (b + 0x7FFFu + ((b >> 16) & 1u)) >> 16;
  return (u16)r;
}

DEVFN u64 shflx64(u64 v, int m) {
  u32 lo = __shfl_xor((u32)v, m, 64);
  u32 hi = __shfl_xor((u32)(v >> 32), m, 64);
  return ((u64)hi << 32) | lo;
}
DEVFN u64 shfl64(u64 v, int src) {
  u32 lo = __shfl((u32)v, src, 64);
  u32 hi = __shfl((u32)(v >> 32), src, 64);
  return ((u64)hi << 32) | lo;
}

DEVFN void csw(u64& a, u64& b) {
  u64 lo = a < b ? a : b;
  u64 hi = a < b ? b : a;
  a = lo; b = hi;
}

DEVFN u32 spread3(u32 v) {  // 4 bits -> bits 0,3,6,9
  return (v & 1u) | ((v & 2u) << 2) | ((v & 4u) << 4) | ((v & 8u) << 6);
}

// ---------------------------------------------------------------------------
// FPS v6: v5 structure (Morton clusters of 64 pts, 4 thr/cluster, 1 barrier
// per iter) + two fixes for the serial critical path:
//  (a) px/py/pz/mdkey pinned into registers via empty asm ("+v") -- blocks
//      the compiler's load-rematerialization that kept VGPR=64 and re-read
//      point data from L2 on every active iteration. waves_per_eu(4,4)
//      provides the 128-reg budget the pinned state needs.
//  (b) winner coords broadcast via LDS payload {key,x,y,z} extracted from
//      the owning thread's registers -- removes the dependent uniform
//      global load (~300-900 cyc) from the per-iteration chain.
// Exactness unchanged: key = md_bits||(16383-oidx); u64 max == numpy argmax
// (max md, tie -> lowest original index); pruning skips only provably
// no-op updates (monotone rounding lower bound).
// ---------------------------------------------------------------------------
__global__ __attribute__((amdgpu_flat_work_group_size(1024, 1024)))
__attribute__((amdgpu_waves_per_eu(4, 4))) void fps_kernel(const float* __restrict__ xyz,
                                                           float* __restrict__ centers) {
  const int b = blockIdx.x;
  const int t = threadIdx.x;
  const int lane = t & 63;
  const int w = t >> 6;
  const float* xb = xyz + (size_t)b * NPTS * 3;

  __shared__ char smem[86016];               // padded: force 1 block/CU
  u32* hist = (u32*)smem;                    // [0, 8K)   2048 u32
  u16* soidx = (u16*)(smem + 8192);          // [8K, 40K) 16384 u16
  u32* skb = (u32*)(smem + 40960);           // 2 x 16 x 10 u32 payload rows
  float* redB = (float*)(smem + 42240);      // 104 f32
  u32* redW = (u32*)(smem + 42688);          // 16 u32

  const u32 inf10 = __float_as_uint(1e10f);

  // ---- setup: global bbox + morton codes ----
  u32 mcode[16];
  {
    float ox[16], oy[16], oz[16];
    float lx = 1e30f, ly = 1e30f, lz = 1e30f;
    float hx = -1e30f, hy = -1e30f, hz = -1e30f;
#pragma unroll
    for (int j = 0; j < 16; ++j) {
      int p = t + j * 1024;
      ox[j] = xb[p * 3 + 0];
      oy[j] = xb[p * 3 + 1];
      oz[j] = xb[p * 3 + 2];
      lx = fminf(lx, ox[j]); hx = fmaxf(hx, ox[j]);
      ly = fminf(ly, oy[j]); hy = fmaxf(hy, oy[j]);
      lz = fminf(lz, oz[j]); hz = fmaxf(hz, oz[j]);
    }
#pragma unroll
    for (int s = 32; s; s >>= 1) {
      lx = fminf(lx, __shfl_xor(lx, s, 64)); hx = fmaxf(hx, __shfl_xor(hx, s, 64));
      ly = fminf(ly, __shfl_xor(ly, s, 64)); hy = fmaxf(hy, __shfl_xor(hy, s, 64));
      lz = fminf(lz, __shfl_xor(lz, s, 64)); hz = fmaxf(hz, __shfl_xor(hz, s, 64));
    }
    if (lane == 0) {
      redB[w * 6 + 0] = lx; redB[w * 6 + 1] = hx;
      redB[w * 6 + 2] = ly; redB[w * 6 + 3] = hy;
      redB[w * 6 + 4] = lz; redB[w * 6 + 5] = hz;
    }
    hist[t] = 0; hist[t + 1024] = 0;
    __syncthreads();
    if (t == 0) {
      float a0 = redB[0], a1 = redB[1], a2 = redB[2], a3 = redB[3], a4 = redB[4], a5 = redB[5];
      for (int q = 1; q < 16; ++q) {
        a0 = fminf(a0, redB[q * 6 + 0]); a1 = fmaxf(a1, redB[q * 6 + 1]);
        a2 = fminf(a2, redB[q * 6 + 2]); a3 = fmaxf(a3, redB[q * 6 + 3]);
        a4 = fminf(a4, redB[q * 6 + 4]); a5 = fmaxf(a5, redB[q * 6 + 5]);
      }
      redB[96] = a0; redB[97] = a1; redB[98] = a2;
      redB[99] = a3; redB[100] = a4; redB[101] = a5;
    }
    __syncthreads();
    const float glx = redB[96], ghx = redB[97];
    const float gly = redB[98], ghy = redB[99];
    const float glz = redB[100], ghz = redB[101];
    const float sx = 15.999f / fmaxf(ghx - glx, 1e-9f);
    const float sy = 15.999f / fmaxf(ghy - gly, 1e-9f);
    const float sz = 7.999f / fmaxf(ghz - glz, 1e-9f);
#pragma unroll
    for (int j = 0; j < 16; ++j) {
      int ix = min(15, max(0, (int)((ox[j] - glx) * sx)));
      int iy = min(15, max(0, (int)((oy[j] - gly) * sy)));
      int iz = min(7, max(0, (int)((oz[j] - glz) * sz)));
      mcode[j] = spread3((u32)ix) | (spread3((u32)iy) << 1) | (spread3((u32)iz) << 2);
    }
  }
  // ---- histogram (2048 bins) ----
#pragma unroll
  for (int j = 0; j < 16; ++j) atomicAdd(&hist[mcode[j]], 1u);
  __syncthreads();
  // ---- exclusive scan over 2048 bins ----
  {
    u32 h0 = hist[t * 2 + 0], h1 = hist[t * 2 + 1];
    u32 s = h0 + h1;
    u32 incl = s;
#pragma unroll
    for (int d = 1; d < 64; d <<= 1) {
      u32 n = __shfl_up(incl, d, 64);
      if (lane >= d) incl += n;
    }
    if (lane == 63) redW[w] = incl;
    __syncthreads();
    if (t == 0) {
      u32 run = 0;
      for (int q = 0; q < 16; ++q) { u32 tmp = redW[q]; redW[q] = run; run += tmp; }
    }
    __syncthreads();
    u32 exc = incl - s + redW[w];
    hist[t * 2 + 0] = exc;
    hist[t * 2 + 1] = exc + h0;
    __syncthreads();
  }
  // ---- scatter: sorted position -> original index ----
#pragma unroll
  for (int j = 0; j < 16; ++j) {
    u32 p = (u32)(t + j * 1024);
    u32 pos = atomicAdd(&hist[mcode[j]], 1u);
    soidx[pos] = (u16)p;
  }
  __syncthreads();
  // ---- gather: thread owns 16 consecutive sorted points of its cluster ----
  const u32 spbase = (u32)((t >> 2) * 64 + (t & 3) * 16);
  float px[16], py[16], pz[16];
  u64 mdkey[16];
#pragma unroll
  for (int j = 0; j < 16; ++j) {
    u32 oidx = (u32)soidx[spbase + j];
    px[j] = xb[oidx * 3 + 0];
    py[j] = xb[oidx * 3 + 1];
    pz[j] = xb[oidx * 3 + 2];
    mdkey[j] = ((u64)inf10 << 32) | (u64)(16383u - oidx);
  }
  // ---- cluster bbox in registers (2-step shuffle over the 4-lane group) ----
  float bxl = px[0], bxh = px[0], byl = py[0], byh = py[0], bzl = pz[0], bzh = pz[0];
#pragma unroll
  for (int j = 1; j < 16; ++j) {
    bxl = fminf(bxl, px[j]); bxh = fmaxf(bxh, px[j]);
    byl = fminf(byl, py[j]); byh = fmaxf(byh, py[j]);
    bzl = fminf(bzl, pz[j]); bzh = fmaxf(bzh, pz[j]);
  }
#pragma unroll
  for (int s = 1; s <= 2; s <<= 1) {
    bxl = fminf(bxl, __shfl_xor(bxl, s, 64)); bxh = fmaxf(bxh, __shfl_xor(bxh, s, 64));
    byl = fminf(byl, __shfl_xor(byl, s, 64)); byh = fmaxf(byh, __shfl_xor(byh, s, 64));
    bzl = fminf(bzl, __shfl_xor(bzl, s, 64)); bzh = fmaxf(bzh, __shfl_xor(bzh, s, 64));
  }
  // ---- PIN the hot state into registers: block load-rematerialization ----
#pragma unroll
  for (int j = 0; j < 16; ++j) {
    asm volatile("" : "+v"(px[j]), "+v"(py[j]), "+v"(pz[j]));
    u32 klo = (u32)mdkey[j], khi = (u32)(mdkey[j] >> 32);
    asm volatile("" : "+v"(klo), "+v"(khi));
    mdkey[j] = ((u64)khi << 32) | klo;
  }
  float cx = xb[0], cy = xb[1], cz = xb[2];
  if (t == 0) {
    centers[(b * NC) * 3 + 0] = cx;
    centers[(b * NC) * 3 + 1] = cy;
    centers[(b * NC) * 3 + 2] = cz;
  }
  u64 mdmkey = (u64)inf10 << 32;  // cluster-max key (group-uniform)

  // ---- main loop: 1 barrier per iteration ----
  for (int i = 1; i < NC; ++i) {
    float ax = fmaxf(0.f, fmaxf(__fsub_rn(bxl, cx), __fsub_rn(cx, bxh)));
    float ay = fmaxf(0.f, fmaxf(__fsub_rn(byl, cy), __fsub_rn(cy, byh)));
    float az = fmaxf(0.f, fmaxf(__fsub_rn(bzl, cz), __fsub_rn(cz, bzh)));
    float dlb = __fadd_rn(__fadd_rn(__fmul_rn(ax, ax), __fmul_rn(ay, ay)), __fmul_rn(az, az));
    if (dlb < __uint_as_float((u32)(mdmkey >> 32))) {  // group-uniform branch
      u64 lmax = 0ull;
#pragma unroll
      for (int j = 0; j < 16; ++j) {
        float dx = __fsub_rn(px[j], cx);
        float dy = __fsub_rn(py[j], cy);
        float dz = __fsub_rn(pz[j], cz);
        float d = __fadd_rn(__fadd_rn(__fmul_rn(dx, dx), __fmul_rn(dy, dy)), __fmul_rn(dz, dz));
        u64 nk = ((u64)__float_as_uint(d) << 32) | (mdkey[j] & 0xFFFFFFFFull);
        u64 k = nk < mdkey[j] ? nk : mdkey[j];  // md = min(md, d)
        mdkey[j] = k;
        lmax = k > lmax ? k : lmax;
      }
      u64 o1 = shflx64(lmax, 1); lmax = o1 > lmax ? o1 : lmax;
      u64 o2 = shflx64(lmax, 2); lmax = o2 > lmax ? o2 : lmax;
      mdmkey = lmax;
    }
    u64 wk = mdmkey;  // wave max over 16 clusters (groups uniform -> start at 4)
#pragma unroll
    for (int s = 4; s <= 32; s <<= 1) { u64 o = shflx64(wk, s); wk = o > wk ? o : wk; }
    // winning thread of this wave publishes {key, coords} from registers
    u32* row = skb + ((i & 1) * 16 + w) * 10;
    if (mdmkey == wk) {  // only the wave-winning cluster's 4 threads
      u32 fx = 0, fy = 0, fz = 0;
      bool found = false;
#pragma unroll
      for (int j = 0; j < 16; ++j) {
        if (mdkey[j] == wk) {
          fx = __float_as_uint(px[j]); fy = __float_as_uint(py[j]); fz = __float_as_uint(pz[j]);
          found = true;
        }
      }
      if (found) {  // exactly one thread in the wave
        row[0] = (u32)(wk >> 32); row[1] = (u32)wk;
        row[2] = fx; row[3] = fy; row[4] = fz;
      }
    }
    __syncthreads();
    const u32* rrow = skb + ((i & 1) * 16 + (lane & 15)) * 10;
    u64 gk = ((u64)rrow[0] << 32) | rrow[1];
    u32 widx = (u32)(lane & 15);
#pragma unroll
    for (int s = 1; s <= 8; s <<= 1) {
      u64 o = shflx64(gk, s);
      u32 ow = __shfl_xor(widx, s, 64);
      if (o > gk) { gk = o; widx = ow; }
    }
    widx = __builtin_amdgcn_readfirstlane(widx);
    const u32* wrow = skb + ((i & 1) * 16 + widx) * 10;
    cx = __uint_as_float(wrow[2]);
    cy = __uint_as_float(wrow[3]);
    cz = __uint_as_float(wrow[4]);
    if (t == 0) {
      centers[(b * NC + i) * 3 + 0] = cx;
      centers[(b * NC + i) * 3 + 1] = cy;
      centers[(b * NC + i) * 3 + 2] = cz;
    }
  }
}

// ---------------------------------------------------------------------------
// KNN: 8 waves/block, wave = one center. Exact top-32 set by (d, idx).
// ---------------------------------------------------------------------------
__global__ __launch_bounds__(512) void knn_kernel(const float* __restrict__ xyz,
                                                  const float* __restrict__ centers,
                                                  float* __restrict__ grouped) {
  __shared__ float spts[1024 * 3];
  __shared__ u64 cand[8][192];
  __shared__ int ccnt[8];
  const int t = threadIdx.x;
  const int lane = t & 63;
  const int w = t >> 6;
  const int cg = blockIdx.x * 8 + w;   // global center id
  const int b = cg >> 9;               // / 512
  const float* xb = xyz + (size_t)b * NPTS * 3;
  const float cx = centers[cg * 3 + 0];
  const float cy = centers[cg * 3 + 1];
  const float cz = centers[cg * 3 + 2];
  if (lane == 0) ccnt[w] = 0;

  // phase 1: per-lane min (packed (d,idx))
  u64 lmin = ~0ull;
  for (int ch = 0; ch < 16; ++ch) {
    __syncthreads();
    const float* src = xb + ch * 1024 * 3;
#pragma unroll
    for (int q = 0; q < 6; ++q) spts[q * 512 + t] = src[q * 512 + t];
    __syncthreads();
#pragma unroll
    for (int j = 0; j < 16; ++j) {
      int p = lane + j * 64;
      float dx = __fsub_rn(cx, spts[p * 3 + 0]);
      float dy = __fsub_rn(cy, spts[p * 3 + 1]);
      float dz = __fsub_rn(cz, spts[p * 3 + 2]);
      float d = __fadd_rn(__fadd_rn(__fmul_rn(dx, dx), __fmul_rn(dy, dy)), __fmul_rn(dz, dz));
      u64 kk = ((u64)__float_as_uint(d) << 32) | (u64)(u32)(ch * 1024 + p);
      lmin = kk < lmin ? kk : lmin;
    }
  }
  // bitonic sort (ascending) of 64 lane-minima; tau = 32nd smallest
  u64 v = lmin;
  for (int k = 2; k <= 64; k <<= 1)
    for (int j = k >> 1; j > 0; j >>= 1) {
      u64 o = shflx64(v, j);
      bool up = ((lane & k) == 0);
      bool lowr = ((lane & j) == 0);
      u64 mn = v < o ? v : o;
      u64 mx = v < o ? o : v;
      v = (lowr == up) ? mn : mx;
    }
  u64 tau = shfl64(v, 31);
  float tf = __uint_as_float((u32)(tau >> 32));

  // phase 2: collect candidates d <= tf  (guaranteed >= 32 of them)
  for (int ch = 0; ch < 16; ++ch) {
    __syncthreads();
    const float* src = xb + ch * 1024 * 3;
#pragma unroll
    for (int q = 0; q < 6; ++q) spts[q * 512 + t] = src[q * 512 + t];
    __syncthreads();
#pragma unroll
    for (int j = 0; j < 16; ++j) {
      int p = lane + j * 64;
      float dx = __fsub_rn(cx, spts[p * 3 + 0]);
      float dy = __fsub_rn(cy, spts[p * 3 + 1]);
      float dz = __fsub_rn(cz, spts[p * 3 + 2]);
      float d = __fadd_rn(__fadd_rn(__fmul_rn(dx, dx), __fmul_rn(dy, dy)), __fmul_rn(dz, dz));
      if (d <= tf) {
        int pos = atomicAdd(&ccnt[w], 1);
        if (pos < 192) cand[w][pos] = ((u64)__float_as_uint(d) << 32) | (u64)(u32)(ch * 1024 + p);
      }
    }
  }
  __syncthreads();
  int cnt = ccnt[w];
  u32 myn = 0u;  // lane r (<32) keeps r-th nearest neighbor's index
  if (cnt <= 192) {
    u64 c0 = (lane < cnt) ? cand[w][lane] : ~0ull;
    u64 c1 = (64 + lane < cnt) ? cand[w][64 + lane] : ~0ull;
    u64 c2 = (128 + lane < cnt) ? cand[w][128 + lane] : ~0ull;
    csw(c0, c1); csw(c1, c2); csw(c0, c1);  // c0<=c1<=c2
    for (int r = 0; r < 32; ++r) {
      u64 wm = c0;
      for (int s = 32; s; s >>= 1) {
        u64 o = shflx64(wm, s);
        wm = o < wm ? o : wm;
      }
      if (c0 == wm) { c0 = c1; c1 = c2; c2 = ~0ull; }
      if (lane == r) myn = (u32)wm;
    }
  } else {
    // exact slow fallback (astronomically rare): ascending extraction
    u64 last = 0ull;
    for (int r = 0; r < 32; ++r) {
      u64 bb = ~0ull;
      for (int j = 0; j < 256; ++j) {
        int p = lane + j * 64;
        float dx = __fsub_rn(cx, xb[p * 3 + 0]);
        float dy = __fsub_rn(cy, xb[p * 3 + 1]);
        float dz = __fsub_rn(cz, xb[p * 3 + 2]);
        float d = __fadd_rn(__fadd_rn(__fmul_rn(dx, dx), __fmul_rn(dy, dy)), __fmul_rn(dz, dz));
        u64 kk = ((u64)__float_as_uint(d) << 32) | (u64)(u32)p;
        if (r == 0 || kk > last)
          if (kk < bb) bb = kk;
      }
      for (int s = 32; s; s >>= 1) {
        u64 o = shflx64(bb, s);
        bb = o < bb ? o : bb;
      }
      last = bb;
      if (lane == r) myn = (u32)bb;
    }
  }
  if (lane < 32) {
    const float nx = xb[(size_t)myn * 3 + 0];
    const float ny = xb[(size_t)myn * 3 + 1];
    const float nz = xb[(size_t)myn * 3 + 2];
    float* gp = grouped + ((size_t)cg * 32 + lane) * 3;
    gp[0] = __fsub_rn(nx, cx);
    gp[1] = __fsub_rn(ny, cy);
    gp[2] = __fsub_rn(nz, cz);
  }
}

// ---------------------------------------------------------------------------
// Weight prep: fold eval-BN into weights, bf16 + MFMA-fragment-swizzled
// layouts for W2/W3 so the MLP kernel stages LDS with a linear copy.
// ---------------------------------------------------------------------------
__global__ __launch_bounds__(256) void prep_kernel(
    const float* __restrict__ W1, const float* __restrict__ b1,
    const float* __restrict__ g1, const float* __restrict__ be1,
    const float* __restrict__ m1, const float* __restrict__ v1,
    const float* __restrict__ W2, const float* __restrict__ b2,
    const float* __restrict__ g2, const float* __restrict__ be2,
    const float* __restrict__ m2, const float* __restrict__ v2,
    const float* __restrict__ W3,
    float* __restrict__ w1eff, u16* __restrict__ w2L,
    float* __restrict__ t2, u16* __restrict__ w3L) {
  const int tid = blockIdx.x * 256 + threadIdx.x;  // 128 blocks -> 32768
  if (tid < 64) {
    float s = g1[tid] / sqrtf(v1[tid] + 1e-5f);
    w1eff[tid * 4 + 0] = W1[tid * 3 + 0] * s;
    w1eff[tid * 4 + 1] = W1[tid * 3 + 1] * s;
    w1eff[tid * 4 + 2] = W1[tid * 3 + 2] * s;
    w1eff[tid * 4 + 3] = (b1[tid] - m1[tid]) * s + be1[tid];
  }
  if (tid < 128) {
    float s = g2[tid] / sqrtf(v2[tid] + 1e-5f);
    t2[tid] = (b2[tid] - m2[tid]) * s + be2[tid];
  }
  if (tid < 8192) {  // W2eff (128 out x 64 in), bn-scaled, as B-fragments
    int i = tid & 63, o = tid >> 6;
    float s = g2[o] / sqrtf(v2[o] + 1e-5f);
    int kg = i >> 3, j = i & 7;
    w2L[((((kg * 128) + o) * 8) ^ ((kg & 7) * 8)) + j] = bf16rne(W2[o * 64 + i] * s);
  }
  if (tid < 32768) {  // W3 (256 out x 128 in) as B-fragments, split in col-halves
    int i = tid & 127, o = tid >> 7;
    int kg = i >> 3, j = i & 7;
    int h = o >> 7, colh = o & 127;
    w3L[h * 16384 + ((((kg * 128) + colh) * 8) ^ ((kg & 7) * 8)) + j] = bf16rne(W3[o * 128 + i]);
  }
}

// ---------------------------------------------------------------------------
// MLP: 4 centers (128 rows) per 256-thread block; wave = one center.
// L1 on VALU (K=3), L2/L3 as bf16 MFMA GEMMs; fused max-pool + pos epilogue.
// LDS (64KB): [0,16K)=W2 (later W3 half over [0,32K)); [16K,32K)=H1; [32K,64K)=H2.
// ---------------------------------------------------------------------------
__global__ __launch_bounds__(256) void mlp_kernel(
    const float* __restrict__ grouped, const u16* __restrict__ w2L,
    const u16* __restrict__ w3L, const float* __restrict__ w1eff,
    const float* __restrict__ t2, const float* __restrict__ b3,
    const float* __restrict__ Wp, const float* __restrict__ bp,
    const float* __restrict__ centers, float* __restrict__ tokens) {
  __shared__ char lds[65536];
  const int t = threadIdx.x;
  const int lane = t & 63;
  const int w = t >> 6;
  const int l15 = lane & 15;
  const int lg = lane >> 4;
  const int c0 = blockIdx.x * 4;
  {  // stage W2 -> [0,16K)
    const u32* s = (const u32*)w2L;
    u32* d = (u32*)lds;
#pragma unroll
    for (int q = 0; q < 16; ++q) d[q * 256 + t] = s[q * 256 + t];
  }
  {  // H1 = relu(X @ W1eff^T + b1eff), bf16, swizzled -> [16K,32K)
    const int row = t & 127;
    const int oh = (t >> 7) * 32;
    const int cg = c0 + (row >> 5);
    const float* gp = grouped + ((size_t)cg * 32 + (row & 31)) * 3;
    const float gx = gp[0], gy = gp[1], gz = gp[2];
    u16 hv[32];
#pragma unroll
    for (int o = 0; o < 32; ++o) {
      const float4 wvv = ((const float4*)w1eff)[oh + o];
      float h = fmaxf(0.f, gx * wvv.x + gy * wvv.y + gz * wvv.z + wvv.w);
      hv[o] = bf16rne(h);
    }
#pragma unroll
    for (int c4 = 0; c4 < 4; ++c4) {
      uint4 pk;
      pk.x = (u32)hv[c4 * 8 + 0] | ((u32)hv[c4 * 8 + 1] << 16);
      pk.y = (u32)hv[c4 * 8 + 2] | ((u32)hv[c4 * 8 + 3] << 16);
      pk.z = (u32)hv[c4 * 8 + 4] | ((u32)hv[c4 * 8 + 5] << 16);
      pk.w = (u32)hv[c4 * 8 + 6] | ((u32)hv[c4 * 8 + 7] << 16);
      int byte = row * 128 + oh * 2 + c4 * 16;
      *reinterpret_cast<uint4*>(lds + 16384 + (byte ^ ((row & 7) << 4))) = pk;
    }
  }
  __syncthreads();
  // GEMM2: H2(32x128) = H1(32x64) @ W2eff^T, per wave
  f32x4 acc2[2][8];
#pragma unroll
  for (int m = 0; m < 2; ++m)
#pragma unroll
    for (int n = 0; n < 8; ++n) acc2[m][n] = (f32x4){0.f, 0.f, 0.f, 0.f};
#pragma unroll
  for (int ks = 0; ks < 2; ++ks) {
    bf16x8 a[2];
#pragma unroll
    for (int m = 0; m < 2; ++m) {
      int row = w * 32 + m * 16 + l15;
      int byte = row * 128 + (ks * 32 + lg * 8) * 2;
      a[m] = *reinterpret_cast<const bf16x8*>(lds + 16384 + (byte ^ ((row & 7) << 4)));
    }
    const int kg = ks * 4 + lg;
#pragma unroll
    for (int n = 0; n < 8; ++n) {
      int idx = (((kg * 128) + (n * 16 + l15)) * 8) ^ ((kg & 7) * 8);
      bf16x8 bb = *reinterpret_cast<const bf16x8*>((const u16*)lds + idx);
      acc2[0][n] = MFMA16(a[0], bb, acc2[0][n]);
      acc2[1][n] = MFMA16(a[1], bb, acc2[1][n]);
    }
  }
#pragma unroll
  for (int n = 0; n < 8; ++n) {  // relu(acc + t2) -> H2 bf16 swizzled
    const int col = n * 16 + l15;
    const float t2v = t2[col];
#pragma unroll
    for (int m = 0; m < 2; ++m)
#pragma unroll
      for (int r = 0; r < 4; ++r) {
        float vv = fmaxf(0.f, acc2[m][n][r] + t2v);
        int row = w * 32 + m * 16 + lg * 4 + r;
        int byte = row * 256 + col * 2;
        *reinterpret_cast<u16*>(lds + 32768 + (byte ^ ((row & 7) << 4))) = bf16rne(vv);
      }
  }
  __syncthreads();
  const float ccx = centers[(c0 + w) * 3 + 0];
  const float ccy = centers[(c0 + w) * 3 + 1];
  const float ccz = centers[(c0 + w) * 3 + 2];
  float* tok = tokens + (size_t)(c0 + w) * 256;
  for (int h = 0; h < 2; ++h) {
    {  // stage W3 col-half (32KB) -> [0,32K); H2 at [32K,64K) untouched
      const u32* s = (const u32*)w3L + h * 8192;
      u32* d = (u32*)lds;
#pragma unroll
      for (int q = 0; q < 32; ++q) d[q * 256 + t] = s[q * 256 + t];
    }
    __syncthreads();
    f32x4 acc3[2][8];
#pragma unroll
    for (int m = 0; m < 2; ++m)
#pragma unroll
      for (int n = 0; n < 8; ++n) acc3[m][n] = (f32x4){0.f, 0.f, 0.f, 0.f};
#pragma unroll
    for (int ks = 0; ks < 4; ++ks) {
      bf16x8 a[2];
#pragma unroll
      for (int m = 0; m < 2; ++m) {
        int row = w * 32 + m * 16 + l15;
        int byte = row * 256 + (ks * 32 + lg * 8) * 2;
        a[m] = *reinterpret_cast<const bf16x8*>(lds + 32768 + (byte ^ ((row & 7) << 4)));
      }
      const int kg = ks * 4 + lg;
#pragma unroll
      for (int n = 0; n < 8; ++n) {
        int idx = (((kg * 128) + (n * 16 + l15)) * 8) ^ ((kg & 7) * 8);
        bf16x8 bb = *reinterpret_cast<const bf16x8*>((const u16*)lds + idx);
        acc3[0][n] = MFMA16(a[0], bb, acc3[0][n]);
        acc3[1][n] = MFMA16(a[1], bb, acc3[1][n]);
      }
    }
#pragma unroll
    for (int n = 0; n < 8; ++n) {  // max over 32 neighbors + b3 + pos
      float vmx = acc3[0][n][0];
#pragma unroll
      for (int m = 0; m < 2; ++m)
#pragma unroll
        for (int r = 0; r < 4; ++r) vmx = fmaxf(vmx, acc3[m][n][r]);
      vmx = fmaxf(vmx, __shfl_xor(vmx, 16, 64));
      vmx = fmaxf(vmx, __shfl_xor(vmx, 32, 64));
      const int col = h * 128 + n * 16 + l15;
      if (lane < 16) {
        float pos = Wp[col * 3 + 0] * ccx + Wp[col * 3 + 1] * ccy +
                    Wp[col * 3 + 2] * ccz + bp[col] + b3[col];
        tok[col] = vmx + pos;
      }
    }
    __syncthreads();
  }
}

// ---------------------------------------------------------------------------
extern "C" void kernel_launch(void* const* d_in, const int* in_sizes, int n_in,
                              void* d_out, int out_size, void* d_ws, size_t ws_size,
                              hipStream_t stream) {
  const float* xyz = (const float*)d_in[0];
  const float* W1 = (const float*)d_in[1];
  const float* b1 = (const float*)d_in[2];
  const float* g1 = (const float*)d_in[3];
  const float* be1 = (const float*)d_in[4];
  const float* m1 = (const float*)d_in[5];
  const float* v1 = (const float*)d_in[6];
  const float* W2 = (const float*)d_in[7];
  const float* b2 = (const float*)d_in[8];
  const float* g2 = (const float*)d_in[9];
  const float* be2 = (const float*)d_in[10];
  const float* m2 = (const float*)d_in[11];
  const float* v2 = (const float*)d_in[12];
  const float* W3 = (const float*)d_in[13];
  const float* b3 = (const float*)d_in[14];
  const float* Wp = (const float*)d_in[15];
  const float* bp = (const float*)d_in[16];

  char* ws = (char*)d_ws;
  float* grouped = (float*)ws;                      // 4096*32*3 f32 = 1572864 B
  float* w1eff = (float*)(ws + 1572864);            // 64*4 f32     = 1024 B
  u16* w2L = (u16*)(ws + 1573888);                  // 8192 u16     = 16384 B
  float* t2 = (float*)(ws + 1590272);               // 128 f32      = 512 B
  u16* w3L = (u16*)(ws + 1590784);                  // 32768 u16    = 65536 B

  float* centers = (float*)d_out;                   // (8,512,3)
  float* tokens = (float*)d_out + 8 * 512 * 3;      // (8,512,256)

  prep_kernel<<<dim3(128), dim3(256), 0, stream>>>(W1, b1, g1, be1, m1, v1,
                                                   W2, b2, g2, be2, m2, v2, W3,
                                                   w1eff, w2L, t2, w3L);
  fps_kernel<<<dim3(8), dim3(1024), 0, stream>>>(xyz, centers);
  knn_kernel<<<dim3(512), dim3(512), 0, stream>>>(xyz, centers, grouped);
  mlp_kernel<<<dim3(1024), dim3(256), 0, stream>>>(grouped, w2L, w3L, w1eff, t2,
                                                   b3, Wp, bp, centers, tokens);
}

// Round 8
// 1426.374 us; speedup vs baseline: 1.0512x; 1.0512x over previous
//
#include <hip/hip_runtime.h>

typedef unsigned int u32;
typedef unsigned long long u64;
typedef unsigned short u16;

#define DEVFN static __device__ __forceinline__

constexpr int NPTS = 16384;  // points per batch
constexpr int NC = 512;      // centers per batch
// B=8, K=32, FEAT=256

typedef __attribute__((ext_vector_type(8))) short bf16x8;
typedef __attribute__((ext_vector_type(4))) float f32x4;

#define MFMA16(a, b, c) __builtin_amdgcn_mfma_f32_16x16x32_bf16(a, b, c, 0, 0, 0)

DEVFN u16 bf16rne(float f) {
  u32 b = __float_as_uint(f);
  u32 r = (b + 0x7FFFu + ((b >> 16) & 1u)) >> 16;
  return (u16)r;
}

DEVFN u64 shflx64(u64 v, int m) {
  u32 lo = __shfl_xor((u32)v, m, 64);
  u32 hi = __shfl_xor((u32)(v >> 32), m, 64);
  return ((u64)hi << 32) | lo;
}
DEVFN u64 shfl64(u64 v, int src) {
  u32 lo = __shfl((u32)v, src, 64);
  u32 hi = __shfl((u32)(v >> 32), src, 64);
  return ((u64)hi << 32) | lo;
}

DEVFN void csw(u64& a, u64& b) {
  u64 lo = a < b ? a : b;
  u64 hi = a < b ? b : a;
  a = lo; b = hi;
}

DEVFN u32 spread3(u32 v) {  // 4 bits -> bits 0,3,6,9
  return (v & 1u) | ((v & 2u) << 2) | ((v & 4u) << 4) | ((v & 8u) << 6);
}

// ---------------------------------------------------------------------------
// FPS v7: accept the 64-VGPR cap; make reloads cheap instead of fighting it.
// Setup writes Morton-sorted coords to ws as SoA in owner-thread layout
// (each thread's 16 points = 64B contiguous per axis). Main loop keeps only
// md[16] f32 + packed oidx[8] + bbox in regs (~50 VGPRs, fits the cap) and
// explicitly reloads coords inside the active branch: 12 dwordx4 L1/L2-hot
// loads per active cluster-iteration, vs 48 scattered scalar loads before.
// Read pointers are asm-laundered so setup stores can't be forwarded into
// long-lived registers. 1 barrier/iter; winner publishes {key,coords} to LDS.
// Exactness: key=(md_bits||16383-oidx), u64 max == numpy argmax (max md,
// tie -> lowest index); prune = monotone-rounding bbox lower bound.
// ---------------------------------------------------------------------------
__global__ __launch_bounds__(1024) void fps_kernel(const float* __restrict__ xyz,
                                                   float* __restrict__ centers,
                                                   float* __restrict__ wsx,
                                                   float* __restrict__ wsy,
                                                   float* __restrict__ wsz) {
  const int b = blockIdx.x;
  const int t = threadIdx.x;
  const int lane = t & 63;
  const int w = t >> 6;
  const float* xb = xyz + (size_t)b * NPTS * 3;

  __shared__ u32 hist[2048];
  __shared__ u16 soidx[NPTS];
  __shared__ u32 skb[2 * 16 * 10];
  __shared__ float redB[104];
  __shared__ u32 redW[16];

  // ---- setup: global bbox + morton codes ----
  u32 mcode[16];
  {
    float ox[16], oy[16], oz[16];
    float lx = 1e30f, ly = 1e30f, lz = 1e30f;
    float hx = -1e30f, hy = -1e30f, hz = -1e30f;
#pragma unroll
    for (int j = 0; j < 16; ++j) {
      int p = t + j * 1024;
      ox[j] = xb[p * 3 + 0];
      oy[j] = xb[p * 3 + 1];
      oz[j] = xb[p * 3 + 2];
      lx = fminf(lx, ox[j]); hx = fmaxf(hx, ox[j]);
      ly = fminf(ly, oy[j]); hy = fmaxf(hy, oy[j]);
      lz = fminf(lz, oz[j]); hz = fmaxf(hz, oz[j]);
    }
#pragma unroll
    for (int s = 32; s; s >>= 1) {
      lx = fminf(lx, __shfl_xor(lx, s, 64)); hx = fmaxf(hx, __shfl_xor(hx, s, 64));
      ly = fminf(ly, __shfl_xor(ly, s, 64)); hy = fmaxf(hy, __shfl_xor(hy, s, 64));
      lz = fminf(lz, __shfl_xor(lz, s, 64)); hz = fmaxf(hz, __shfl_xor(hz, s, 64));
    }
    if (lane == 0) {
      redB[w * 6 + 0] = lx; redB[w * 6 + 1] = hx;
      redB[w * 6 + 2] = ly; redB[w * 6 + 3] = hy;
      redB[w * 6 + 4] = lz; redB[w * 6 + 5] = hz;
    }
    hist[t] = 0; hist[t + 1024] = 0;
    __syncthreads();
    if (t == 0) {
      float a0 = redB[0], a1 = redB[1], a2 = redB[2], a3 = redB[3], a4 = redB[4], a5 = redB[5];
      for (int q = 1; q < 16; ++q) {
        a0 = fminf(a0, redB[q * 6 + 0]); a1 = fmaxf(a1, redB[q * 6 + 1]);
        a2 = fminf(a2, redB[q * 6 + 2]); a3 = fmaxf(a3, redB[q * 6 + 3]);
        a4 = fminf(a4, redB[q * 6 + 4]); a5 = fmaxf(a5, redB[q * 6 + 5]);
      }
      redB[96] = a0; redB[97] = a1; redB[98] = a2;
      redB[99] = a3; redB[100] = a4; redB[101] = a5;
    }
    __syncthreads();
    const float glx = redB[96], ghx = redB[97];
    const float gly = redB[98], ghy = redB[99];
    const float glz = redB[100], ghz = redB[101];
    const float sx = 15.999f / fmaxf(ghx - glx, 1e-9f);
    const float sy = 15.999f / fmaxf(ghy - gly, 1e-9f);
    const float sz = 7.999f / fmaxf(ghz - glz, 1e-9f);
#pragma unroll
    for (int j = 0; j < 16; ++j) {
      int ix = min(15, max(0, (int)((ox[j] - glx) * sx)));
      int iy = min(15, max(0, (int)((oy[j] - gly) * sy)));
      int iz = min(7, max(0, (int)((oz[j] - glz) * sz)));
      mcode[j] = spread3((u32)ix) | (spread3((u32)iy) << 1) | (spread3((u32)iz) << 2);
    }
  }
  // ---- histogram (2048 bins) ----
#pragma unroll
  for (int j = 0; j < 16; ++j) atomicAdd(&hist[mcode[j]], 1u);
  __syncthreads();
  // ---- exclusive scan over 2048 bins ----
  {
    u32 h0 = hist[t * 2 + 0], h1 = hist[t * 2 + 1];
    u32 s = h0 + h1;
    u32 incl = s;
#pragma unroll
    for (int d = 1; d < 64; d <<= 1) {
      u32 n = __shfl_up(incl, d, 64);
      if (lane >= d) incl += n;
    }
    if (lane == 63) redW[w] = incl;
    __syncthreads();
    if (t == 0) {
      u32 run = 0;
      for (int q = 0; q < 16; ++q) { u32 tmp = redW[q]; redW[q] = run; run += tmp; }
    }
    __syncthreads();
    u32 exc = incl - s + redW[w];
    hist[t * 2 + 0] = exc;
    hist[t * 2 + 1] = exc + h0;
    __syncthreads();
  }
  // ---- scatter: sorted position -> original index ----
#pragma unroll
  for (int j = 0; j < 16; ++j) {
    u32 p = (u32)(t + j * 1024);
    u32 pos = atomicAdd(&hist[mcode[j]], 1u);
    soidx[pos] = (u16)p;
  }
  __syncthreads();
  // ---- gather own 16 sorted points: write SoA ws arrays, pack oidx, bbox ----
  const u32 spbase = (u32)((t >> 2) * 64 + (t & 3) * 16);
  float* wxs = wsx + (size_t)b * NPTS + spbase;
  float* wys = wsy + (size_t)b * NPTS + spbase;
  float* wzs = wsz + (size_t)b * NPTS + spbase;
  float md[16];
  u32 op[8];
#pragma unroll
  for (int h = 0; h < 8; ++h) op[h] = 0;
  float bxl = 1e30f, bxh = -1e30f, byl = 1e30f, byh = -1e30f, bzl = 1e30f, bzh = -1e30f;
#pragma unroll
  for (int j = 0; j < 16; ++j) {
    u32 oidx = (u32)soidx[spbase + j];
    float X = xb[oidx * 3 + 0];
    float Y = xb[oidx * 3 + 1];
    float Z = xb[oidx * 3 + 2];
    wxs[j] = X; wys[j] = Y; wzs[j] = Z;
    op[j >> 1] |= oidx << ((j & 1) * 16);
    bxl = fminf(bxl, X); bxh = fmaxf(bxh, X);
    byl = fminf(byl, Y); byh = fmaxf(byh, Y);
    bzl = fminf(bzl, Z); bzh = fmaxf(bzh, Z);
    md[j] = 1e10f;
  }
#pragma unroll
  for (int s = 1; s <= 2; s <<= 1) {
    bxl = fminf(bxl, __shfl_xor(bxl, s, 64)); bxh = fmaxf(bxh, __shfl_xor(bxh, s, 64));
    byl = fminf(byl, __shfl_xor(byl, s, 64)); byh = fmaxf(byh, __shfl_xor(byh, s, 64));
    bzl = fminf(bzl, __shfl_xor(bzl, s, 64)); bzh = fmaxf(bzh, __shfl_xor(bzh, s, 64));
  }
  // laundered read pointers: compiler cannot store-forward the ws writes
  const float* wxp = wxs; const float* wyp = wys; const float* wzp = wzs;
  asm("" : "+v"(wxp), "+v"(wyp), "+v"(wzp));
  float cx = xb[0], cy = xb[1], cz = xb[2];
  if (t == 0) {
    centers[(b * NC) * 3 + 0] = cx;
    centers[(b * NC) * 3 + 1] = cy;
    centers[(b * NC) * 3 + 2] = cz;
  }
  float mdm = 1e10f;  // cluster max md (group-uniform)
  u32 mlo = 0;        // cluster tie bits (group-uniform)

  // ---- main loop: 1 barrier per iteration ----
  for (int i = 1; i < NC; ++i) {
    float ax = fmaxf(0.f, fmaxf(__fsub_rn(bxl, cx), __fsub_rn(cx, bxh)));
    float ay = fmaxf(0.f, fmaxf(__fsub_rn(byl, cy), __fsub_rn(cy, byh)));
    float az = fmaxf(0.f, fmaxf(__fsub_rn(bzl, cz), __fsub_rn(cz, bzh)));
    float dlb = __fadd_rn(__fadd_rn(__fmul_rn(ax, ax), __fmul_rn(ay, ay)), __fmul_rn(az, az));
    if (dlb < mdm) {  // group-uniform branch; explicit contiguous reloads inside
      float nmx = 0.0f;
#pragma unroll
      for (int j = 0; j < 16; ++j) {
        float dx = __fsub_rn(wxp[j], cx);
        float dy = __fsub_rn(wyp[j], cy);
        float dz = __fsub_rn(wzp[j], cz);
        float d = __fadd_rn(__fadd_rn(__fmul_rn(dx, dx), __fmul_rn(dy, dy)), __fmul_rn(dz, dz));
        md[j] = fminf(md[j], d);
        nmx = fmaxf(nmx, md[j]);
      }
      nmx = fmaxf(nmx, __shfl_xor(nmx, 1, 64));
      nmx = fmaxf(nmx, __shfl_xor(nmx, 2, 64));
      u32 pk = 0;
#pragma unroll
      for (int j = 0; j < 16; ++j) {
        u32 oj = (op[j >> 1] >> ((j & 1) * 16)) & 0xFFFFu;
        pk = (md[j] == nmx) ? max(pk, 16383u - oj) : pk;
      }
      pk = max(pk, __shfl_xor(pk, 1, 64));
      pk = max(pk, __shfl_xor(pk, 2, 64));
      mdm = nmx; mlo = pk;
    }
    u64 ck = ((u64)__float_as_uint(mdm) << 32) | mlo;
    u64 wk = ck;  // wave max over 16 clusters (groups uniform -> start at 4)
#pragma unroll
    for (int s = 4; s <= 32; s <<= 1) { u64 o = shflx64(wk, s); wk = o > wk ? o : wk; }
    u32* row = skb + ((i & 1) * 16 + w) * 10;
    if (ck == wk) {  // winning cluster's 4 lanes; unique (lane,j) matches
      const u32 whi = (u32)(wk >> 32), wlo = (u32)wk;
#pragma unroll
      for (int j = 0; j < 16; ++j) {
        u32 oj = (op[j >> 1] >> ((j & 1) * 16)) & 0xFFFFu;
        if (__float_as_uint(md[j]) == whi && (16383u - oj) == wlo) {
          row[0] = whi; row[1] = wlo;
          row[2] = __float_as_uint(wxp[j]);
          row[3] = __float_as_uint(wyp[j]);
          row[4] = __float_as_uint(wzp[j]);
        }
      }
    }
    __syncthreads();
    const u32* rrow = skb + ((i & 1) * 16 + (lane & 15)) * 10;
    u64 gk = ((u64)rrow[0] << 32) | rrow[1];
    u32 widx = (u32)(lane & 15);
#pragma unroll
    for (int s = 1; s <= 8; s <<= 1) {
      u64 o = shflx64(gk, s);
      u32 ow = __shfl_xor(widx, s, 64);
      if (o > gk) { gk = o; widx = ow; }
    }
    widx = __builtin_amdgcn_readfirstlane(widx);
    const u32* wrow = skb + ((i & 1) * 16 + widx) * 10;
    cx = __uint_as_float(wrow[2]);
    cy = __uint_as_float(wrow[3]);
    cz = __uint_as_float(wrow[4]);
    if (t == 0) {
      centers[(b * NC + i) * 3 + 0] = cx;
      centers[(b * NC + i) * 3 + 1] = cy;
      centers[(b * NC + i) * 3 + 2] = cz;
    }
  }
}

// ---------------------------------------------------------------------------
// KNN: 8 waves/block, wave = one center. Exact top-32 set by (d, idx).
// ---------------------------------------------------------------------------
__global__ __launch_bounds__(512) void knn_kernel(const float* __restrict__ xyz,
                                                  const float* __restrict__ centers,
                                                  float* __restrict__ grouped) {
  __shared__ float spts[1024 * 3];
  __shared__ u64 cand[8][192];
  __shared__ int ccnt[8];
  const int t = threadIdx.x;
  const int lane = t & 63;
  const int w = t >> 6;
  const int cg = blockIdx.x * 8 + w;   // global center id
  const int b = cg >> 9;               // / 512
  const float* xb = xyz + (size_t)b * NPTS * 3;
  const float cx = centers[cg * 3 + 0];
  const float cy = centers[cg * 3 + 1];
  const float cz = centers[cg * 3 + 2];
  if (lane == 0) ccnt[w] = 0;

  // phase 1: per-lane min (packed (d,idx))
  u64 lmin = ~0ull;
  for (int ch = 0; ch < 16; ++ch) {
    __syncthreads();
    const float* src = xb + ch * 1024 * 3;
#pragma unroll
    for (int q = 0; q < 6; ++q) spts[q * 512 + t] = src[q * 512 + t];
    __syncthreads();
#pragma unroll
    for (int j = 0; j < 16; ++j) {
      int p = lane + j * 64;
      float dx = __fsub_rn(cx, spts[p * 3 + 0]);
      float dy = __fsub_rn(cy, spts[p * 3 + 1]);
      float dz = __fsub_rn(cz, spts[p * 3 + 2]);
      float d = __fadd_rn(__fadd_rn(__fmul_rn(dx, dx), __fmul_rn(dy, dy)), __fmul_rn(dz, dz));
      u64 kk = ((u64)__float_as_uint(d) << 32) | (u64)(u32)(ch * 1024 + p);
      lmin = kk < lmin ? kk : lmin;
    }
  }
  // bitonic sort (ascending) of 64 lane-minima; tau = 32nd smallest
  u64 v = lmin;
  for (int k = 2; k <= 64; k <<= 1)
    for (int j = k >> 1; j > 0; j >>= 1) {
      u64 o = shflx64(v, j);
      bool up = ((lane & k) == 0);
      bool lowr = ((lane & j) == 0);
      u64 mn = v < o ? v : o;
      u64 mx = v < o ? o : v;
      v = (lowr == up) ? mn : mx;
    }
  u64 tau = shfl64(v, 31);
  float tf = __uint_as_float((u32)(tau >> 32));

  // phase 2: collect candidates d <= tf  (guaranteed >= 32 of them)
  for (int ch = 0; ch < 16; ++ch) {
    __syncthreads();
    const float* src = xb + ch * 1024 * 3;
#pragma unroll
    for (int q = 0; q < 6; ++q) spts[q * 512 + t] = src[q * 512 + t];
    __syncthreads();
#pragma unroll
    for (int j = 0; j < 16; ++j) {
      int p = lane + j * 64;
      float dx = __fsub_rn(cx, spts[p * 3 + 0]);
      float dy = __fsub_rn(cy, spts[p * 3 + 1]);
      float dz = __fsub_rn(cz, spts[p * 3 + 2]);
      float d = __fadd_rn(__fadd_rn(__fmul_rn(dx, dx), __fmul_rn(dy, dy)), __fmul_rn(dz, dz));
      if (d <= tf) {
        int pos = atomicAdd(&ccnt[w], 1);
        if (pos < 192) cand[w][pos] = ((u64)__float_as_uint(d) << 32) | (u64)(u32)(ch * 1024 + p);
      }
    }
  }
  __syncthreads();
  int cnt = ccnt[w];
  u32 myn = 0u;  // lane r (<32) keeps r-th nearest neighbor's index
  if (cnt <= 192) {
    u64 c0 = (lane < cnt) ? cand[w][lane] : ~0ull;
    u64 c1 = (64 + lane < cnt) ? cand[w][64 + lane] : ~0ull;
    u64 c2 = (128 + lane < cnt) ? cand[w][128 + lane] : ~0ull;
    csw(c0, c1); csw(c1, c2); csw(c0, c1);  // c0<=c1<=c2
    for (int r = 0; r < 32; ++r) {
      u64 wm = c0;
      for (int s = 32; s; s >>= 1) {
        u64 o = shflx64(wm, s);
        wm = o < wm ? o : wm;
      }
      if (c0 == wm) { c0 = c1; c1 = c2; c2 = ~0ull; }
      if (lane == r) myn = (u32)wm;
    }
  } else {
    // exact slow fallback (astronomically rare): ascending extraction
    u64 last = 0ull;
    for (int r = 0; r < 32; ++r) {
      u64 bb = ~0ull;
      for (int j = 0; j < 256; ++j) {
        int p = lane + j * 64;
        float dx = __fsub_rn(cx, xb[p * 3 + 0]);
        float dy = __fsub_rn(cy, xb[p * 3 + 1]);
        float dz = __fsub_rn(cz, xb[p * 3 + 2]);
        float d = __fadd_rn(__fadd_rn(__fmul_rn(dx, dx), __fmul_rn(dy, dy)), __fmul_rn(dz, dz));
        u64 kk = ((u64)__float_as_uint(d) << 32) | (u64)(u32)p;
        if (r == 0 || kk > last)
          if (kk < bb) bb = kk;
      }
      for (int s = 32; s; s >>= 1) {
        u64 o = shflx64(bb, s);
        bb = o < bb ? o : bb;
      }
      last = bb;
      if (lane == r) myn = (u32)bb;
    }
  }
  if (lane < 32) {
    const float nx = xb[(size_t)myn * 3 + 0];
    const float ny = xb[(size_t)myn * 3 + 1];
    const float nz = xb[(size_t)myn * 3 + 2];
    float* gp = grouped + ((size_t)cg * 32 + lane) * 3;
    gp[0] = __fsub_rn(nx, cx);
    gp[1] = __fsub_rn(ny, cy);
    gp[2] = __fsub_rn(nz, cz);
  }
}

// ---------------------------------------------------------------------------
// Weight prep: fold eval-BN into weights, bf16 + MFMA-fragment-swizzled
// layouts for W2/W3 so the MLP kernel stages LDS with a linear copy.
// ---------------------------------------------------------------------------
__global__ __launch_bounds__(256) void prep_kernel(
    const float* __restrict__ W1, const float* __restrict__ b1,
    const float* __restrict__ g1, const float* __restrict__ be1,
    const float* __restrict__ m1, const float* __restrict__ v1,
    const float* __restrict__ W2, const float* __restrict__ b2,
    const float* __restrict__ g2, const float* __restrict__ be2,
    const float* __restrict__ m2, const float* __restrict__ v2,
    const float* __restrict__ W3,
    float* __restrict__ w1eff, u16* __restrict__ w2L,
    float* __restrict__ t2, u16* __restrict__ w3L) {
  const int tid = blockIdx.x * 256 + threadIdx.x;  // 128 blocks -> 32768
  if (tid < 64) {
    float s = g1[tid] / sqrtf(v1[tid] + 1e-5f);
    w1eff[tid * 4 + 0] = W1[tid * 3 + 0] * s;
    w1eff[tid * 4 + 1] = W1[tid * 3 + 1] * s;
    w1eff[tid * 4 + 2] = W1[tid * 3 + 2] * s;
    w1eff[tid * 4 + 3] = (b1[tid] - m1[tid]) * s + be1[tid];
  }
  if (tid < 128) {
    float s = g2[tid] / sqrtf(v2[tid] + 1e-5f);
    t2[tid] = (b2[tid] - m2[tid]) * s + be2[tid];
  }
  if (tid < 8192) {  // W2eff (128 out x 64 in), bn-scaled, as B-fragments
    int i = tid & 63, o = tid >> 6;
    float s = g2[o] / sqrtf(v2[o] + 1e-5f);
    int kg = i >> 3, j = i & 7;
    w2L[((((kg * 128) + o) * 8) ^ ((kg & 7) * 8)) + j] = bf16rne(W2[o * 64 + i] * s);
  }
  if (tid < 32768) {  // W3 (256 out x 128 in) as B-fragments, split in col-halves
    int i = tid & 127, o = tid >> 7;
    int kg = i >> 3, j = i & 7;
    int h = o >> 7, colh = o & 127;
    w3L[h * 16384 + ((((kg * 128) + colh) * 8) ^ ((kg & 7) * 8)) + j] = bf16rne(W3[o * 128 + i]);
  }
}

// ---------------------------------------------------------------------------
// MLP: 4 centers (128 rows) per 256-thread block; wave = one center.
// L1 on VALU (K=3), L2/L3 as bf16 MFMA GEMMs; fused max-pool + pos epilogue.
// LDS (64KB): [0,16K)=W2 (later W3 half over [0,32K)); [16K,32K)=H1; [32K,64K)=H2.
// ---------------------------------------------------------------------------
__global__ __launch_bounds__(256) void mlp_kernel(
    const float* __restrict__ grouped, const u16* __restrict__ w2L,
    const u16* __restrict__ w3L, const float* __restrict__ w1eff,
    const float* __restrict__ t2, const float* __restrict__ b3,
    const float* __restrict__ Wp, const float* __restrict__ bp,
    const float* __restrict__ centers, float* __restrict__ tokens) {
  __shared__ char lds[65536];
  const int t = threadIdx.x;
  const int lane = t & 63;
  const int w = t >> 6;
  const int l15 = lane & 15;
  const int lg = lane >> 4;
  const int c0 = blockIdx.x * 4;
  {  // stage W2 -> [0,16K)
    const u32* s = (const u32*)w2L;
    u32* d = (u32*)lds;
#pragma unroll
    for (int q = 0; q < 16; ++q) d[q * 256 + t] = s[q * 256 + t];
  }
  {  // H1 = relu(X @ W1eff^T + b1eff), bf16, swizzled -> [16K,32K)
    const int row = t & 127;
    const int oh = (t >> 7) * 32;
    const int cg = c0 + (row >> 5);
    const float* gp = grouped + ((size_t)cg * 32 + (row & 31)) * 3;
    const float gx = gp[0], gy = gp[1], gz = gp[2];
    u16 hv[32];
#pragma unroll
    for (int o = 0; o < 32; ++o) {
      const float4 wvv = ((const float4*)w1eff)[oh + o];
      float h = fmaxf(0.f, gx * wvv.x + gy * wvv.y + gz * wvv.z + wvv.w);
      hv[o] = bf16rne(h);
    }
#pragma unroll
    for (int c4 = 0; c4 < 4; ++c4) {
      uint4 pk;
      pk.x = (u32)hv[c4 * 8 + 0] | ((u32)hv[c4 * 8 + 1] << 16);
      pk.y = (u32)hv[c4 * 8 + 2] | ((u32)hv[c4 * 8 + 3] << 16);
      pk.z = (u32)hv[c4 * 8 + 4] | ((u32)hv[c4 * 8 + 5] << 16);
      pk.w = (u32)hv[c4 * 8 + 6] | ((u32)hv[c4 * 8 + 7] << 16);
      int byte = row * 128 + oh * 2 + c4 * 16;
      *reinterpret_cast<uint4*>(lds + 16384 + (byte ^ ((row & 7) << 4))) = pk;
    }
  }
  __syncthreads();
  // GEMM2: H2(32x128) = H1(32x64) @ W2eff^T, per wave
  f32x4 acc2[2][8];
#pragma unroll
  for (int m = 0; m < 2; ++m)
#pragma unroll
    for (int n = 0; n < 8; ++n) acc2[m][n] = (f32x4){0.f, 0.f, 0.f, 0.f};
#pragma unroll
  for (int ks = 0; ks < 2; ++ks) {
    bf16x8 a[2];
#pragma unroll
    for (int m = 0; m < 2; ++m) {
      int row = w * 32 + m * 16 + l15;
      int byte = row * 128 + (ks * 32 + lg * 8) * 2;
      a[m] = *reinterpret_cast<const bf16x8*>(lds + 16384 + (byte ^ ((row & 7) << 4)));
    }
    const int kg = ks * 4 + lg;
#pragma unroll
    for (int n = 0; n < 8; ++n) {
      int idx = (((kg * 128) + (n * 16 + l15)) * 8) ^ ((kg & 7) * 8);
      bf16x8 bb = *reinterpret_cast<const bf16x8*>((const u16*)lds + idx);
      acc2[0][n] = MFMA16(a[0], bb, acc2[0][n]);
      acc2[1][n] = MFMA16(a[1], bb, acc2[1][n]);
    }
  }
#pragma unroll
  for (int n = 0; n < 8; ++n) {  // relu(acc + t2) -> H2 bf16 swizzled
    const int col = n * 16 + l15;
    const float t2v = t2[col];
#pragma unroll
    for (int m = 0; m < 2; ++m)
#pragma unroll
      for (int r = 0; r < 4; ++r) {
        float vv = fmaxf(0.f, acc2[m][n][r] + t2v);
        int row = w * 32 + m * 16 + lg * 4 + r;
        int byte = row * 256 + col * 2;
        *reinterpret_cast<u16*>(lds + 32768 + (byte ^ ((row & 7) << 4))) = bf16rne(vv);
      }
  }
  __syncthreads();
  const float ccx = centers[(c0 + w) * 3 + 0];
  const float ccy = centers[(c0 + w) * 3 + 1];
  const float ccz = centers[(c0 + w) * 3 + 2];
  float* tok = tokens + (size_t)(c0 + w) * 256;
  for (int h = 0; h < 2; ++h) {
    {  // stage W3 col-half (32KB) -> [0,32K); H2 at [32K,64K) untouched
      const u32* s = (const u32*)w3L + h * 8192;
      u32* d = (u32*)lds;
#pragma unroll
      for (int q = 0; q < 32; ++q) d[q * 256 + t] = s[q * 256 + t];
    }
    __syncthreads();
    f32x4 acc3[2][8];
#pragma unroll
    for (int m = 0; m < 2; ++m)
#pragma unroll
      for (int n = 0; n < 8; ++n) acc3[m][n] = (f32x4){0.f, 0.f, 0.f, 0.f};
#pragma unroll
    for (int ks = 0; ks < 4; ++ks) {
      bf16x8 a[2];
#pragma unroll
      for (int m = 0; m < 2; ++m) {
        int row = w * 32 + m * 16 + l15;
        int byte = row * 256 + (ks * 32 + lg * 8) * 2;
        a[m] = *reinterpret_cast<const bf16x8*>(lds + 32768 + (byte ^ ((row & 7) << 4)));
      }
      const int kg = ks * 4 + lg;
#pragma unroll
      for (int n = 0; n < 8; ++n) {
        int idx = (((kg * 128) + (n * 16 + l15)) * 8) ^ ((kg & 7) * 8);
        bf16x8 bb = *reinterpret_cast<const bf16x8*>((const u16*)lds + idx);
        acc3[0][n] = MFMA16(a[0], bb, acc3[0][n]);
        acc3[1][n] = MFMA16(a[1], bb, acc3[1][n]);
      }
    }
#pragma unroll
    for (int n = 0; n < 8; ++n) {  // max over 32 neighbors + b3 + pos
      float vmx = acc3[0][n][0];
#pragma unroll
      for (int m = 0; m < 2; ++m)
#pragma unroll
        for (int r = 0; r < 4; ++r) vmx = fmaxf(vmx, acc3[m][n][r]);
      vmx = fmaxf(vmx, __shfl_xor(vmx, 16, 64));
      vmx = fmaxf(vmx, __shfl_xor(vmx, 32, 64));
      const int col = h * 128 + n * 16 + l15;
      if (lane < 16) {
        float pos = Wp[col * 3 + 0] * ccx + Wp[col * 3 + 1] * ccy +
                    Wp[col * 3 + 2] * ccz + bp[col] + b3[col];
        tok[col] = vmx + pos;
      }
    }
    __syncthreads();
  }
}

// ---------------------------------------------------------------------------
extern "C" void kernel_launch(void* const* d_in, const int* in_sizes, int n_in,
                              void* d_out, int out_size, void* d_ws, size_t ws_size,
                              hipStream_t stream) {
  const float* xyz = (const float*)d_in[0];
  const float* W1 = (const float*)d_in[1];
  const float* b1 = (const float*)d_in[2];
  const float* g1 = (const float*)d_in[3];
  const float* be1 = (const float*)d_in[4];
  const float* m1 = (const float*)d_in[5];
  const float* v1 = (const float*)d_in[6];
  const float* W2 = (const float*)d_in[7];
  const float* b2 = (const float*)d_in[8];
  const float* g2 = (const float*)d_in[9];
  const float* be2 = (const float*)d_in[10];
  const float* m2 = (const float*)d_in[11];
  const float* v2 = (const float*)d_in[12];
  const float* W3 = (const float*)d_in[13];
  const float* b3 = (const float*)d_in[14];
  const float* Wp = (const float*)d_in[15];
  const float* bp = (const float*)d_in[16];

  char* ws = (char*)d_ws;
  float* grouped = (float*)ws;                      // 4096*32*3 f32 = 1572864 B
  float* w1eff = (float*)(ws + 1572864);            // 64*4 f32     = 1024 B
  u16* w2L = (u16*)(ws + 1573888);                  // 8192 u16     = 16384 B
  float* t2 = (float*)(ws + 1590272);               // 128 f32      = 512 B
  u16* w3L = (u16*)(ws + 1590784);                  // 32768 u16    = 65536 B
  float* wsx = (float*)(ws + 1656320);              // 8*16384 f32  = 524288 B
  float* wsy = (float*)(ws + 2180608);              // 8*16384 f32  = 524288 B
  float* wsz = (float*)(ws + 2704896);              // 8*16384 f32  = 524288 B

  float* centers = (float*)d_out;                   // (8,512,3)
  float* tokens = (float*)d_out + 8 * 512 * 3;      // (8,512,256)

  prep_kernel<<<dim3(128), dim3(256), 0, stream>>>(W1, b1, g1, be1, m1, v1,
                                                   W2, b2, g2, be2, m2, v2, W3,
                                                   w1eff, w2L, t2, w3L);
  fps_kernel<<<dim3(8), dim3(1024), 0, stream>>>(xyz, centers, wsx, wsy, wsz);
  knn_kernel<<<dim3(512), dim3(512), 0, stream>>>(xyz, centers, grouped);
  mlp_kernel<<<dim3(1024), dim3(256), 0, stream>>>(grouped, w2L, w3L, w1eff, t2,
                                                   b3, Wp, bp, centers, tokens);
}

// Round 9
// 1187.513 us; speedup vs baseline: 1.2627x; 1.2011x over previous
//
#include <hip/hip_runtime.h>

typedef unsigned int u32;
typedef unsigned long long u64;
typedef unsigned short u16;

#define DEVFN static __device__ __forceinline__

constexpr int NPTS = 16384;  // points per batch
constexpr int NC = 512;      // centers per batch
// B=8, K=32, FEAT=256

typedef __attribute__((ext_vector_type(8))) short bf16x8;
typedef __attribute__((ext_vector_type(4))) float f32x4;

#define MFMA16(a, b, c) __builtin_amdgcn_mfma_f32_16x16x32_bf16(a, b, c, 0, 0, 0)

DEVFN u16 bf16rne(float f) {
  u32 b = __float_as_uint(f);
  u32 r = (b + 0x7FFFu + ((b >> 16) & 1u)) >> 16;
  return (u16)r;
}

DEVFN u64 shflx64(u64 v, int m) {
  u32 lo = __shfl_xor((u32)v, m, 64);
  u32 hi = __shfl_xor((u32)(v >> 32), m, 64);
  return ((u64)hi << 32) | lo;
}
DEVFN u64 shfl64(u64 v, int src) {
  u32 lo = __shfl((u32)v, src, 64);
  u32 hi = __shfl((u32)(v >> 32), src, 64);
  return ((u64)hi << 32) | lo;
}

DEVFN void csw(u64& a, u64& b) {
  u64 lo = a < b ? a : b;
  u64 hi = a < b ? b : a;
  a = lo; b = hi;
}

DEVFN u32 spread3(u32 v) {  // 4 bits -> bits 0,3,6,9
  return (v & 1u) | ((v & 2u) << 2) | ((v & 4u) << 4) | ((v & 8u) << 6);
}

// ---------------------------------------------------------------------------
// FPS v8: Morton clusters of 64 pts, 4 thr/cluster, 16 pts/thread.
// State: mdkey[16] u64 in REGISTERS (md_bits<<32 | (16383-oidx)<<4 | waveId),
// coords reloaded per active iteration from ws (per-thread interleaved
// 48-float block: 12 dwordx4, L2-hot, one base ptr + imm offsets). Single
// u64-min/max pass. Global argmax via per-wave pre-barrier 4-shfl reduce +
// one LDS atomicMax(u64) into gkey (triple-buffered; reset one epoch ahead).
// Post-barrier: 1 broadcast LDS read (widx in low 4 key bits) + skb row read.
// Exactness: u64 key max == numpy argmax (max md, tie -> lowest oidx; wave
// bits only separate identical points, impossible). Prune = monotone-
// rounding bbox lower bound (skips only provably no-op updates).
// ---------------------------------------------------------------------------
__global__ __launch_bounds__(1024) void fps_kernel(const float* __restrict__ xyz,
                                                   float* __restrict__ centers,
                                                   float* __restrict__ wsp) {
  const int b = blockIdx.x;
  const int t = threadIdx.x;
  const int lane = t & 63;
  const int w = t >> 6;
  const float* xb = xyz + (size_t)b * NPTS * 3;

  __shared__ u32 hist[2048];
  __shared__ u16 soidx[NPTS];
  __shared__ u64 gkeybuf[3];
  __shared__ u32 skb[2][16][4];
  __shared__ float redB[104];
  __shared__ u32 redW[16];

  const u32 inf10 = __float_as_uint(1e10f);

  // ---- setup: global bbox + morton codes ----
  u32 mcode[16];
  {
    float ox[16], oy[16], oz[16];
    float lx = 1e30f, ly = 1e30f, lz = 1e30f;
    float hx = -1e30f, hy = -1e30f, hz = -1e30f;
#pragma unroll
    for (int j = 0; j < 16; ++j) {
      int p = t + j * 1024;
      ox[j] = xb[p * 3 + 0];
      oy[j] = xb[p * 3 + 1];
      oz[j] = xb[p * 3 + 2];
      lx = fminf(lx, ox[j]); hx = fmaxf(hx, ox[j]);
      ly = fminf(ly, oy[j]); hy = fmaxf(hy, oy[j]);
      lz = fminf(lz, oz[j]); hz = fmaxf(hz, oz[j]);
    }
#pragma unroll
    for (int s = 32; s; s >>= 1) {
      lx = fminf(lx, __shfl_xor(lx, s, 64)); hx = fmaxf(hx, __shfl_xor(hx, s, 64));
      ly = fminf(ly, __shfl_xor(ly, s, 64)); hy = fmaxf(hy, __shfl_xor(hy, s, 64));
      lz = fminf(lz, __shfl_xor(lz, s, 64)); hz = fmaxf(hz, __shfl_xor(hz, s, 64));
    }
    if (lane == 0) {
      redB[w * 6 + 0] = lx; redB[w * 6 + 1] = hx;
      redB[w * 6 + 2] = ly; redB[w * 6 + 3] = hy;
      redB[w * 6 + 4] = lz; redB[w * 6 + 5] = hz;
    }
    hist[t] = 0; hist[t + 1024] = 0;
    if (t < 3) gkeybuf[t] = 0ull;
    __syncthreads();
    if (t == 0) {
      float a0 = redB[0], a1 = redB[1], a2 = redB[2], a3 = redB[3], a4 = redB[4], a5 = redB[5];
      for (int q = 1; q < 16; ++q) {
        a0 = fminf(a0, redB[q * 6 + 0]); a1 = fmaxf(a1, redB[q * 6 + 1]);
        a2 = fminf(a2, redB[q * 6 + 2]); a3 = fmaxf(a3, redB[q * 6 + 3]);
        a4 = fminf(a4, redB[q * 6 + 4]); a5 = fmaxf(a5, redB[q * 6 + 5]);
      }
      redB[96] = a0; redB[97] = a1; redB[98] = a2;
      redB[99] = a3; redB[100] = a4; redB[101] = a5;
    }
    __syncthreads();
    const float glx = redB[96], ghx = redB[97];
    const float gly = redB[98], ghy = redB[99];
    const float glz = redB[100], ghz = redB[101];
    const float sx = 15.999f / fmaxf(ghx - glx, 1e-9f);
    const float sy = 15.999f / fmaxf(ghy - gly, 1e-9f);
    const float sz = 7.999f / fmaxf(ghz - glz, 1e-9f);
#pragma unroll
    for (int j = 0; j < 16; ++j) {
      int ix = min(15, max(0, (int)((ox[j] - glx) * sx)));
      int iy = min(15, max(0, (int)((oy[j] - gly) * sy)));
      int iz = min(7, max(0, (int)((oz[j] - glz) * sz)));
      mcode[j] = spread3((u32)ix) | (spread3((u32)iy) << 1) | (spread3((u32)iz) << 2);
    }
  }
  // ---- histogram (2048 bins) ----
#pragma unroll
  for (int j = 0; j < 16; ++j) atomicAdd(&hist[mcode[j]], 1u);
  __syncthreads();
  // ---- exclusive scan over 2048 bins ----
  {
    u32 h0 = hist[t * 2 + 0], h1 = hist[t * 2 + 1];
    u32 s = h0 + h1;
    u32 incl = s;
#pragma unroll
    for (int d = 1; d < 64; d <<= 1) {
      u32 n = __shfl_up(incl, d, 64);
      if (lane >= d) incl += n;
    }
    if (lane == 63) redW[w] = incl;
    __syncthreads();
    if (t == 0) {
      u32 run = 0;
      for (int q = 0; q < 16; ++q) { u32 tmp = redW[q]; redW[q] = run; run += tmp; }
    }
    __syncthreads();
    u32 exc = incl - s + redW[w];
    hist[t * 2 + 0] = exc;
    hist[t * 2 + 1] = exc + h0;
    __syncthreads();
  }
  // ---- scatter: sorted position -> original index ----
#pragma unroll
  for (int j = 0; j < 16; ++j) {
    u32 p = (u32)(t + j * 1024);
    u32 pos = atomicAdd(&hist[mcode[j]], 1u);
    soidx[pos] = (u16)p;
  }
  __syncthreads();
  // ---- gather own 16 sorted pts: write interleaved ws block, init keys ----
  const u32 spbase = (u32)((t >> 2) * 64 + (t & 3) * 16);
  float* wpw = wsp + (size_t)(b * 1024 + t) * 48;
  u64 mdkey[16];
  u32 lomax = 0;
  float bxl = 1e30f, bxh = -1e30f, byl = 1e30f, byh = -1e30f, bzl = 1e30f, bzh = -1e30f;
#pragma unroll
  for (int j = 0; j < 16; ++j) {
    u32 oidx = (u32)soidx[spbase + j];
    float X = xb[oidx * 3 + 0];
    float Y = xb[oidx * 3 + 1];
    float Z = xb[oidx * 3 + 2];
    wpw[j] = X; wpw[16 + j] = Y; wpw[32 + j] = Z;
    u32 lo = ((16383u - oidx) << 4) | (u32)w;
    mdkey[j] = ((u64)inf10 << 32) | lo;
    lomax = max(lomax, lo);
    bxl = fminf(bxl, X); bxh = fmaxf(bxh, X);
    byl = fminf(byl, Y); byh = fmaxf(byh, Y);
    bzl = fminf(bzl, Z); bzh = fmaxf(bzh, Z);
  }
#pragma unroll
  for (int s = 1; s <= 2; s <<= 1) {
    bxl = fminf(bxl, __shfl_xor(bxl, s, 64)); bxh = fmaxf(bxh, __shfl_xor(bxh, s, 64));
    byl = fminf(byl, __shfl_xor(byl, s, 64)); byh = fmaxf(byh, __shfl_xor(byh, s, 64));
    bzl = fminf(bzl, __shfl_xor(bzl, s, 64)); bzh = fmaxf(bzh, __shfl_xor(bzh, s, 64));
    lomax = max(lomax, (u32)__shfl_xor(lomax, s, 64));
  }
  u64 mdmkey = ((u64)inf10 << 32) | lomax;  // cluster max key (group-uniform)
  // laundered read pointer: compiler cannot store-forward the ws writes
  const float* wp = wpw;
  asm("" : "+v"(wp));
  float cx = xb[0], cy = xb[1], cz = xb[2];
  if (t == 0) {
    centers[(b * NC) * 3 + 0] = cx;
    centers[(b * NC) * 3 + 1] = cy;
    centers[(b * NC) * 3 + 2] = cz;
  }

  // ---- main loop: 1 barrier per iteration ----
  for (int i = 1; i < NC; ++i) {
    float ax = fmaxf(0.f, fmaxf(__fsub_rn(bxl, cx), __fsub_rn(cx, bxh)));
    float ay = fmaxf(0.f, fmaxf(__fsub_rn(byl, cy), __fsub_rn(cy, byh)));
    float az = fmaxf(0.f, fmaxf(__fsub_rn(bzl, cz), __fsub_rn(cz, bzh)));
    float dlb = __fadd_rn(__fadd_rn(__fmul_rn(ax, ax), __fmul_rn(ay, ay)), __fmul_rn(az, az));
    if (dlb < __uint_as_float((u32)(mdmkey >> 32))) {  // group-uniform branch
      u64 lmax = 0ull;
#pragma unroll
      for (int j = 0; j < 16; ++j) {
        float dx = __fsub_rn(wp[j], cx);
        float dy = __fsub_rn(wp[16 + j], cy);
        float dz = __fsub_rn(wp[32 + j], cz);
        float d = __fadd_rn(__fadd_rn(__fmul_rn(dx, dx), __fmul_rn(dy, dy)), __fmul_rn(dz, dz));
        u64 nk = ((u64)__float_as_uint(d) << 32) | (u64)(u32)mdkey[j];
        u64 k = nk < mdkey[j] ? nk : mdkey[j];  // md = min(md, d), lo constant
        mdkey[j] = k;
        lmax = k > lmax ? k : lmax;
      }
      u64 o1 = shflx64(lmax, 1); lmax = o1 > lmax ? o1 : lmax;
      u64 o2 = shflx64(lmax, 2); lmax = o2 > lmax ? o2 : lmax;
      mdmkey = lmax;
    }
    u64 wk = mdmkey;  // wave max over 16 clusters (groups uniform -> start at 4)
#pragma unroll
    for (int s = 4; s <= 32; s <<= 1) { u64 o = shflx64(wk, s); wk = o > wk ? o : wk; }
    // wave winner publishes its coords (from its own L2-hot ws block)
#pragma unroll
    for (int j = 0; j < 16; ++j) {
      if (mdkey[j] == wk) {
        skb[i & 1][w][0] = __float_as_uint(wp[j]);
        skb[i & 1][w][1] = __float_as_uint(wp[16 + j]);
        skb[i & 1][w][2] = __float_as_uint(wp[32 + j]);
      }
    }
    if (t == 0) gkeybuf[(i + 1) % 3] = 0ull;  // reset one epoch ahead of use
    if (lane == 0) atomicMax((u64*)&gkeybuf[i % 3], wk);
    __syncthreads();
    u64 g = gkeybuf[i % 3];
    u32 widx = (u32)g & 15u;
    cx = __uint_as_float(skb[i & 1][widx][0]);
    cy = __uint_as_float(skb[i & 1][widx][1]);
    cz = __uint_as_float(skb[i & 1][widx][2]);
    if (t == 0) {
      centers[(b * NC + i) * 3 + 0] = cx;
      centers[(b * NC + i) * 3 + 1] = cy;
      centers[(b * NC + i) * 3 + 2] = cz;
    }
  }
}

// ---------------------------------------------------------------------------
// KNN: 8 waves/block, wave = one center. Exact top-32 set by (d, idx).
// ---------------------------------------------------------------------------
__global__ __launch_bounds__(512) void knn_kernel(const float* __restrict__ xyz,
                                                  const float* __restrict__ centers,
                                                  float* __restrict__ grouped) {
  __shared__ float spts[1024 * 3];
  __shared__ u64 cand[8][192];
  __shared__ int ccnt[8];
  const int t = threadIdx.x;
  const int lane = t & 63;
  const int w = t >> 6;
  const int cg = blockIdx.x * 8 + w;   // global center id
  const int b = cg >> 9;               // / 512
  const float* xb = xyz + (size_t)b * NPTS * 3;
  const float cx = centers[cg * 3 + 0];
  const float cy = centers[cg * 3 + 1];
  const float cz = centers[cg * 3 + 2];
  if (lane == 0) ccnt[w] = 0;

  // phase 1: per-lane min (packed (d,idx))
  u64 lmin = ~0ull;
  for (int ch = 0; ch < 16; ++ch) {
    __syncthreads();
    const float* src = xb + ch * 1024 * 3;
#pragma unroll
    for (int q = 0; q < 6; ++q) spts[q * 512 + t] = src[q * 512 + t];
    __syncthreads();
#pragma unroll
    for (int j = 0; j < 16; ++j) {
      int p = lane + j * 64;
      float dx = __fsub_rn(cx, spts[p * 3 + 0]);
      float dy = __fsub_rn(cy, spts[p * 3 + 1]);
      float dz = __fsub_rn(cz, spts[p * 3 + 2]);
      float d = __fadd_rn(__fadd_rn(__fmul_rn(dx, dx), __fmul_rn(dy, dy)), __fmul_rn(dz, dz));
      u64 kk = ((u64)__float_as_uint(d) << 32) | (u64)(u32)(ch * 1024 + p);
      lmin = kk < lmin ? kk : lmin;
    }
  }
  // bitonic sort (ascending) of 64 lane-minima; tau = 32nd smallest
  u64 v = lmin;
  for (int k = 2; k <= 64; k <<= 1)
    for (int j = k >> 1; j > 0; j >>= 1) {
      u64 o = shflx64(v, j);
      bool up = ((lane & k) == 0);
      bool lowr = ((lane & j) == 0);
      u64 mn = v < o ? v : o;
      u64 mx = v < o ? o : v;
      v = (lowr == up) ? mn : mx;
    }
  u64 tau = shfl64(v, 31);
  float tf = __uint_as_float((u32)(tau >> 32));

  // phase 2: collect candidates d <= tf  (guaranteed >= 32 of them)
  for (int ch = 0; ch < 16; ++ch) {
    __syncthreads();
    const float* src = xb + ch * 1024 * 3;
#pragma unroll
    for (int q = 0; q < 6; ++q) spts[q * 512 + t] = src[q * 512 + t];
    __syncthreads();
#pragma unroll
    for (int j = 0; j < 16; ++j) {
      int p = lane + j * 64;
      float dx = __fsub_rn(cx, spts[p * 3 + 0]);
      float dy = __fsub_rn(cy, spts[p * 3 + 1]);
      float dz = __fsub_rn(cz, spts[p * 3 + 2]);
      float d = __fadd_rn(__fadd_rn(__fmul_rn(dx, dx), __fmul_rn(dy, dy)), __fmul_rn(dz, dz));
      if (d <= tf) {
        int pos = atomicAdd(&ccnt[w], 1);
        if (pos < 192) cand[w][pos] = ((u64)__float_as_uint(d) << 32) | (u64)(u32)(ch * 1024 + p);
      }
    }
  }
  __syncthreads();
  int cnt = ccnt[w];
  u32 myn = 0u;  // lane r (<32) keeps r-th nearest neighbor's index
  if (cnt <= 192) {
    u64 c0 = (lane < cnt) ? cand[w][lane] : ~0ull;
    u64 c1 = (64 + lane < cnt) ? cand[w][64 + lane] : ~0ull;
    u64 c2 = (128 + lane < cnt) ? cand[w][128 + lane] : ~0ull;
    csw(c0, c1); csw(c1, c2); csw(c0, c1);  // c0<=c1<=c2
    for (int r = 0; r < 32; ++r) {
      u64 wm = c0;
      for (int s = 32; s; s >>= 1) {
        u64 o = shflx64(wm, s);
        wm = o < wm ? o : wm;
      }
      if (c0 == wm) { c0 = c1; c1 = c2; c2 = ~0ull; }
      if (lane == r) myn = (u32)wm;
    }
  } else {
    // exact slow fallback (astronomically rare): ascending extraction
    u64 last = 0ull;
    for (int r = 0; r < 32; ++r) {
      u64 bb = ~0ull;
      for (int j = 0; j < 256; ++j) {
        int p = lane + j * 64;
        float dx = __fsub_rn(cx, xb[p * 3 + 0]);
        float dy = __fsub_rn(cy, xb[p * 3 + 1]);
        float dz = __fsub_rn(cz, xb[p * 3 + 2]);
        float d = __fadd_rn(__fadd_rn(__fmul_rn(dx, dx), __fmul_rn(dy, dy)), __fmul_rn(dz, dz));
        u64 kk = ((u64)__float_as_uint(d) << 32) | (u64)(u32)p;
        if (r == 0 || kk > last)
          if (kk < bb) bb = kk;
      }
      for (int s = 32; s; s >>= 1) {
        u64 o = shflx64(bb, s);
        bb = o < bb ? o : bb;
      }
      last = bb;
      if (lane == r) myn = (u32)bb;
    }
  }
  if (lane < 32) {
    const float nx = xb[(size_t)myn * 3 + 0];
    const float ny = xb[(size_t)myn * 3 + 1];
    const float nz = xb[(size_t)myn * 3 + 2];
    float* gp = grouped + ((size_t)cg * 32 + lane) * 3;
    gp[0] = __fsub_rn(nx, cx);
    gp[1] = __fsub_rn(ny, cy);
    gp[2] = __fsub_rn(nz, cz);
  }
}

// ---------------------------------------------------------------------------
// Weight prep: fold eval-BN into weights, bf16 + MFMA-fragment-swizzled
// layouts for W2/W3 so the MLP kernel stages LDS with a linear copy.
// ---------------------------------------------------------------------------
__global__ __launch_bounds__(256) void prep_kernel(
    const float* __restrict__ W1, const float* __restrict__ b1,
    const float* __restrict__ g1, const float* __restrict__ be1,
    const float* __restrict__ m1, const float* __restrict__ v1,
    const float* __restrict__ W2, const float* __restrict__ b2,
    const float* __restrict__ g2, const float* __restrict__ be2,
    const float* __restrict__ m2, const float* __restrict__ v2,
    const float* __restrict__ W3,
    float* __restrict__ w1eff, u16* __restrict__ w2L,
    float* __restrict__ t2, u16* __restrict__ w3L) {
  const int tid = blockIdx.x * 256 + threadIdx.x;  // 128 blocks -> 32768
  if (tid < 64) {
    float s = g1[tid] / sqrtf(v1[tid] + 1e-5f);
    w1eff[tid * 4 + 0] = W1[tid * 3 + 0] * s;
    w1eff[tid * 4 + 1] = W1[tid * 3 + 1] * s;
    w1eff[tid * 4 + 2] = W1[tid * 3 + 2] * s;
    w1eff[tid * 4 + 3] = (b1[tid] - m1[tid]) * s + be1[tid];
  }
  if (tid < 128) {
    float s = g2[tid] / sqrtf(v2[tid] + 1e-5f);
    t2[tid] = (b2[tid] - m2[tid]) * s + be2[tid];
  }
  if (tid < 8192) {  // W2eff (128 out x 64 in), bn-scaled, as B-fragments
    int i = tid & 63, o = tid >> 6;
    float s = g2[o] / sqrtf(v2[o] + 1e-5f);
    int kg = i >> 3, j = i & 7;
    w2L[((((kg * 128) + o) * 8) ^ ((kg & 7) * 8)) + j] = bf16rne(W2[o * 64 + i] * s);
  }
  if (tid < 32768) {  // W3 (256 out x 128 in) as B-fragments, split in col-halves
    int i = tid & 127, o = tid >> 7;
    int kg = i >> 3, j = i & 7;
    int h = o >> 7, colh = o & 127;
    w3L[h * 16384 + ((((kg * 128) + colh) * 8) ^ ((kg & 7) * 8)) + j] = bf16rne(W3[o * 128 + i]);
  }
}

// ---------------------------------------------------------------------------
// MLP: 4 centers (128 rows) per 256-thread block; wave = one center.
// L1 on VALU (K=3), L2/L3 as bf16 MFMA GEMMs; fused max-pool + pos epilogue.
// LDS (64KB): [0,16K)=W2 (later W3 half over [0,32K)); [16K,32K)=H1; [32K,64K)=H2.
// ---------------------------------------------------------------------------
__global__ __launch_bounds__(256) void mlp_kernel(
    const float* __restrict__ grouped, const u16* __restrict__ w2L,
    const u16* __restrict__ w3L, const float* __restrict__ w1eff,
    const float* __restrict__ t2, const float* __restrict__ b3,
    const float* __restrict__ Wp, const float* __restrict__ bp,
    const float* __restrict__ centers, float* __restrict__ tokens) {
  __shared__ char lds[65536];
  const int t = threadIdx.x;
  const int lane = t & 63;
  const int w = t >> 6;
  const int l15 = lane & 15;
  const int lg = lane >> 4;
  const int c0 = blockIdx.x * 4;
  {  // stage W2 -> [0,16K)
    const u32* s = (const u32*)w2L;
    u32* d = (u32*)lds;
#pragma unroll
    for (int q = 0; q < 16; ++q) d[q * 256 + t] = s[q * 256 + t];
  }
  {  // H1 = relu(X @ W1eff^T + b1eff), bf16, swizzled -> [16K,32K)
    const int row = t & 127;
    const int oh = (t >> 7) * 32;
    const int cg = c0 + (row >> 5);
    const float* gp = grouped + ((size_t)cg * 32 + (row & 31)) * 3;
    const float gx = gp[0], gy = gp[1], gz = gp[2];
    u16 hv[32];
#pragma unroll
    for (int o = 0; o < 32; ++o) {
      const float4 wvv = ((const float4*)w1eff)[oh + o];
      float h = fmaxf(0.f, gx * wvv.x + gy * wvv.y + gz * wvv.z + wvv.w);
      hv[o] = bf16rne(h);
    }
#pragma unroll
    for (int c4 = 0; c4 < 4; ++c4) {
      uint4 pk;
      pk.x = (u32)hv[c4 * 8 + 0] | ((u32)hv[c4 * 8 + 1] << 16);
      pk.y = (u32)hv[c4 * 8 + 2] | ((u32)hv[c4 * 8 + 3] << 16);
      pk.z = (u32)hv[c4 * 8 + 4] | ((u32)hv[c4 * 8 + 5] << 16);
      pk.w = (u32)hv[c4 * 8 + 6] | ((u32)hv[c4 * 8 + 7] << 16);
      int byte = row * 128 + oh * 2 + c4 * 16;
      *reinterpret_cast<uint4*>(lds + 16384 + (byte ^ ((row & 7) << 4))) = pk;
    }
  }
  __syncthreads();
  // GEMM2: H2(32x128) = H1(32x64) @ W2eff^T, per wave
  f32x4 acc2[2][8];
#pragma unroll
  for (int m = 0; m < 2; ++m)
#pragma unroll
    for (int n = 0; n < 8; ++n) acc2[m][n] = (f32x4){0.f, 0.f, 0.f, 0.f};
#pragma unroll
  for (int ks = 0; ks < 2; ++ks) {
    bf16x8 a[2];
#pragma unroll
    for (int m = 0; m < 2; ++m) {
      int row = w * 32 + m * 16 + l15;
      int byte = row * 128 + (ks * 32 + lg * 8) * 2;
      a[m] = *reinterpret_cast<const bf16x8*>(lds + 16384 + (byte ^ ((row & 7) << 4)));
    }
    const int kg = ks * 4 + lg;
#pragma unroll
    for (int n = 0; n < 8; ++n) {
      int idx = (((kg * 128) + (n * 16 + l15)) * 8) ^ ((kg & 7) * 8);
      bf16x8 bb = *reinterpret_cast<const bf16x8*>((const u16*)lds + idx);
      acc2[0][n] = MFMA16(a[0], bb, acc2[0][n]);
      acc2[1][n] = MFMA16(a[1], bb, acc2[1][n]);
    }
  }
#pragma unroll
  for (int n = 0; n < 8; ++n) {  // relu(acc + t2) -> H2 bf16 swizzled
    const int col = n * 16 + l15;
    const float t2v = t2[col];
#pragma unroll
    for (int m = 0; m < 2; ++m)
#pragma unroll
      for (int r = 0; r < 4; ++r) {
        float vv = fmaxf(0.f, acc2[m][n][r] + t2v);
        int row = w * 32 + m * 16 + lg * 4 + r;
        int byte = row * 256 + col * 2;
        *reinterpret_cast<u16*>(lds + 32768 + (byte ^ ((row & 7) << 4))) = bf16rne(vv);
      }
  }
  __syncthreads();
  const float ccx = centers[(c0 + w) * 3 + 0];
  const float ccy = centers[(c0 + w) * 3 + 1];
  const float ccz = centers[(c0 + w) * 3 + 2];
  float* tok = tokens + (size_t)(c0 + w) * 256;
  for (int h = 0; h < 2; ++h) {
    {  // stage W3 col-half (32KB) -> [0,32K); H2 at [32K,64K) untouched
      const u32* s = (const u32*)w3L + h * 8192;
      u32* d = (u32*)lds;
#pragma unroll
      for (int q = 0; q < 32; ++q) d[q * 256 + t] = s[q * 256 + t];
    }
    __syncthreads();
    f32x4 acc3[2][8];
#pragma unroll
    for (int m = 0; m < 2; ++m)
#pragma unroll
      for (int n = 0; n < 8; ++n) acc3[m][n] = (f32x4){0.f, 0.f, 0.f, 0.f};
#pragma unroll
    for (int ks = 0; ks < 4; ++ks) {
      bf16x8 a[2];
#pragma unroll
      for (int m = 0; m < 2; ++m) {
        int row = w * 32 + m * 16 + l15;
        int byte = row * 256 + (ks * 32 + lg * 8) * 2;
        a[m] = *reinterpret_cast<const bf16x8*>(lds + 32768 + (byte ^ ((row & 7) << 4)));
      }
      const int kg = ks * 4 + lg;
#pragma unroll
      for (int n = 0; n < 8; ++n) {
        int idx = (((kg * 128) + (n * 16 + l15)) * 8) ^ ((kg & 7) * 8);
        bf16x8 bb = *reinterpret_cast<const bf16x8*>((const u16*)lds + idx);
        acc3[0][n] = MFMA16(a[0], bb, acc3[0][n]);
        acc3[1][n] = MFMA16(a[1], bb, acc3[1][n]);
      }
    }
#pragma unroll
    for (int n = 0; n < 8; ++n) {  // max over 32 neighbors + b3 + pos
      float vmx = acc3[0][n][0];
#pragma unroll
      for (int m = 0; m < 2; ++m)
#pragma unroll
        for (int r = 0; r < 4; ++r) vmx = fmaxf(vmx, acc3[m][n][r]);
      vmx = fmaxf(vmx, __shfl_xor(vmx, 16, 64));
      vmx = fmaxf(vmx, __shfl_xor(vmx, 32, 64));
      const int col = h * 128 + n * 16 + l15;
      if (lane < 16) {
        float pos = Wp[col * 3 + 0] * ccx + Wp[col * 3 + 1] * ccy +
                    Wp[col * 3 + 2] * ccz + bp[col] + b3[col];
        tok[col] = vmx + pos;
      }
    }
    __syncthreads();
  }
}

// ---------------------------------------------------------------------------
extern "C" void kernel_launch(void* const* d_in, const int* in_sizes, int n_in,
                              void* d_out, int out_size, void* d_ws, size_t ws_size,
                              hipStream_t stream) {
  const float* xyz = (const float*)d_in[0];
  const float* W1 = (const float*)d_in[1];
  const float* b1 = (const float*)d_in[2];
  const float* g1 = (const float*)d_in[3];
  const float* be1 = (const float*)d_in[4];
  const float* m1 = (const float*)d_in[5];
  const float* v1 = (const float*)d_in[6];
  const float* W2 = (const float*)d_in[7];
  const float* b2 = (const float*)d_in[8];
  const float* g2 = (const float*)d_in[9];
  const float* be2 = (const float*)d_in[10];
  const float* m2 = (const float*)d_in[11];
  const float* v2 = (const float*)d_in[12];
  const float* W3 = (const float*)d_in[13];
  const float* b3 = (const float*)d_in[14];
  const float* Wp = (const float*)d_in[15];
  const float* bp = (const float*)d_in[16];

  char* ws = (char*)d_ws;
  float* grouped = (float*)ws;                      // 4096*32*3 f32 = 1572864 B
  float* w1eff = (float*)(ws + 1572864);            // 64*4 f32     = 1024 B
  u16* w2L = (u16*)(ws + 1573888);                  // 8192 u16     = 16384 B
  float* t2 = (float*)(ws + 1590272);               // 128 f32      = 512 B
  u16* w3L = (u16*)(ws + 1590784);                  // 32768 u16    = 65536 B
  float* wsp = (float*)(ws + 1656320);              // 8*1024*48 f32 = 1572864 B

  float* centers = (float*)d_out;                   // (8,512,3)
  float* tokens = (float*)d_out + 8 * 512 * 3;      // (8,512,256)

  prep_kernel<<<dim3(128), dim3(256), 0, stream>>>(W1, b1, g1, be1, m1, v1,
                                                   W2, b2, g2, be2, m2, v2, W3,
                                                   w1eff, w2L, t2, w3L);
  fps_kernel<<<dim3(8), dim3(1024), 0, stream>>>(xyz, centers, wsp);
  knn_kernel<<<dim3(512), dim3(512), 0, stream>>>(xyz, centers, grouped);
  mlp_kernel<<<dim3(1024), dim3(256), 0, stream>>>(grouped, w2L, w3L, w1eff, t2,
                                                   b3, Wp, bp, centers, tokens);
}

// Round 10
// 1184.262 us; speedup vs baseline: 1.2661x; 1.0027x over previous
//
#include <hip/hip_runtime.h>

typedef unsigned int u32;
typedef unsigned long long u64;
typedef unsigned short u16;

#define DEVFN static __device__ __forceinline__

constexpr int NPTS = 16384;  // points per batch
constexpr int NC = 512;      // centers per batch
// B=8, K=32, FEAT=256

typedef __attribute__((ext_vector_type(8))) short bf16x8;
typedef __attribute__((ext_vector_type(4))) float f32x4;

#define MFMA16(a, b, c) __builtin_amdgcn_mfma_f32_16x16x32_bf16(a, b, c, 0, 0, 0)

DEVFN u16 bf16rne(float f) {
  u32 b = __float_as_uint(f);
  u32 r = (b + 0x7FFFu + ((b >> 16) & 1u)) >> 16;
  return (u16)r;
}

DEVFN u64 shflx64(u64 v, int m) {
  u32 lo = __shfl_xor((u32)v, m, 64);
  u32 hi = __shfl_xor((u32)(v >> 32), m, 64);
  return ((u64)hi << 32) | lo;
}
DEVFN u64 shfl64(u64 v, int src) {
  u32 lo = __shfl((u32)v, src, 64);
  u32 hi = __shfl((u32)(v >> 32), src, 64);
  return ((u64)hi << 32) | lo;
}

DEVFN void csw(u64& a, u64& b) {
  u64 lo = a < b ? a : b;
  u64 hi = a < b ? b : a;
  a = lo; b = hi;
}

DEVFN u32 spread3(u32 v) {  // 4 bits -> bits 0,3,6,9
  return (v & 1u) | ((v & 2u) << 2) | ((v & 4u) << 4) | ((v & 8u) << 6);
}

// u64 max with a DPP-shifted copy of itself. CTRL: DPP control immediate,
// RM: row mask (rows not written keep OLD = own value -> max is identity).
// VALU-speed (~10-15 cyc) vs shfl_xor's 2 dependent ds_bpermute (~130 cyc).
template <int CTRL, int RM>
DEVFN u64 dppmax64(u64 k) {
  u32 lo = (u32)k, hi = (u32)(k >> 32);
  u32 lo2 = (u32)__builtin_amdgcn_update_dpp((int)lo, (int)lo, CTRL, RM, 0xF, false);
  u32 hi2 = (u32)__builtin_amdgcn_update_dpp((int)hi, (int)hi, CTRL, RM, 0xF, false);
  u64 o = ((u64)hi2 << 32) | lo2;
  return o > k ? o : k;
}

// ---------------------------------------------------------------------------
// FPS v10: v8 skeleton (Morton clusters of 64 pts, 4 thr/cluster, ws coord
// reload, 1 barrier/iter) with ALL cross-lane reduces moved from
// shfl(ds_bpermute) chains to DPP + readlane:
//   cluster max : quad_perm xor1/xor2 (quads == 4-lane groups, exec-uniform)
//   wave max    : row_ror4/8 (values quad-uniform -> full row max) +
//                 row_bcast15/31 -> lane63 -> v_readlane x2 (uniform key)
//   global max  : skeybuf[2][16] double-buffer; post-barrier each lane reads
//                 slot lane&15, ror1/2/4/8 -> all lanes hold the max.
// Winner wave id in key low 4 bits -> skb coords row. atomicMax removed.
// Exactness: u64 key max == numpy argmax (max md, tie -> lowest oidx; wave
// bits only separate distinct points). Prune = monotone-rounding bbox lower
// bound (skips only provably no-op updates).
// ---------------------------------------------------------------------------
__global__ __launch_bounds__(1024) void fps_kernel(const float* __restrict__ xyz,
                                                   float* __restrict__ centers,
                                                   float* __restrict__ wsp) {
  const int b = blockIdx.x;
  const int t = threadIdx.x;
  const int lane = t & 63;
  const int w = t >> 6;
  const float* xb = xyz + (size_t)b * NPTS * 3;

  __shared__ u32 hist[2048];
  __shared__ u16 soidx[NPTS];
  __shared__ u64 skeybuf[2][16];
  __shared__ u32 skb[2][16][4];
  __shared__ float redB[104];
  __shared__ u32 redW[16];

  const u32 inf10 = __float_as_uint(1e10f);

  // ---- setup: global bbox + morton codes ----
  u32 mcode[16];
  {
    float ox[16], oy[16], oz[16];
    float lx = 1e30f, ly = 1e30f, lz = 1e30f;
    float hx = -1e30f, hy = -1e30f, hz = -1e30f;
#pragma unroll
    for (int j = 0; j < 16; ++j) {
      int p = t + j * 1024;
      ox[j] = xb[p * 3 + 0];
      oy[j] = xb[p * 3 + 1];
      oz[j] = xb[p * 3 + 2];
      lx = fminf(lx, ox[j]); hx = fmaxf(hx, ox[j]);
      ly = fminf(ly, oy[j]); hy = fmaxf(hy, oy[j]);
      lz = fminf(lz, oz[j]); hz = fmaxf(hz, oz[j]);
    }
#pragma unroll
    for (int s = 32; s; s >>= 1) {
      lx = fminf(lx, __shfl_xor(lx, s, 64)); hx = fmaxf(hx, __shfl_xor(hx, s, 64));
      ly = fminf(ly, __shfl_xor(ly, s, 64)); hy = fmaxf(hy, __shfl_xor(hy, s, 64));
      lz = fminf(lz, __shfl_xor(lz, s, 64)); hz = fmaxf(hz, __shfl_xor(hz, s, 64));
    }
    if (lane == 0) {
      redB[w * 6 + 0] = lx; redB[w * 6 + 1] = hx;
      redB[w * 6 + 2] = ly; redB[w * 6 + 3] = hy;
      redB[w * 6 + 4] = lz; redB[w * 6 + 5] = hz;
    }
    hist[t] = 0; hist[t + 1024] = 0;
    __syncthreads();
    if (t == 0) {
      float a0 = redB[0], a1 = redB[1], a2 = redB[2], a3 = redB[3], a4 = redB[4], a5 = redB[5];
      for (int q = 1; q < 16; ++q) {
        a0 = fminf(a0, redB[q * 6 + 0]); a1 = fmaxf(a1, redB[q * 6 + 1]);
        a2 = fminf(a2, redB[q * 6 + 2]); a3 = fmaxf(a3, redB[q * 6 + 3]);
        a4 = fminf(a4, redB[q * 6 + 4]); a5 = fmaxf(a5, redB[q * 6 + 5]);
      }
      redB[96] = a0; redB[97] = a1; redB[98] = a2;
      redB[99] = a3; redB[100] = a4; redB[101] = a5;
    }
    __syncthreads();
    const float glx = redB[96], ghx = redB[97];
    const float gly = redB[98], ghy = redB[99];
    const float glz = redB[100], ghz = redB[101];
    const float sx = 15.999f / fmaxf(ghx - glx, 1e-9f);
    const float sy = 15.999f / fmaxf(ghy - gly, 1e-9f);
    const float sz = 7.999f / fmaxf(ghz - glz, 1e-9f);
#pragma unroll
    for (int j = 0; j < 16; ++j) {
      int ix = min(15, max(0, (int)((ox[j] - glx) * sx)));
      int iy = min(15, max(0, (int)((oy[j] - gly) * sy)));
      int iz = min(7, max(0, (int)((oz[j] - glz) * sz)));
      mcode[j] = spread3((u32)ix) | (spread3((u32)iy) << 1) | (spread3((u32)iz) << 2);
    }
  }
  // ---- histogram (2048 bins) ----
#pragma unroll
  for (int j = 0; j < 16; ++j) atomicAdd(&hist[mcode[j]], 1u);
  __syncthreads();
  // ---- exclusive scan over 2048 bins ----
  {
    u32 h0 = hist[t * 2 + 0], h1 = hist[t * 2 + 1];
    u32 s = h0 + h1;
    u32 incl = s;
#pragma unroll
    for (int d = 1; d < 64; d <<= 1) {
      u32 n = __shfl_up(incl, d, 64);
      if (lane >= d) incl += n;
    }
    if (lane == 63) redW[w] = incl;
    __syncthreads();
    if (t == 0) {
      u32 run = 0;
      for (int q = 0; q < 16; ++q) { u32 tmp = redW[q]; redW[q] = run; run += tmp; }
    }
    __syncthreads();
    u32 exc = incl - s + redW[w];
    hist[t * 2 + 0] = exc;
    hist[t * 2 + 1] = exc + h0;
    __syncthreads();
  }
  // ---- scatter: sorted position -> original index ----
#pragma unroll
  for (int j = 0; j < 16; ++j) {
    u32 p = (u32)(t + j * 1024);
    u32 pos = atomicAdd(&hist[mcode[j]], 1u);
    soidx[pos] = (u16)p;
  }
  __syncthreads();
  // ---- gather own 16 sorted pts: write interleaved ws block, init keys ----
  const u32 spbase = (u32)((t >> 2) * 64 + (t & 3) * 16);
  float* wpw = wsp + (size_t)(b * 1024 + t) * 48;
  u64 mdkey[16];
  u32 lomax = 0;
  float bxl = 1e30f, bxh = -1e30f, byl = 1e30f, byh = -1e30f, bzl = 1e30f, bzh = -1e30f;
#pragma unroll
  for (int j = 0; j < 16; ++j) {
    u32 oidx = (u32)soidx[spbase + j];
    float X = xb[oidx * 3 + 0];
    float Y = xb[oidx * 3 + 1];
    float Z = xb[oidx * 3 + 2];
    wpw[j] = X; wpw[16 + j] = Y; wpw[32 + j] = Z;
    u32 lo = ((16383u - oidx) << 4) | (u32)w;
    mdkey[j] = ((u64)inf10 << 32) | lo;
    lomax = max(lomax, lo);
    bxl = fminf(bxl, X); bxh = fmaxf(bxh, X);
    byl = fminf(byl, Y); byh = fmaxf(byh, Y);
    bzl = fminf(bzl, Z); bzh = fmaxf(bzh, Z);
  }
#pragma unroll
  for (int s = 1; s <= 2; s <<= 1) {
    bxl = fminf(bxl, __shfl_xor(bxl, s, 64)); bxh = fmaxf(bxh, __shfl_xor(bxh, s, 64));
    byl = fminf(byl, __shfl_xor(byl, s, 64)); byh = fmaxf(byh, __shfl_xor(byh, s, 64));
    bzl = fminf(bzl, __shfl_xor(bzl, s, 64)); bzh = fmaxf(bzh, __shfl_xor(bzh, s, 64));
    lomax = max(lomax, (u32)__shfl_xor(lomax, s, 64));
  }
  u64 mdmkey = ((u64)inf10 << 32) | lomax;  // cluster max key (group-uniform)
  // laundered read pointer: compiler cannot store-forward the ws writes
  const float* wp = wpw;
  asm("" : "+v"(wp));
  float cx = xb[0], cy = xb[1], cz = xb[2];
  if (t == 0) {
    centers[(b * NC) * 3 + 0] = cx;
    centers[(b * NC) * 3 + 1] = cy;
    centers[(b * NC) * 3 + 2] = cz;
  }

  // ---- main loop: 1 barrier per iteration ----
  for (int i = 1; i < NC; ++i) {
    float ax = fmaxf(0.f, fmaxf(__fsub_rn(bxl, cx), __fsub_rn(cx, bxh)));
    float ay = fmaxf(0.f, fmaxf(__fsub_rn(byl, cy), __fsub_rn(cy, byh)));
    float az = fmaxf(0.f, fmaxf(__fsub_rn(bzl, cz), __fsub_rn(cz, bzh)));
    float dlb = __fadd_rn(__fadd_rn(__fmul_rn(ax, ax), __fmul_rn(ay, ay)), __fmul_rn(az, az));
    if (dlb < __uint_as_float((u32)(mdmkey >> 32))) {  // group-uniform branch
      u64 lmax = 0ull;
#pragma unroll
      for (int j = 0; j < 16; ++j) {
        float dx = __fsub_rn(wp[j], cx);
        float dy = __fsub_rn(wp[16 + j], cy);
        float dz = __fsub_rn(wp[32 + j], cz);
        float d = __fadd_rn(__fadd_rn(__fmul_rn(dx, dx), __fmul_rn(dy, dy)), __fmul_rn(dz, dz));
        u64 nk = ((u64)__float_as_uint(d) << 32) | (u64)(u32)mdkey[j];
        u64 k = nk < mdkey[j] ? nk : mdkey[j];  // md = min(md, d), lo constant
        mdkey[j] = k;
        lmax = k > lmax ? k : lmax;
      }
      // group (quad) max via DPP: quads are exec-uniform here
      lmax = dppmax64<0xB1, 0xF>(lmax);  // quad_perm xor1
      lmax = dppmax64<0x4E, 0xF>(lmax);  // quad_perm xor2
      mdmkey = lmax;
    }
    // wave max over 16 quad-uniform clusters: row rotations + row bcasts
    u64 wkv = mdmkey;
    wkv = dppmax64<0x124, 0xF>(wkv);  // row_ror:4
    wkv = dppmax64<0x128, 0xF>(wkv);  // row_ror:8  -> full row max (quad-uniform)
    wkv = dppmax64<0x142, 0xA>(wkv);  // row_bcast15 -> rows 1,3
    wkv = dppmax64<0x143, 0xC>(wkv);  // row_bcast31 -> rows 2,3; lane63 = wave max
    u32 wlo = (u32)__builtin_amdgcn_readlane((int)(u32)wkv, 63);
    u32 whi = (u32)__builtin_amdgcn_readlane((int)(u32)(wkv >> 32), 63);
    u64 wkey = ((u64)whi << 32) | wlo;
    // winner wave publishes its coords (from its own L1/L2-hot ws block)
    if (mdmkey == wkey) {
#pragma unroll
      for (int j = 0; j < 16; ++j) {
        if (mdkey[j] == wkey) {
          skb[i & 1][w][0] = __float_as_uint(wp[j]);
          skb[i & 1][w][1] = __float_as_uint(wp[16 + j]);
          skb[i & 1][w][2] = __float_as_uint(wp[32 + j]);
        }
      }
    }
    if (lane == 0) skeybuf[i & 1][w] = wkey;
    __syncthreads();
    // global max over the 16 wave keys: LDS read + 4 DPP rotations
    u64 g = skeybuf[i & 1][lane & 15];
    g = dppmax64<0x121, 0xF>(g);  // ror1
    g = dppmax64<0x122, 0xF>(g);  // ror2
    g = dppmax64<0x124, 0xF>(g);  // ror4
    g = dppmax64<0x128, 0xF>(g);  // ror8 -> all lanes hold global max
    u32 widx = (u32)g & 15u;      // wave id lives in key low 4 bits
    cx = __uint_as_float(skb[i & 1][widx][0]);
    cy = __uint_as_float(skb[i & 1][widx][1]);
    cz = __uint_as_float(skb[i & 1][widx][2]);
    if (t == 0) {
      centers[(b * NC + i) * 3 + 0] = cx;
      centers[(b * NC + i) * 3 + 1] = cy;
      centers[(b * NC + i) * 3 + 2] = cz;
    }
  }
}

// ---------------------------------------------------------------------------
// KNN: 8 waves/block, wave = one center. Exact top-32 set by (d, idx).
// ---------------------------------------------------------------------------
__global__ __launch_bounds__(512) void knn_kernel(const float* __restrict__ xyz,
                                                  const float* __restrict__ centers,
                                                  float* __restrict__ grouped) {
  __shared__ float spts[1024 * 3];
  __shared__ u64 cand[8][192];
  __shared__ int ccnt[8];
  const int t = threadIdx.x;
  const int lane = t & 63;
  const int w = t >> 6;
  const int cg = blockIdx.x * 8 + w;   // global center id
  const int b = cg >> 9;               // / 512
  const float* xb = xyz + (size_t)b * NPTS * 3;
  const float cx = centers[cg * 3 + 0];
  const float cy = centers[cg * 3 + 1];
  const float cz = centers[cg * 3 + 2];
  if (lane == 0) ccnt[w] = 0;

  // phase 1: per-lane min (packed (d,idx))
  u64 lmin = ~0ull;
  for (int ch = 0; ch < 16; ++ch) {
    __syncthreads();
    const float* src = xb + ch * 1024 * 3;
#pragma unroll
    for (int q = 0; q < 6; ++q) spts[q * 512 + t] = src[q * 512 + t];
    __syncthreads();
#pragma unroll
    for (int j = 0; j < 16; ++j) {
      int p = lane + j * 64;
      float dx = __fsub_rn(cx, spts[p * 3 + 0]);
      float dy = __fsub_rn(cy, spts[p * 3 + 1]);
      float dz = __fsub_rn(cz, spts[p * 3 + 2]);
      float d = __fadd_rn(__fadd_rn(__fmul_rn(dx, dx), __fmul_rn(dy, dy)), __fmul_rn(dz, dz));
      u64 kk = ((u64)__float_as_uint(d) << 32) | (u64)(u32)(ch * 1024 + p);
      lmin = kk < lmin ? kk : lmin;
    }
  }
  // bitonic sort (ascending) of 64 lane-minima; tau = 32nd smallest
  u64 v = lmin;
  for (int k = 2; k <= 64; k <<= 1)
    for (int j = k >> 1; j > 0; j >>= 1) {
      u64 o = shflx64(v, j);
      bool up = ((lane & k) == 0);
      bool lowr = ((lane & j) == 0);
      u64 mn = v < o ? v : o;
      u64 mx = v < o ? o : v;
      v = (lowr == up) ? mn : mx;
    }
  u64 tau = shfl64(v, 31);
  float tf = __uint_as_float((u32)(tau >> 32));

  // phase 2: collect candidates d <= tf  (guaranteed >= 32 of them)
  for (int ch = 0; ch < 16; ++ch) {
    __syncthreads();
    const float* src = xb + ch * 1024 * 3;
#pragma unroll
    for (int q = 0; q < 6; ++q) spts[q * 512 + t] = src[q * 512 + t];
    __syncthreads();
#pragma unroll
    for (int j = 0; j < 16; ++j) {
      int p = lane + j * 64;
      float dx = __fsub_rn(cx, spts[p * 3 + 0]);
      float dy = __fsub_rn(cy, spts[p * 3 + 1]);
      float dz = __fsub_rn(cz, spts[p * 3 + 2]);
      float d = __fadd_rn(__fadd_rn(__fmul_rn(dx, dx), __fmul_rn(dy, dy)), __fmul_rn(dz, dz));
      if (d <= tf) {
        int pos = atomicAdd(&ccnt[w], 1);
        if (pos < 192) cand[w][pos] = ((u64)__float_as_uint(d) << 32) | (u64)(u32)(ch * 1024 + p);
      }
    }
  }
  __syncthreads();
  int cnt = ccnt[w];
  u32 myn = 0u;  // lane r (<32) keeps r-th nearest neighbor's index
  if (cnt <= 192) {
    u64 c0 = (lane < cnt) ? cand[w][lane] : ~0ull;
    u64 c1 = (64 + lane < cnt) ? cand[w][64 + lane] : ~0ull;
    u64 c2 = (128 + lane < cnt) ? cand[w][128 + lane] : ~0ull;
    csw(c0, c1); csw(c1, c2); csw(c0, c1);  // c0<=c1<=c2
    for (int r = 0; r < 32; ++r) {
      u64 wm = c0;
      for (int s = 32; s; s >>= 1) {
        u64 o = shflx64(wm, s);
        wm = o < wm ? o : wm;
      }
      if (c0 == wm) { c0 = c1; c1 = c2; c2 = ~0ull; }
      if (lane == r) myn = (u32)wm;
    }
  } else {
    // exact slow fallback (astronomically rare): ascending extraction
    u64 last = 0ull;
    for (int r = 0; r < 32; ++r) {
      u64 bb = ~0ull;
      for (int j = 0; j < 256; ++j) {
        int p = lane + j * 64;
        float dx = __fsub_rn(cx, xb[p * 3 + 0]);
        float dy = __fsub_rn(cy, xb[p * 3 + 1]);
        float dz = __fsub_rn(cz, xb[p * 3 + 2]);
        float d = __fadd_rn(__fadd_rn(__fmul_rn(dx, dx), __fmul_rn(dy, dy)), __fmul_rn(dz, dz));
        u64 kk = ((u64)__float_as_uint(d) << 32) | (u64)(u32)p;
        if (r == 0 || kk > last)
          if (kk < bb) bb = kk;
      }
      for (int s = 32; s; s >>= 1) {
        u64 o = shflx64(bb, s);
        bb = o < bb ? o : bb;
      }
      last = bb;
      if (lane == r) myn = (u32)bb;
    }
  }
  if (lane < 32) {
    const float nx = xb[(size_t)myn * 3 + 0];
    const float ny = xb[(size_t)myn * 3 + 1];
    const float nz = xb[(size_t)myn * 3 + 2];
    float* gp = grouped + ((size_t)cg * 32 + lane) * 3;
    gp[0] = __fsub_rn(nx, cx);
    gp[1] = __fsub_rn(ny, cy);
    gp[2] = __fsub_rn(nz, cz);
  }
}

// ---------------------------------------------------------------------------
// Weight prep: fold eval-BN into weights, bf16 + MFMA-fragment-swizzled
// layouts for W2/W3 so the MLP kernel stages LDS with a linear copy.
// ---------------------------------------------------------------------------
__global__ __launch_bounds__(256) void prep_kernel(
    const float* __restrict__ W1, const float* __restrict__ b1,
    const float* __restrict__ g1, const float* __restrict__ be1,
    const float* __restrict__ m1, const float* __restrict__ v1,
    const float* __restrict__ W2, const float* __restrict__ b2,
    const float* __restrict__ g2, const float* __restrict__ be2,
    const float* __restrict__ m2, const float* __restrict__ v2,
    const float* __restrict__ W3,
    float* __restrict__ w1eff, u16* __restrict__ w2L,
    float* __restrict__ t2, u16* __restrict__ w3L) {
  const int tid = blockIdx.x * 256 + threadIdx.x;  // 128 blocks -> 32768
  if (tid < 64) {
    float s = g1[tid] / sqrtf(v1[tid] + 1e-5f);
    w1eff[tid * 4 + 0] = W1[tid * 3 + 0] * s;
    w1eff[tid * 4 + 1] = W1[tid * 3 + 1] * s;
    w1eff[tid * 4 + 2] = W1[tid * 3 + 2] * s;
    w1eff[tid * 4 + 3] = (b1[tid] - m1[tid]) * s + be1[tid];
  }
  if (tid < 128) {
    float s = g2[tid] / sqrtf(v2[tid] + 1e-5f);
    t2[tid] = (b2[tid] - m2[tid]) * s + be2[tid];
  }
  if (tid < 8192) {  // W2eff (128 out x 64 in), bn-scaled, as B-fragments
    int i = tid & 63, o = tid >> 6;
    float s = g2[o] / sqrtf(v2[o] + 1e-5f);
    int kg = i >> 3, j = i & 7;
    w2L[((((kg * 128) + o) * 8) ^ ((kg & 7) * 8)) + j] = bf16rne(W2[o * 64 + i] * s);
  }
  if (tid < 32768) {  // W3 (256 out x 128 in) as B-fragments, split in col-halves
    int i = tid & 127, o = tid >> 7;
    int kg = i >> 3, j = i & 7;
    int h = o >> 7, colh = o & 127;
    w3L[h * 16384 + ((((kg * 128) + colh) * 8) ^ ((kg & 7) * 8)) + j] = bf16rne(W3[o * 128 + i]);
  }
}

// ---------------------------------------------------------------------------
// MLP: 4 centers (128 rows) per 256-thread block; wave = one center.
// L1 on VALU (K=3), L2/L3 as bf16 MFMA GEMMs; fused max-pool + pos epilogue.
// LDS (64KB): [0,16K)=W2 (later W3 half over [0,32K)); [16K,32K)=H1; [32K,64K)=H2.
// ---------------------------------------------------------------------------
__global__ __launch_bounds__(256) void mlp_kernel(
    const float* __restrict__ grouped, const u16* __restrict__ w2L,
    const u16* __restrict__ w3L, const float* __restrict__ w1eff,
    const float* __restrict__ t2, const float* __restrict__ b3,
    const float* __restrict__ Wp, const float* __restrict__ bp,
    const float* __restrict__ centers, float* __restrict__ tokens) {
  __shared__ char lds[65536];
  const int t = threadIdx.x;
  const int lane = t & 63;
  const int w = t >> 6;
  const int l15 = lane & 15;
  const int lg = lane >> 4;
  const int c0 = blockIdx.x * 4;
  {  // stage W2 -> [0,16K)
    const u32* s = (const u32*)w2L;
    u32* d = (u32*)lds;
#pragma unroll
    for (int q = 0; q < 16; ++q) d[q * 256 + t] = s[q * 256 + t];
  }
  {  // H1 = relu(X @ W1eff^T + b1eff), bf16, swizzled -> [16K,32K)
    const int row = t & 127;
    const int oh = (t >> 7) * 32;
    const int cg = c0 + (row >> 5);
    const float* gp = grouped + ((size_t)cg * 32 + (row & 31)) * 3;
    const float gx = gp[0], gy = gp[1], gz = gp[2];
    u16 hv[32];
#pragma unroll
    for (int o = 0; o < 32; ++o) {
      const float4 wvv = ((const float4*)w1eff)[oh + o];
      float h = fmaxf(0.f, gx * wvv.x + gy * wvv.y + gz * wvv.z + wvv.w);
      hv[o] = bf16rne(h);
    }
#pragma unroll
    for (int c4 = 0; c4 < 4; ++c4) {
      uint4 pk;
      pk.x = (u32)hv[c4 * 8 + 0] | ((u32)hv[c4 * 8 + 1] << 16);
      pk.y = (u32)hv[c4 * 8 + 2] | ((u32)hv[c4 * 8 + 3] << 16);
      pk.z = (u32)hv[c4 * 8 + 4] | ((u32)hv[c4 * 8 + 5] << 16);
      pk.w = (u32)hv[c4 * 8 + 6] | ((u32)hv[c4 * 8 + 7] << 16);
      int byte = row * 128 + oh * 2 + c4 * 16;
      *reinterpret_cast<uint4*>(lds + 16384 + (byte ^ ((row & 7) << 4))) = pk;
    }
  }
  __syncthreads();
  // GEMM2: H2(32x128) = H1(32x64) @ W2eff^T, per wave
  f32x4 acc2[2][8];
#pragma unroll
  for (int m = 0; m < 2; ++m)
#pragma unroll
    for (int n = 0; n < 8; ++n) acc2[m][n] = (f32x4){0.f, 0.f, 0.f, 0.f};
#pragma unroll
  for (int ks = 0; ks < 2; ++ks) {
    bf16x8 a[2];
#pragma unroll
    for (int m = 0; m < 2; ++m) {
      int row = w * 32 + m * 16 + l15;
      int byte = row * 128 + (ks * 32 + lg * 8) * 2;
      a[m] = *reinterpret_cast<const bf16x8*>(lds + 16384 + (byte ^ ((row & 7) << 4)));
    }
    const int kg = ks * 4 + lg;
#pragma unroll
    for (int n = 0; n < 8; ++n) {
      int idx = (((kg * 128) + (n * 16 + l15)) * 8) ^ ((kg & 7) * 8);
      bf16x8 bb = *reinterpret_cast<const bf16x8*>((const u16*)lds + idx);
      acc2[0][n] = MFMA16(a[0], bb, acc2[0][n]);
      acc2[1][n] = MFMA16(a[1], bb, acc2[1][n]);
    }
  }
#pragma unroll
  for (int n = 0; n < 8; ++n) {  // relu(acc + t2) -> H2 bf16 swizzled
    const int col = n * 16 + l15;
    const float t2v = t2[col];
#pragma unroll
    for (int m = 0; m < 2; ++m)
#pragma unroll
      for (int r = 0; r < 4; ++r) {
        float vv = fmaxf(0.f, acc2[m][n][r] + t2v);
        int row = w * 32 + m * 16 + lg * 4 + r;
        int byte = row * 256 + col * 2;
        *reinterpret_cast<u16*>(lds + 32768 + (byte ^ ((row & 7) << 4))) = bf16rne(vv);
      }
  }
  __syncthreads();
  const float ccx = centers[(c0 + w) * 3 + 0];
  const float ccy = centers[(c0 + w) * 3 + 1];
  const float ccz = centers[(c0 + w) * 3 + 2];
  float* tok = tokens + (size_t)(c0 + w) * 256;
  for (int h = 0; h < 2; ++h) {
    {  // stage W3 col-half (32KB) -> [0,32K); H2 at [32K,64K) untouched
      const u32* s = (const u32*)w3L + h * 8192;
      u32* d = (u32*)lds;
#pragma unroll
      for (int q = 0; q < 32; ++q) d[q * 256 + t] = s[q * 256 + t];
    }
    __syncthreads();
    f32x4 acc3[2][8];
#pragma unroll
    for (int m = 0; m < 2; ++m)
#pragma unroll
      for (int n = 0; n < 8; ++n) acc3[m][n] = (f32x4){0.f, 0.f, 0.f, 0.f};
#pragma unroll
    for (int ks = 0; ks < 4; ++ks) {
      bf16x8 a[2];
#pragma unroll
      for (int m = 0; m < 2; ++m) {
        int row = w * 32 + m * 16 + l15;
        int byte = row * 256 + (ks * 32 + lg * 8) * 2;
        a[m] = *reinterpret_cast<const bf16x8*>(lds + 32768 + (byte ^ ((row & 7) << 4)));
      }
      const int kg = ks * 4 + lg;
#pragma unroll
      for (int n = 0; n < 8; ++n) {
        int idx = (((kg * 128) + (n * 16 + l15)) * 8) ^ ((kg & 7) * 8);
        bf16x8 bb = *reinterpret_cast<const bf16x8*>((const u16*)lds + idx);
        acc3[0][n] = MFMA16(a[0], bb, acc3[0][n]);
        acc3[1][n] = MFMA16(a[1], bb, acc3[1][n]);
      }
    }
#pragma unroll
    for (int n = 0; n < 8; ++n) {  // max over 32 neighbors + b3 + pos
      float vmx = acc3[0][n][0];
#pragma unroll
      for (int m = 0; m < 2; ++m)
#pragma unroll
        for (int r = 0; r < 4; ++r) vmx = fmaxf(vmx, acc3[m][n][r]);
      vmx = fmaxf(vmx, __shfl_xor(vmx, 16, 64));
      vmx = fmaxf(vmx, __shfl_xor(vmx, 32, 64));
      const int col = h * 128 + n * 16 + l15;
      if (lane < 16) {
        float pos = Wp[col * 3 + 0] * ccx + Wp[col * 3 + 1] * ccy +
                    Wp[col * 3 + 2] * ccz + bp[col] + b3[col];
        tok[col] = vmx + pos;
      }
    }
    __syncthreads();
  }
}

// ---------------------------------------------------------------------------
extern "C" void kernel_launch(void* const* d_in, const int* in_sizes, int n_in,
                              void* d_out, int out_size, void* d_ws, size_t ws_size,
                              hipStream_t stream) {
  const float* xyz = (const float*)d_in[0];
  const float* W1 = (const float*)d_in[1];
  const float* b1 = (const float*)d_in[2];
  const float* g1 = (const float*)d_in[3];
  const float* be1 = (const float*)d_in[4];
  const float* m1 = (const float*)d_in[5];
  const float* v1 = (const float*)d_in[6];
  const float* W2 = (const float*)d_in[7];
  const float* b2 = (const float*)d_in[8];
  const float* g2 = (const float*)d_in[9];
  const float* be2 = (const float*)d_in[10];
  const float* m2 = (const float*)d_in[11];
  const float* v2 = (const float*)d_in[12];
  const float* W3 = (const float*)d_in[13];
  const float* b3 = (const float*)d_in[14];
  const float* Wp = (const float*)d_in[15];
  const float* bp = (const float*)d_in[16];

  char* ws = (char*)d_ws;
  float* grouped = (float*)ws;                      // 4096*32*3 f32 = 1572864 B
  float* w1eff = (float*)(ws + 1572864);            // 64*4 f32     = 1024 B
  u16* w2L = (u16*)(ws + 1573888);                  // 8192 u16     = 16384 B
  float* t2 = (float*)(ws + 1590272);               // 128 f32      = 512 B
  u16* w3L = (u16*)(ws + 1590784);                  // 32768 u16    = 65536 B
  float* wsp = (float*)(ws + 1656320);              // 8*1024*48 f32 = 1572864 B

  float* centers = (float*)d_out;                   // (8,512,3)
  float* tokens = (float*)d_out + 8 * 512 * 3;      // (8,512,256)

  prep_kernel<<<dim3(128), dim3(256), 0, stream>>>(W1, b1, g1, be1, m1, v1,
                                                   W2, b2, g2, be2, m2, v2, W3,
                                                   w1eff, w2L, t2, w3L);
  fps_kernel<<<dim3(8), dim3(1024), 0, stream>>>(xyz, centers, wsp);
  knn_kernel<<<dim3(512), dim3(512), 0, stream>>>(xyz, centers, grouped);
  mlp_kernel<<<dim3(1024), dim3(256), 0, stream>>>(grouped, w2L, w3L, w1eff, t2,
                                                   b3, Wp, bp, centers, tokens);
}

// Round 11
// 844.694 us; speedup vs baseline: 1.7751x; 1.4020x over previous
//
#include <hip/hip_runtime.h>

typedef unsigned int u32;
typedef unsigned long long u64;
typedef unsigned short u16;

#define DEVFN static __device__ __forceinline__

constexpr int NPTS = 16384;  // points per batch
constexpr int NC = 512;      // centers per batch
// B=8, K=32, FEAT=256

typedef __attribute__((ext_vector_type(8))) short bf16x8;
typedef __attribute__((ext_vector_type(4))) float f32x4;

#define MFMA16(a, b, c) __builtin_amdgcn_mfma_f32_16x16x32_bf16(a, b, c, 0, 0, 0)

DEVFN u16 bf16rne(float f) {
  u32 b = __float_as_uint(f);
  u32 r = (b + 0x7FFFu + ((b >> 16) & 1u)) >> 16;
  return (u16)r;
}

DEVFN u64 shflx64(u64 v, int m) {
  u32 lo = __shfl_xor((u32)v, m, 64);
  u32 hi = __shfl_xor((u32)(v >> 32), m, 64);
  return ((u64)hi << 32) | lo;
}
DEVFN u64 shfl64(u64 v, int src) {
  u32 lo = __shfl((u32)v, src, 64);
  u32 hi = __shfl((u32)(v >> 32), src, 64);
  return ((u64)hi << 32) | lo;
}

DEVFN void csw(u64& a, u64& b) {
  u64 lo = a < b ? a : b;
  u64 hi = a < b ? b : a;
  a = lo; b = hi;
}

DEVFN u32 spread3(u32 v) {  // 4 bits -> bits 0,3,6,9
  return (v & 1u) | ((v & 2u) << 2) | ((v & 4u) << 4) | ((v & 8u) << 6);
}

// u64 max with a DPP-shifted copy of itself (VALU-speed cross-lane).
template <int CTRL, int RM>
DEVFN u64 dppmax64(u64 k) {
  u32 lo = (u32)k, hi = (u32)(k >> 32);
  u32 lo2 = (u32)__builtin_amdgcn_update_dpp((int)lo, (int)lo, CTRL, RM, 0xF, false);
  u32 hi2 = (u32)__builtin_amdgcn_update_dpp((int)hi, (int)hi, CTRL, RM, 0xF, false);
  u64 o = ((u64)hi2 << 32) | lo2;
  return o > k ? o : k;
}
// full 64-lane max -> lane 63 holds result (ror1/2/4/8 -> row max; bcasts merge rows)
DEVFN u64 wavemax64(u64 k) {
  k = dppmax64<0x121, 0xF>(k);
  k = dppmax64<0x122, 0xF>(k);
  k = dppmax64<0x124, 0xF>(k);
  k = dppmax64<0x128, 0xF>(k);
  k = dppmax64<0x142, 0xA>(k);  // row_bcast15 -> rows 1,3
  k = dppmax64<0x143, 0xC>(k);  // row_bcast31 -> rows 2,3
  return k;
}

// ---------------------------------------------------------------------------
// FPS v11: worklist compaction. md state in LDS (f32/point), ckey[256] u64 in
// LDS. Per iteration: Phase A (t<256) bbox-prune -> active clusters pushed to
// a double-buffered worklist (LDS atomicAdd); Phase B: active clusters spread
// over 16 waves, 1 cluster = 64 pts = 1 pt/lane, coalesced SoA loads, md
// update in LDS, DPP wave-max -> ckey; Phase C (redundant/wave): max over
// ckey[256] -> winner oidx -> uniform xyz load. 2 barriers/iter. Issued work
// scales with active clusters, not total points (exec-mask saves lanes, not
// issue slots -- the r10 lesson).
// Exactness: key = md_bits<<32 | (16383-oidx); u64 max == numpy argmax (max
// md, tie -> lowest original index). Distances use the same rounded-op shape
// as numpy; prune = monotone-rounding bbox lower bound (skips only provably
// no-op updates).
// ---------------------------------------------------------------------------
__global__ __launch_bounds__(1024) void fps_kernel(const float* __restrict__ xyz,
                                                   float* __restrict__ centers,
                                                   float* __restrict__ wsX,
                                                   float* __restrict__ wsY,
                                                   float* __restrict__ wsZ,
                                                   u16* __restrict__ wsO) {
  const int b = blockIdx.x;
  const int t = threadIdx.x;
  const int lane = t & 63;
  const int w = t >> 6;
  const float* xb = xyz + (size_t)b * NPTS * 3;
  const int bo = b * NPTS;

  __shared__ char smem[75776];
  float* mdL = (float*)smem;                 // [0, 64K)  md per sorted point
  u64* ckeyL = (u64*)(smem + 65536);         // [64K, +2K) per-cluster max key
  float* bboxT = (float*)(smem + 67584);     // [6][256] transposed bboxes
  u16* wl = (u16*)(smem + 73728);            // [2][256] worklist
  u32* wcnt = (u32*)(smem + 74752);          // [2] counters
  float* redB = (float*)(smem + 74768);      // 104 f32
  u32* redW = (u32*)(smem + 75200);          // 16 u32
  u32* hist = (u32*)smem;                    // setup alias [0, 8K)
  u16* soidx = (u16*)(smem + 8192);          // setup alias [8K, 40K)

  const u32 inf10 = __float_as_uint(1e10f);

  // ---- setup: global bbox + morton codes ----
  u32 mcode[16];
  {
    float ox[16], oy[16], oz[16];
    float lx = 1e30f, ly = 1e30f, lz = 1e30f;
    float hx = -1e30f, hy = -1e30f, hz = -1e30f;
#pragma unroll
    for (int j = 0; j < 16; ++j) {
      int p = t + j * 1024;
      ox[j] = xb[p * 3 + 0];
      oy[j] = xb[p * 3 + 1];
      oz[j] = xb[p * 3 + 2];
      lx = fminf(lx, ox[j]); hx = fmaxf(hx, ox[j]);
      ly = fminf(ly, oy[j]); hy = fmaxf(hy, oy[j]);
      lz = fminf(lz, oz[j]); hz = fmaxf(hz, oz[j]);
    }
#pragma unroll
    for (int s = 32; s; s >>= 1) {
      lx = fminf(lx, __shfl_xor(lx, s, 64)); hx = fmaxf(hx, __shfl_xor(hx, s, 64));
      ly = fminf(ly, __shfl_xor(ly, s, 64)); hy = fmaxf(hy, __shfl_xor(hy, s, 64));
      lz = fminf(lz, __shfl_xor(lz, s, 64)); hz = fmaxf(hz, __shfl_xor(hz, s, 64));
    }
    if (lane == 0) {
      redB[w * 6 + 0] = lx; redB[w * 6 + 1] = hx;
      redB[w * 6 + 2] = ly; redB[w * 6 + 3] = hy;
      redB[w * 6 + 4] = lz; redB[w * 6 + 5] = hz;
    }
    hist[t] = 0; hist[t + 1024] = 0;
    if (t < 2) wcnt[t] = 0;
    __syncthreads();
    if (t == 0) {
      float a0 = redB[0], a1 = redB[1], a2 = redB[2], a3 = redB[3], a4 = redB[4], a5 = redB[5];
      for (int q = 1; q < 16; ++q) {
        a0 = fminf(a0, redB[q * 6 + 0]); a1 = fmaxf(a1, redB[q * 6 + 1]);
        a2 = fminf(a2, redB[q * 6 + 2]); a3 = fmaxf(a3, redB[q * 6 + 3]);
        a4 = fminf(a4, redB[q * 6 + 4]); a5 = fmaxf(a5, redB[q * 6 + 5]);
      }
      redB[96] = a0; redB[97] = a1; redB[98] = a2;
      redB[99] = a3; redB[100] = a4; redB[101] = a5;
    }
    __syncthreads();
    const float glx = redB[96], ghx = redB[97];
    const float gly = redB[98], ghy = redB[99];
    const float glz = redB[100], ghz = redB[101];
    const float sx = 15.999f / fmaxf(ghx - glx, 1e-9f);
    const float sy = 15.999f / fmaxf(ghy - gly, 1e-9f);
    const float sz = 7.999f / fmaxf(ghz - glz, 1e-9f);
#pragma unroll
    for (int j = 0; j < 16; ++j) {
      int ix = min(15, max(0, (int)((ox[j] - glx) * sx)));
      int iy = min(15, max(0, (int)((oy[j] - gly) * sy)));
      int iz = min(7, max(0, (int)((oz[j] - glz) * sz)));
      mcode[j] = spread3((u32)ix) | (spread3((u32)iy) << 1) | (spread3((u32)iz) << 2);
    }
  }
  // ---- histogram (2048 bins) ----
#pragma unroll
  for (int j = 0; j < 16; ++j) atomicAdd(&hist[mcode[j]], 1u);
  __syncthreads();
  // ---- exclusive scan over 2048 bins ----
  {
    u32 h0 = hist[t * 2 + 0], h1 = hist[t * 2 + 1];
    u32 s = h0 + h1;
    u32 incl = s;
#pragma unroll
    for (int d = 1; d < 64; d <<= 1) {
      u32 n = __shfl_up(incl, d, 64);
      if (lane >= d) incl += n;
    }
    if (lane == 63) redW[w] = incl;
    __syncthreads();
    if (t == 0) {
      u32 run = 0;
      for (int q = 0; q < 16; ++q) { u32 tmp = redW[q]; redW[q] = run; run += tmp; }
    }
    __syncthreads();
    u32 exc = incl - s + redW[w];
    hist[t * 2 + 0] = exc;
    hist[t * 2 + 1] = exc + h0;
    __syncthreads();
  }
  // ---- scatter: sorted position -> original index ----
#pragma unroll
  for (int j = 0; j < 16; ++j) {
    u32 p = (u32)(t + j * 1024);
    u32 pos = atomicAdd(&hist[mcode[j]], 1u);
    soidx[pos] = (u16)p;
  }
  __syncthreads();
  // ---- gather: write SoA ws arrays (cluster-major), bbox + ckey init ----
  {
    const int c = t >> 2;          // cluster 0..255
    const int q = t & 3;           // quarter
    float bxl = 1e30f, bxh = -1e30f, byl = 1e30f, byh = -1e30f, bzl = 1e30f, bzh = -1e30f;
    u32 lomax = 0;
#pragma unroll
    for (int j = 0; j < 16; ++j) {
      int sp = c * 64 + q * 16 + j;
      u32 oidx = (u32)soidx[sp];
      float X = xb[oidx * 3 + 0];
      float Y = xb[oidx * 3 + 1];
      float Z = xb[oidx * 3 + 2];
      wsX[bo + sp] = X; wsY[bo + sp] = Y; wsZ[bo + sp] = Z;
      wsO[bo + sp] = (u16)oidx;
      lomax = max(lomax, 16383u - oidx);
      bxl = fminf(bxl, X); bxh = fmaxf(bxh, X);
      byl = fminf(byl, Y); byh = fmaxf(byh, Y);
      bzl = fminf(bzl, Z); bzh = fmaxf(bzh, Z);
    }
#pragma unroll
    for (int s = 1; s <= 2; s <<= 1) {
      bxl = fminf(bxl, __shfl_xor(bxl, s, 64)); bxh = fmaxf(bxh, __shfl_xor(bxh, s, 64));
      byl = fminf(byl, __shfl_xor(byl, s, 64)); byh = fmaxf(byh, __shfl_xor(byh, s, 64));
      bzl = fminf(bzl, __shfl_xor(bzl, s, 64)); bzh = fmaxf(bzh, __shfl_xor(bzh, s, 64));
      lomax = max(lomax, (u32)__shfl_xor(lomax, s, 64));
    }
    if (q == 0) {
      bboxT[0 * 256 + c] = bxl; bboxT[1 * 256 + c] = bxh;
      bboxT[2 * 256 + c] = byl; bboxT[3 * 256 + c] = byh;
      bboxT[4 * 256 + c] = bzl; bboxT[5 * 256 + c] = bzh;
      ckeyL[c] = ((u64)inf10 << 32) | lomax;
    }
  }
  __syncthreads();  // gather done; hist/soidx region now dead
  // ---- init md (overwrites setup aliases) ----
#pragma unroll
  for (int j = 0; j < 16; ++j) mdL[t + j * 1024] = 1e10f;

  float cx = xb[0], cy = xb[1], cz = xb[2];
  if (t == 0) {
    centers[(b * NC) * 3 + 0] = cx;
    centers[(b * NC) * 3 + 1] = cy;
    centers[(b * NC) * 3 + 2] = cz;
  }

  // ---- main loop: 2 barriers per iteration ----
  for (int i = 1; i < NC; ++i) {
    // Phase A: prune + worklist build (clusters 0..255 on threads 0..255)
    if (t < 256) {
      float mdm = __uint_as_float((u32)(ckeyL[t] >> 32));
      float ax = fmaxf(0.f, fmaxf(__fsub_rn(bboxT[0 * 256 + t], cx), __fsub_rn(cx, bboxT[1 * 256 + t])));
      float ay = fmaxf(0.f, fmaxf(__fsub_rn(bboxT[2 * 256 + t], cy), __fsub_rn(cy, bboxT[3 * 256 + t])));
      float az = fmaxf(0.f, fmaxf(__fsub_rn(bboxT[4 * 256 + t], cz), __fsub_rn(cz, bboxT[5 * 256 + t])));
      float dlb = __fadd_rn(__fadd_rn(__fmul_rn(ax, ax), __fmul_rn(ay, ay)), __fmul_rn(az, az));
      if (dlb < mdm) {
        u32 pos = atomicAdd(&wcnt[i & 1], 1u);
        wl[(i & 1) * 256 + pos] = (u16)t;
      }
    } else if (t == 512) {
      wcnt[(i + 1) & 1] = 0u;  // reset one epoch ahead of its atomics
    }
    __syncthreads();  // barrier 1: worklist ready; md-init ready (iter 1)
    // Phase B: process active clusters, 1 cluster per wave-entry, 1 pt/lane
    {
      const int A = (int)wcnt[i & 1];
      for (int e = w; e < A; e += 16) {
        const int c = (int)wl[(i & 1) * 256 + e];
        const int sp = c * 64 + lane;
        float X = wsX[bo + sp];
        float Y = wsY[bo + sp];
        float Z = wsZ[bo + sp];
        u32 oidx = (u32)wsO[bo + sp];
        float dx = __fsub_rn(X, cx);
        float dy = __fsub_rn(Y, cy);
        float dz = __fsub_rn(Z, cz);
        float d = __fadd_rn(__fadd_rn(__fmul_rn(dx, dx), __fmul_rn(dy, dy)), __fmul_rn(dz, dz));
        float nm = fminf(mdL[sp], d);
        mdL[sp] = nm;
        u64 key = ((u64)__float_as_uint(nm) << 32) | (16383u - oidx);
        key = wavemax64(key);
        if (lane == 63) ckeyL[c] = key;
      }
    }
    __syncthreads();  // barrier 2: md/ckey updates visible
    // Phase C: global argmax over ckey[256], redundant in every wave
    {
      u64 g0 = ckeyL[lane];
      u64 g1 = ckeyL[lane + 64];
      u64 g2 = ckeyL[lane + 128];
      u64 g3 = ckeyL[lane + 192];
      u64 g = g0 > g1 ? g0 : g1;
      u64 h = g2 > g3 ? g2 : g3;
      g = g > h ? g : h;
      g = wavemax64(g);
      u32 glo = (u32)__builtin_amdgcn_readlane((int)(u32)g, 63);
      u32 oidx = 16383u - glo;
      cx = xb[oidx * 3 + 0];
      cy = xb[oidx * 3 + 1];
      cz = xb[oidx * 3 + 2];
      if (t == 0) {
        centers[(b * NC + i) * 3 + 0] = cx;
        centers[(b * NC + i) * 3 + 1] = cy;
        centers[(b * NC + i) * 3 + 2] = cz;
      }
    }
  }
}

// ---------------------------------------------------------------------------
// KNN: 8 waves/block, wave = one center. Exact top-32 set by (d, idx).
// ---------------------------------------------------------------------------
__global__ __launch_bounds__(512) void knn_kernel(const float* __restrict__ xyz,
                                                  const float* __restrict__ centers,
                                                  float* __restrict__ grouped) {
  __shared__ float spts[1024 * 3];
  __shared__ u64 cand[8][192];
  __shared__ int ccnt[8];
  const int t = threadIdx.x;
  const int lane = t & 63;
  const int w = t >> 6;
  const int cg = blockIdx.x * 8 + w;   // global center id
  const int b = cg >> 9;               // / 512
  const float* xb = xyz + (size_t)b * NPTS * 3;
  const float cx = centers[cg * 3 + 0];
  const float cy = centers[cg * 3 + 1];
  const float cz = centers[cg * 3 + 2];
  if (lane == 0) ccnt[w] = 0;

  // phase 1: per-lane min (packed (d,idx))
  u64 lmin = ~0ull;
  for (int ch = 0; ch < 16; ++ch) {
    __syncthreads();
    const float* src = xb + ch * 1024 * 3;
#pragma unroll
    for (int q = 0; q < 6; ++q) spts[q * 512 + t] = src[q * 512 + t];
    __syncthreads();
#pragma unroll
    for (int j = 0; j < 16; ++j) {
      int p = lane + j * 64;
      float dx = __fsub_rn(cx, spts[p * 3 + 0]);
      float dy = __fsub_rn(cy, spts[p * 3 + 1]);
      float dz = __fsub_rn(cz, spts[p * 3 + 2]);
      float d = __fadd_rn(__fadd_rn(__fmul_rn(dx, dx), __fmul_rn(dy, dy)), __fmul_rn(dz, dz));
      u64 kk = ((u64)__float_as_uint(d) << 32) | (u64)(u32)(ch * 1024 + p);
      lmin = kk < lmin ? kk : lmin;
    }
  }
  // bitonic sort (ascending) of 64 lane-minima; tau = 32nd smallest
  u64 v = lmin;
  for (int k = 2; k <= 64; k <<= 1)
    for (int j = k >> 1; j > 0; j >>= 1) {
      u64 o = shflx64(v, j);
      bool up = ((lane & k) == 0);
      bool lowr = ((lane & j) == 0);
      u64 mn = v < o ? v : o;
      u64 mx = v < o ? o : v;
      v = (lowr == up) ? mn : mx;
    }
  u64 tau = shfl64(v, 31);
  float tf = __uint_as_float((u32)(tau >> 32));

  // phase 2: collect candidates d <= tf  (guaranteed >= 32 of them)
  for (int ch = 0; ch < 16; ++ch) {
    __syncthreads();
    const float* src = xb + ch * 1024 * 3;
#pragma unroll
    for (int q = 0; q < 6; ++q) spts[q * 512 + t] = src[q * 512 + t];
    __syncthreads();
#pragma unroll
    for (int j = 0; j < 16; ++j) {
      int p = lane + j * 64;
      float dx = __fsub_rn(cx, spts[p * 3 + 0]);
      float dy = __fsub_rn(cy, spts[p * 3 + 1]);
      float dz = __fsub_rn(cz, spts[p * 3 + 2]);
      float d = __fadd_rn(__fadd_rn(__fmul_rn(dx, dx), __fmul_rn(dy, dy)), __fmul_rn(dz, dz));
      if (d <= tf) {
        int pos = atomicAdd(&ccnt[w], 1);
        if (pos < 192) cand[w][pos] = ((u64)__float_as_uint(d) << 32) | (u64)(u32)(ch * 1024 + p);
      }
    }
  }
  __syncthreads();
  int cnt = ccnt[w];
  u32 myn = 0u;  // lane r (<32) keeps r-th nearest neighbor's index
  if (cnt <= 192) {
    u64 c0 = (lane < cnt) ? cand[w][lane] : ~0ull;
    u64 c1 = (64 + lane < cnt) ? cand[w][64 + lane] : ~0ull;
    u64 c2 = (128 + lane < cnt) ? cand[w][128 + lane] : ~0ull;
    csw(c0, c1); csw(c1, c2); csw(c0, c1);  // c0<=c1<=c2
    for (int r = 0; r < 32; ++r) {
      u64 wm = c0;
      for (int s = 32; s; s >>= 1) {
        u64 o = shflx64(wm, s);
        wm = o < wm ? o : wm;
      }
      if (c0 == wm) { c0 = c1; c1 = c2; c2 = ~0ull; }
      if (lane == r) myn = (u32)wm;
    }
  } else {
    // exact slow fallback (astronomically rare): ascending extraction
    u64 last = 0ull;
    for (int r = 0; r < 32; ++r) {
      u64 bb = ~0ull;
      for (int j = 0; j < 256; ++j) {
        int p = lane + j * 64;
        float dx = __fsub_rn(cx, xb[p * 3 + 0]);
        float dy = __fsub_rn(cy, xb[p * 3 + 1]);
        float dz = __fsub_rn(cz, xb[p * 3 + 2]);
        float d = __fadd_rn(__fadd_rn(__fmul_rn(dx, dx), __fmul_rn(dy, dy)), __fmul_rn(dz, dz));
        u64 kk = ((u64)__float_as_uint(d) << 32) | (u64)(u32)p;
        if (r == 0 || kk > last)
          if (kk < bb) bb = kk;
      }
      for (int s = 32; s; s >>= 1) {
        u64 o = shflx64(bb, s);
        bb = o < bb ? o : bb;
      }
      last = bb;
      if (lane == r) myn = (u32)bb;
    }
  }
  if (lane < 32) {
    const float nx = xb[(size_t)myn * 3 + 0];
    const float ny = xb[(size_t)myn * 3 + 1];
    const float nz = xb[(size_t)myn * 3 + 2];
    float* gp = grouped + ((size_t)cg * 32 + lane) * 3;
    gp[0] = __fsub_rn(nx, cx);
    gp[1] = __fsub_rn(ny, cy);
    gp[2] = __fsub_rn(nz, cz);
  }
}

// ---------------------------------------------------------------------------
// Weight prep: fold eval-BN into weights, bf16 + MFMA-fragment-swizzled
// layouts for W2/W3 so the MLP kernel stages LDS with a linear copy.
// ---------------------------------------------------------------------------
__global__ __launch_bounds__(256) void prep_kernel(
    const float* __restrict__ W1, const float* __restrict__ b1,
    const float* __restrict__ g1, const float* __restrict__ be1,
    const float* __restrict__ m1, const float* __restrict__ v1,
    const float* __restrict__ W2, const float* __restrict__ b2,
    const float* __restrict__ g2, const float* __restrict__ be2,
    const float* __restrict__ m2, const float* __restrict__ v2,
    const float* __restrict__ W3,
    float* __restrict__ w1eff, u16* __restrict__ w2L,
    float* __restrict__ t2, u16* __restrict__ w3L) {
  const int tid = blockIdx.x * 256 + threadIdx.x;  // 128 blocks -> 32768
  if (tid < 64) {
    float s = g1[tid] / sqrtf(v1[tid] + 1e-5f);
    w1eff[tid * 4 + 0] = W1[tid * 3 + 0] * s;
    w1eff[tid * 4 + 1] = W1[tid * 3 + 1] * s;
    w1eff[tid * 4 + 2] = W1[tid * 3 + 2] * s;
    w1eff[tid * 4 + 3] = (b1[tid] - m1[tid]) * s + be1[tid];
  }
  if (tid < 128) {
    float s = g2[tid] / sqrtf(v2[tid] + 1e-5f);
    t2[tid] = (b2[tid] - m2[tid]) * s + be2[tid];
  }
  if (tid < 8192) {  // W2eff (128 out x 64 in), bn-scaled, as B-fragments
    int i = tid & 63, o = tid >> 6;
    float s = g2[o] / sqrtf(v2[o] + 1e-5f);
    int kg = i >> 3, j = i & 7;
    w2L[((((kg * 128) + o) * 8) ^ ((kg & 7) * 8)) + j] = bf16rne(W2[o * 64 + i] * s);
  }
  if (tid < 32768) {  // W3 (256 out x 128 in) as B-fragments, split in col-halves
    int i = tid & 127, o = tid >> 7;
    int kg = i >> 3, j = i & 7;
    int h = o >> 7, colh = o & 127;
    w3L[h * 16384 + ((((kg * 128) + colh) * 8) ^ ((kg & 7) * 8)) + j] = bf16rne(W3[o * 128 + i]);
  }
}

// ---------------------------------------------------------------------------
// MLP: 4 centers (128 rows) per 256-thread block; wave = one center.
// L1 on VALU (K=3), L2/L3 as bf16 MFMA GEMMs; fused max-pool + pos epilogue.
// LDS (64KB): [0,16K)=W2 (later W3 half over [0,32K)); [16K,32K)=H1; [32K,64K)=H2.
// ---------------------------------------------------------------------------
__global__ __launch_bounds__(256) void mlp_kernel(
    const float* __restrict__ grouped, const u16* __restrict__ w2L,
    const u16* __restrict__ w3L, const float* __restrict__ w1eff,
    const float* __restrict__ t2, const float* __restrict__ b3,
    const float* __restrict__ Wp, const float* __restrict__ bp,
    const float* __restrict__ centers, float* __restrict__ tokens) {
  __shared__ char lds[65536];
  const int t = threadIdx.x;
  const int lane = t & 63;
  const int w = t >> 6;
  const int l15 = lane & 15;
  const int lg = lane >> 4;
  const int c0 = blockIdx.x * 4;
  {  // stage W2 -> [0,16K)
    const u32* s = (const u32*)w2L;
    u32* d = (u32*)lds;
#pragma unroll
    for (int q = 0; q < 16; ++q) d[q * 256 + t] = s[q * 256 + t];
  }
  {  // H1 = relu(X @ W1eff^T + b1eff), bf16, swizzled -> [16K,32K)
    const int row = t & 127;
    const int oh = (t >> 7) * 32;
    const int cg = c0 + (row >> 5);
    const float* gp = grouped + ((size_t)cg * 32 + (row & 31)) * 3;
    const float gx = gp[0], gy = gp[1], gz = gp[2];
    u16 hv[32];
#pragma unroll
    for (int o = 0; o < 32; ++o) {
      const float4 wvv = ((const float4*)w1eff)[oh + o];
      float h = fmaxf(0.f, gx * wvv.x + gy * wvv.y + gz * wvv.z + wvv.w);
      hv[o] = bf16rne(h);
    }
#pragma unroll
    for (int c4 = 0; c4 < 4; ++c4) {
      uint4 pk;
      pk.x = (u32)hv[c4 * 8 + 0] | ((u32)hv[c4 * 8 + 1] << 16);
      pk.y = (u32)hv[c4 * 8 + 2] | ((u32)hv[c4 * 8 + 3] << 16);
      pk.z = (u32)hv[c4 * 8 + 4] | ((u32)hv[c4 * 8 + 5] << 16);
      pk.w = (u32)hv[c4 * 8 + 6] | ((u32)hv[c4 * 8 + 7] << 16);
      int byte = row * 128 + oh * 2 + c4 * 16;
      *reinterpret_cast<uint4*>(lds + 16384 + (byte ^ ((row & 7) << 4))) = pk;
    }
  }
  __syncthreads();
  // GEMM2: H2(32x128) = H1(32x64) @ W2eff^T, per wave
  f32x4 acc2[2][8];
#pragma unroll
  for (int m = 0; m < 2; ++m)
#pragma unroll
    for (int n = 0; n < 8; ++n) acc2[m][n] = (f32x4){0.f, 0.f, 0.f, 0.f};
#pragma unroll
  for (int ks = 0; ks < 2; ++ks) {
    bf16x8 a[2];
#pragma unroll
    for (int m = 0; m < 2; ++m) {
      int row = w * 32 + m * 16 + l15;
      int byte = row * 128 + (ks * 32 + lg * 8) * 2;
      a[m] = *reinterpret_cast<const bf16x8*>(lds + 16384 + (byte ^ ((row & 7) << 4)));
    }
    const int kg = ks * 4 + lg;
#pragma unroll
    for (int n = 0; n < 8; ++n) {
      int idx = (((kg * 128) + (n * 16 + l15)) * 8) ^ ((kg & 7) * 8);
      bf16x8 bb = *reinterpret_cast<const bf16x8*>((const u16*)lds + idx);
      acc2[0][n] = MFMA16(a[0], bb, acc2[0][n]);
      acc2[1][n] = MFMA16(a[1], bb, acc2[1][n]);
    }
  }
#pragma unroll
  for (int n = 0; n < 8; ++n) {  // relu(acc + t2) -> H2 bf16 swizzled
    const int col = n * 16 + l15;
    const float t2v = t2[col];
#pragma unroll
    for (int m = 0; m < 2; ++m)
#pragma unroll
      for (int r = 0; r < 4; ++r) {
        float vv = fmaxf(0.f, acc2[m][n][r] + t2v);
        int row = w * 32 + m * 16 + lg * 4 + r;
        int byte = row * 256 + col * 2;
        *reinterpret_cast<u16*>(lds + 32768 + (byte ^ ((row & 7) << 4))) = bf16rne(vv);
      }
  }
  __syncthreads();
  const float ccx = centers[(c0 + w) * 3 + 0];
  const float ccy = centers[(c0 + w) * 3 + 1];
  const float ccz = centers[(c0 + w) * 3 + 2];
  float* tok = tokens + (size_t)(c0 + w) * 256;
  for (int h = 0; h < 2; ++h) {
    {  // stage W3 col-half (32KB) -> [0,32K); H2 at [32K,64K) untouched
      const u32* s = (const u32*)w3L + h * 8192;
      u32* d = (u32*)lds;
#pragma unroll
      for (int q = 0; q < 32; ++q) d[q * 256 + t] = s[q * 256 + t];
    }
    __syncthreads();
    f32x4 acc3[2][8];
#pragma unroll
    for (int m = 0; m < 2; ++m)
#pragma unroll
      for (int n = 0; n < 8; ++n) acc3[m][n] = (f32x4){0.f, 0.f, 0.f, 0.f};
#pragma unroll
    for (int ks = 0; ks < 4; ++ks) {
      bf16x8 a[2];
#pragma unroll
      for (int m = 0; m < 2; ++m) {
        int row = w * 32 + m * 16 + l15;
        int byte = row * 256 + (ks * 32 + lg * 8) * 2;
        a[m] = *reinterpret_cast<const bf16x8*>(lds + 32768 + (byte ^ ((row & 7) << 4)));
      }
      const int kg = ks * 4 + lg;
#pragma unroll
      for (int n = 0; n < 8; ++n) {
        int idx = (((kg * 128) + (n * 16 + l15)) * 8) ^ ((kg & 7) * 8);
        bf16x8 bb = *reinterpret_cast<const bf16x8*>((const u16*)lds + idx);
        acc3[0][n] = MFMA16(a[0], bb, acc3[0][n]);
        acc3[1][n] = MFMA16(a[1], bb, acc3[1][n]);
      }
    }
#pragma unroll
    for (int n = 0; n < 8; ++n) {  // max over 32 neighbors + b3 + pos
      float vmx = acc3[0][n][0];
#pragma unroll
      for (int m = 0; m < 2; ++m)
#pragma unroll
        for (int r = 0; r < 4; ++r) vmx = fmaxf(vmx, acc3[m][n][r]);
      vmx = fmaxf(vmx, __shfl_xor(vmx, 16, 64));
      vmx = fmaxf(vmx, __shfl_xor(vmx, 32, 64));
      const int col = h * 128 + n * 16 + l15;
      if (lane < 16) {
        float pos = Wp[col * 3 + 0] * ccx + Wp[col * 3 + 1] * ccy +
                    Wp[col * 3 + 2] * ccz + bp[col] + b3[col];
        tok[col] = vmx + pos;
      }
    }
    __syncthreads();
  }
}

// ---------------------------------------------------------------------------
extern "C" void kernel_launch(void* const* d_in, const int* in_sizes, int n_in,
                              void* d_out, int out_size, void* d_ws, size_t ws_size,
                              hipStream_t stream) {
  const float* xyz = (const float*)d_in[0];
  const float* W1 = (const float*)d_in[1];
  const float* b1 = (const float*)d_in[2];
  const float* g1 = (const float*)d_in[3];
  const float* be1 = (const float*)d_in[4];
  const float* m1 = (const float*)d_in[5];
  const float* v1 = (const float*)d_in[6];
  const float* W2 = (const float*)d_in[7];
  const float* b2 = (const float*)d_in[8];
  const float* g2 = (const float*)d_in[9];
  const float* be2 = (const float*)d_in[10];
  const float* m2 = (const float*)d_in[11];
  const float* v2 = (const float*)d_in[12];
  const float* W3 = (const float*)d_in[13];
  const float* b3 = (const float*)d_in[14];
  const float* Wp = (const float*)d_in[15];
  const float* bp = (const float*)d_in[16];

  char* ws = (char*)d_ws;
  // fps scratch overlaps `grouped` (disjoint in time: fps finishes before knn)
  float* wsX = (float*)ws;                          // 8*16384 f32 = 524288 B
  float* wsY = (float*)(ws + 524288);               // 524288 B
  float* wsZ = (float*)(ws + 1048576);              // 524288 B
  u16* wsO = (u16*)(ws + 1572864);                  // 8*16384 u16 = 262144 B
  float* grouped = (float*)ws;                      // 4096*32*3 f32 = 1572864 B
  float* w1eff = (float*)(ws + 1835008);            // 64*4 f32     = 1024 B
  u16* w2L = (u16*)(ws + 1836032);                  // 8192 u16     = 16384 B
  float* t2 = (float*)(ws + 1852416);               // 128 f32      = 512 B
  u16* w3L = (u16*)(ws + 1852928);                  // 32768 u16    = 65536 B

  float* centers = (float*)d_out;                   // (8,512,3)
  float* tokens = (float*)d_out + 8 * 512 * 3;      // (8,512,256)

  prep_kernel<<<dim3(128), dim3(256), 0, stream>>>(W1, b1, g1, be1, m1, v1,
                                                   W2, b2, g2, be2, m2, v2, W3,
                                                   w1eff, w2L, t2, w3L);
  fps_kernel<<<dim3(8), dim3(1024), 0, stream>>>(xyz, centers, wsX, wsY, wsZ, wsO);
  knn_kernel<<<dim3(512), dim3(512), 0, stream>>>(xyz, centers, grouped);
  mlp_kernel<<<dim3(1024), dim3(256), 0, stream>>>(grouped, w2L, w3L, w1eff, t2,
                                                   b3, Wp, bp, centers, tokens);
}

// Round 12
// 832.568 us; speedup vs baseline: 1.8010x; 1.0146x over previous
//
#include <hip/hip_runtime.h>

typedef unsigned int u32;
typedef unsigned long long u64;
typedef unsigned short u16;

#define DEVFN static __device__ __forceinline__

constexpr int NPTS = 16384;  // points per batch
constexpr int NC = 512;      // centers per batch
// B=8, K=32, FEAT=256

typedef __attribute__((ext_vector_type(8))) short bf16x8;
typedef __attribute__((ext_vector_type(4))) float f32x4;

#define MFMA16(a, b, c) __builtin_amdgcn_mfma_f32_16x16x32_bf16(a, b, c, 0, 0, 0)

DEVFN u16 bf16rne(float f) {
  u32 b = __float_as_uint(f);
  u32 r = (b + 0x7FFFu + ((b >> 16) & 1u)) >> 16;
  return (u16)r;
}

DEVFN u64 shflx64(u64 v, int m) {
  u32 lo = __shfl_xor((u32)v, m, 64);
  u32 hi = __shfl_xor((u32)(v >> 32), m, 64);
  return ((u64)hi << 32) | lo;
}
DEVFN u64 shfl64(u64 v, int src) {
  u32 lo = __shfl((u32)v, src, 64);
  u32 hi = __shfl((u32)(v >> 32), src, 64);
  return ((u64)hi << 32) | lo;
}

DEVFN void csw(u64& a, u64& b) {
  u64 lo = a < b ? a : b;
  u64 hi = a < b ? b : a;
  a = lo; b = hi;
}

DEVFN u32 spread3(u32 v) {  // 4 bits -> bits 0,3,6,9
  return (v & 1u) | ((v & 2u) << 2) | ((v & 4u) << 4) | ((v & 8u) << 6);
}

// All FPS keys are < 2^63 with sign bit 0: positive-f64 ordering == u64
// ordering (high word = positive-f32 md bits -> f64 exponent in [0x001,0x501],
// never NaN/Inf; f64 denormals compare correctly, never flushed on CDNA).
// So u64 max == v_max_f64 on the bit pattern: 1 inst instead of cmp+2cndmask.
DEVFN u64 maxf64u(u64 a, u64 b) {
  double x = __longlong_as_double((long long)a);
  double y = __longlong_as_double((long long)b);
  return (u64)__double_as_longlong(fmax(x, y));
}
template <int CTRL, int RM>
DEVFN u64 dppmaxf(u64 k) {
  u32 lo = (u32)k, hi = (u32)(k >> 32);
  u32 lo2 = (u32)__builtin_amdgcn_update_dpp((int)lo, (int)lo, CTRL, RM, 0xF, false);
  u32 hi2 = (u32)__builtin_amdgcn_update_dpp((int)hi, (int)hi, CTRL, RM, 0xF, false);
  return maxf64u(k, ((u64)hi2 << 32) | lo2);
}
// full 64-lane max -> lane 63 holds result (standard ror/bcast sequence)
DEVFN u64 wavemaxf(u64 k) {
  k = dppmaxf<0x121, 0xF>(k);  // ror1
  k = dppmaxf<0x122, 0xF>(k);  // ror2
  k = dppmaxf<0x124, 0xF>(k);  // ror4
  k = dppmaxf<0x128, 0xF>(k);  // ror8 -> row max in every lane of row
  k = dppmaxf<0x142, 0xA>(k);  // row_bcast15 -> rows 1,3
  k = dppmaxf<0x143, 0xC>(k);  // row_bcast31 -> rows 2,3; lane63 = wave max
  return k;
}

// ---------------------------------------------------------------------------
// FPS v12: v11 worklist structure (Phase A prune->worklist, Phase B 1 cluster
// per wave-entry / 1 pt per lane, Phase C redundant argmax; 2 barriers/iter)
// with the issued-instruction count cut ~2x:
//  - u64 reduces via v_max_f64 bit-pattern trick (3 inst/step vs 5)
//  - point data packed as one float4 {x,y,z,lo_bits}: 1 addr calc + 1
//    dwordx4 per entry (was 4 of each). lo = (16383-oidx)<<8 | cluster.
//  - winner coords from LDS ccoord[] (cluster id in key low 8 bits) instead
//    of a dependent uniform global load.
// Exactness: key = md_bits<<32 | lo; max == numpy argmax (max md, tie ->
// lowest oidx; cluster bits only separate distinct points). Prune =
// monotone-rounding bbox lower bound (skips only provably no-op updates).
// ---------------------------------------------------------------------------
__global__ __launch_bounds__(1024) void fps_kernel(const float* __restrict__ xyz,
                                                   float* __restrict__ centers,
                                                   float4* __restrict__ ws4) {
  const int b = blockIdx.x;
  const int t = threadIdx.x;
  const int lane = t & 63;
  const int w = t >> 6;
  const float* xb = xyz + (size_t)b * NPTS * 3;
  const int bo = b * NPTS;

  __shared__ char smem[78336];
  float* mdL = (float*)smem;                 // [0, 64K)  md per sorted point
  u64* ckeyL = (u64*)(smem + 65536);         // u64[256]
  float* bboxT = (float*)(smem + 67584);     // f32[6][256]
  float* ccoordL = (float*)(smem + 73728);   // f32[256*3] argmax coords
  u16* wl = (u16*)(smem + 76800);            // u16[2][256] worklist
  u32* wcnt = (u32*)(smem + 77824);          // u32[2]
  float* redB = (float*)(smem + 77832);      // 104 f32
  u32* redW = (u32*)(smem + 78248);          // 16 u32
  u32* hist = (u32*)smem;                    // setup alias [0, 8K)
  u16* soidx = (u16*)(smem + 8192);          // setup alias [8K, 40K)

  const u32 inf10 = __float_as_uint(1e10f);

  // ---- setup: global bbox + morton codes ----
  u32 mcode[16];
  {
    float ox[16], oy[16], oz[16];
    float lx = 1e30f, ly = 1e30f, lz = 1e30f;
    float hx = -1e30f, hy = -1e30f, hz = -1e30f;
#pragma unroll
    for (int j = 0; j < 16; ++j) {
      int p = t + j * 1024;
      ox[j] = xb[p * 3 + 0];
      oy[j] = xb[p * 3 + 1];
      oz[j] = xb[p * 3 + 2];
      lx = fminf(lx, ox[j]); hx = fmaxf(hx, ox[j]);
      ly = fminf(ly, oy[j]); hy = fmaxf(hy, oy[j]);
      lz = fminf(lz, oz[j]); hz = fmaxf(hz, oz[j]);
    }
#pragma unroll
    for (int s = 32; s; s >>= 1) {
      lx = fminf(lx, __shfl_xor(lx, s, 64)); hx = fmaxf(hx, __shfl_xor(hx, s, 64));
      ly = fminf(ly, __shfl_xor(ly, s, 64)); hy = fmaxf(hy, __shfl_xor(hy, s, 64));
      lz = fminf(lz, __shfl_xor(lz, s, 64)); hz = fmaxf(hz, __shfl_xor(hz, s, 64));
    }
    if (lane == 0) {
      redB[w * 6 + 0] = lx; redB[w * 6 + 1] = hx;
      redB[w * 6 + 2] = ly; redB[w * 6 + 3] = hy;
      redB[w * 6 + 4] = lz; redB[w * 6 + 5] = hz;
    }
    hist[t] = 0; hist[t + 1024] = 0;
    if (t < 2) wcnt[t] = 0;
    __syncthreads();
    if (t == 0) {
      float a0 = redB[0], a1 = redB[1], a2 = redB[2], a3 = redB[3], a4 = redB[4], a5 = redB[5];
      for (int q = 1; q < 16; ++q) {
        a0 = fminf(a0, redB[q * 6 + 0]); a1 = fmaxf(a1, redB[q * 6 + 1]);
        a2 = fminf(a2, redB[q * 6 + 2]); a3 = fmaxf(a3, redB[q * 6 + 3]);
        a4 = fminf(a4, redB[q * 6 + 4]); a5 = fmaxf(a5, redB[q * 6 + 5]);
      }
      redB[96] = a0; redB[97] = a1; redB[98] = a2;
      redB[99] = a3; redB[100] = a4; redB[101] = a5;
    }
    __syncthreads();
    const float glx = redB[96], ghx = redB[97];
    const float gly = redB[98], ghy = redB[99];
    const float glz = redB[100], ghz = redB[101];
    const float sx = 15.999f / fmaxf(ghx - glx, 1e-9f);
    const float sy = 15.999f / fmaxf(ghy - gly, 1e-9f);
    const float sz = 7.999f / fmaxf(ghz - glz, 1e-9f);
#pragma unroll
    for (int j = 0; j < 16; ++j) {
      int ix = min(15, max(0, (int)((ox[j] - glx) * sx)));
      int iy = min(15, max(0, (int)((oy[j] - gly) * sy)));
      int iz = min(7, max(0, (int)((oz[j] - glz) * sz)));
      mcode[j] = spread3((u32)ix) | (spread3((u32)iy) << 1) | (spread3((u32)iz) << 2);
    }
  }
  // ---- histogram (2048 bins) ----
#pragma unroll
  for (int j = 0; j < 16; ++j) atomicAdd(&hist[mcode[j]], 1u);
  __syncthreads();
  // ---- exclusive scan over 2048 bins ----
  {
    u32 h0 = hist[t * 2 + 0], h1 = hist[t * 2 + 1];
    u32 s = h0 + h1;
    u32 incl = s;
#pragma unroll
    for (int d = 1; d < 64; d <<= 1) {
      u32 n = __shfl_up(incl, d, 64);
      if (lane >= d) incl += n;
    }
    if (lane == 63) redW[w] = incl;
    __syncthreads();
    if (t == 0) {
      u32 run = 0;
      for (int q = 0; q < 16; ++q) { u32 tmp = redW[q]; redW[q] = run; run += tmp; }
    }
    __syncthreads();
    u32 exc = incl - s + redW[w];
    hist[t * 2 + 0] = exc;
    hist[t * 2 + 1] = exc + h0;
    __syncthreads();
  }
  // ---- scatter: sorted position -> original index ----
#pragma unroll
  for (int j = 0; j < 16; ++j) {
    u32 p = (u32)(t + j * 1024);
    u32 pos = atomicAdd(&hist[mcode[j]], 1u);
    soidx[pos] = (u16)p;
  }
  __syncthreads();
  // ---- gather: pack float4 {x,y,z,lo}, bbox + ckey + ccoord init ----
  {
    const int c = t >> 2;          // cluster 0..255
    const int q = t & 3;           // quarter
    float bxl = 1e30f, bxh = -1e30f, byl = 1e30f, byh = -1e30f, bzl = 1e30f, bzh = -1e30f;
    u32 lomax = 0;
    float axc = 0.f, ayc = 0.f, azc = 0.f;
#pragma unroll
    for (int j = 0; j < 16; ++j) {
      int sp = c * 64 + q * 16 + j;
      u32 oidx = (u32)soidx[sp];
      float X = xb[oidx * 3 + 0];
      float Y = xb[oidx * 3 + 1];
      float Z = xb[oidx * 3 + 2];
      u32 lo = ((16383u - oidx) << 8) | (u32)c;
      float4 pk; pk.x = X; pk.y = Y; pk.z = Z; pk.w = __uint_as_float(lo);
      ws4[bo + sp] = pk;
      if (lo > lomax) { lomax = lo; axc = X; ayc = Y; azc = Z; }
      bxl = fminf(bxl, X); bxh = fmaxf(bxh, X);
      byl = fminf(byl, Y); byh = fmaxf(byh, Y);
      bzl = fminf(bzl, Z); bzh = fmaxf(bzh, Z);
    }
    u32 gl = lomax;
#pragma unroll
    for (int s = 1; s <= 2; s <<= 1) {
      bxl = fminf(bxl, __shfl_xor(bxl, s, 64)); bxh = fmaxf(bxh, __shfl_xor(bxh, s, 64));
      byl = fminf(byl, __shfl_xor(byl, s, 64)); byh = fmaxf(byh, __shfl_xor(byh, s, 64));
      bzl = fminf(bzl, __shfl_xor(bzl, s, 64)); bzh = fmaxf(bzh, __shfl_xor(bzh, s, 64));
      gl = max(gl, (u32)__shfl_xor(gl, s, 64));
    }
    if (lomax == gl) {  // exactly one of the 4 threads (lo unique)
      ccoordL[c * 3 + 0] = axc; ccoordL[c * 3 + 1] = ayc; ccoordL[c * 3 + 2] = azc;
    }
    if (q == 0) {
      bboxT[0 * 256 + c] = bxl; bboxT[1 * 256 + c] = bxh;
      bboxT[2 * 256 + c] = byl; bboxT[3 * 256 + c] = byh;
      bboxT[4 * 256 + c] = bzl; bboxT[5 * 256 + c] = bzh;
      ckeyL[c] = ((u64)inf10 << 32) | gl;
    }
  }
  __syncthreads();  // gather done; hist/soidx region now dead
  // ---- init md (overwrites setup aliases) ----
#pragma unroll
  for (int j = 0; j < 16; ++j) mdL[t + j * 1024] = 1e10f;

  float cx = xb[0], cy = xb[1], cz = xb[2];
  if (t == 0) {
    centers[(b * NC) * 3 + 0] = cx;
    centers[(b * NC) * 3 + 1] = cy;
    centers[(b * NC) * 3 + 2] = cz;
  }

  // ---- main loop: 2 barriers per iteration ----
  for (int i = 1; i < NC; ++i) {
    // Phase A: prune + worklist build (clusters 0..255 on threads 0..255)
    if (t < 256) {
      float mdm = __uint_as_float((u32)(ckeyL[t] >> 32));
      float ax = fmaxf(0.f, fmaxf(__fsub_rn(bboxT[0 * 256 + t], cx), __fsub_rn(cx, bboxT[1 * 256 + t])));
      float ay = fmaxf(0.f, fmaxf(__fsub_rn(bboxT[2 * 256 + t], cy), __fsub_rn(cy, bboxT[3 * 256 + t])));
      float az = fmaxf(0.f, fmaxf(__fsub_rn(bboxT[4 * 256 + t], cz), __fsub_rn(cz, bboxT[5 * 256 + t])));
      float dlb = __fadd_rn(__fadd_rn(__fmul_rn(ax, ax), __fmul_rn(ay, ay)), __fmul_rn(az, az));
      if (dlb < mdm) {
        u32 pos = atomicAdd(&wcnt[i & 1], 1u);
        wl[(i & 1) * 256 + pos] = (u16)t;
      }
    } else if (t == 512) {
      wcnt[(i + 1) & 1] = 0u;  // reset one epoch ahead of its atomics
    }
    __syncthreads();  // barrier 1: worklist ready; md-init ready (iter 1)
    // Phase B: process active clusters, 1 cluster per wave-entry, 1 pt/lane
    {
      const int A = (int)wcnt[i & 1];
      for (int e = w; e < A; e += 16) {
        const int c = (int)wl[(i & 1) * 256 + e];
        const int sp = c * 64 + lane;
        float4 p = ws4[bo + sp];
        float dx = __fsub_rn(p.x, cx);
        float dy = __fsub_rn(p.y, cy);
        float dz = __fsub_rn(p.z, cz);
        float d = __fadd_rn(__fadd_rn(__fmul_rn(dx, dx), __fmul_rn(dy, dy)), __fmul_rn(dz, dz));
        float nm = fminf(mdL[sp], d);
        mdL[sp] = nm;
        u64 key = ((u64)__float_as_uint(nm) << 32) | (u64)__float_as_uint(p.w);
        u64 r = wavemaxf(key);
        u32 klo = (u32)__builtin_amdgcn_readlane((int)(u32)r, 63);
        u32 khi = (u32)__builtin_amdgcn_readlane((int)(u32)(r >> 32), 63);
        u64 wmax = ((u64)khi << 32) | klo;
        if (key == wmax) {  // exactly one lane (keys unique)
          ckeyL[c] = key;
          ccoordL[c * 3 + 0] = p.x; ccoordL[c * 3 + 1] = p.y; ccoordL[c * 3 + 2] = p.z;
        }
      }
    }
    __syncthreads();  // barrier 2: md/ckey/ccoord updates visible
    // Phase C: global argmax over ckey[256], redundant in every wave
    {
      u64 g0 = ckeyL[lane];
      u64 g1 = ckeyL[lane + 64];
      u64 g2 = ckeyL[lane + 128];
      u64 g3 = ckeyL[lane + 192];
      u64 g = maxf64u(maxf64u(g0, g1), maxf64u(g2, g3));
      g = wavemaxf(g);
      u32 glo = (u32)__builtin_amdgcn_readlane((int)(u32)g, 63);
      u32 widx = glo & 255u;  // cluster id lives in key low 8 bits
      cx = ccoordL[widx * 3 + 0];
      cy = ccoordL[widx * 3 + 1];
      cz = ccoordL[widx * 3 + 2];
      if (t == 0) {
        centers[(b * NC + i) * 3 + 0] = cx;
        centers[(b * NC + i) * 3 + 1] = cy;
        centers[(b * NC + i) * 3 + 2] = cz;
      }
    }
  }
}

// ---------------------------------------------------------------------------
// KNN: 8 waves/block, wave = one center. Exact top-32 set by (d, idx).
// ---------------------------------------------------------------------------
__global__ __launch_bounds__(512) void knn_kernel(const float* __restrict__ xyz,
                                                  const float* __restrict__ centers,
                                                  float* __restrict__ grouped) {
  __shared__ float spts[1024 * 3];
  __shared__ u64 cand[8][192];
  __shared__ int ccnt[8];
  const int t = threadIdx.x;
  const int lane = t & 63;
  const int w = t >> 6;
  const int cg = blockIdx.x * 8 + w;   // global center id
  const int b = cg >> 9;               // / 512
  const float* xb = xyz + (size_t)b * NPTS * 3;
  const float cx = centers[cg * 3 + 0];
  const float cy = centers[cg * 3 + 1];
  const float cz = centers[cg * 3 + 2];
  if (lane == 0) ccnt[w] = 0;

  // phase 1: per-lane min (packed (d,idx))
  u64 lmin = ~0ull;
  for (int ch = 0; ch < 16; ++ch) {
    __syncthreads();
    const float* src = xb + ch * 1024 * 3;
#pragma unroll
    for (int q = 0; q < 6; ++q) spts[q * 512 + t] = src[q * 512 + t];
    __syncthreads();
#pragma unroll
    for (int j = 0; j < 16; ++j) {
      int p = lane + j * 64;
      float dx = __fsub_rn(cx, spts[p * 3 + 0]);
      float dy = __fsub_rn(cy, spts[p * 3 + 1]);
      float dz = __fsub_rn(cz, spts[p * 3 + 2]);
      float d = __fadd_rn(__fadd_rn(__fmul_rn(dx, dx), __fmul_rn(dy, dy)), __fmul_rn(dz, dz));
      u64 kk = ((u64)__float_as_uint(d) << 32) | (u64)(u32)(ch * 1024 + p);
      lmin = kk < lmin ? kk : lmin;
    }
  }
  // bitonic sort (ascending) of 64 lane-minima; tau = 32nd smallest
  u64 v = lmin;
  for (int k = 2; k <= 64; k <<= 1)
    for (int j = k >> 1; j > 0; j >>= 1) {
      u64 o = shflx64(v, j);
      bool up = ((lane & k) == 0);
      bool lowr = ((lane & j) == 0);
      u64 mn = v < o ? v : o;
      u64 mx = v < o ? o : v;
      v = (lowr == up) ? mn : mx;
    }
  u64 tau = shfl64(v, 31);
  float tf = __uint_as_float((u32)(tau >> 32));

  // phase 2: collect candidates d <= tf  (guaranteed >= 32 of them)
  for (int ch = 0; ch < 16; ++ch) {
    __syncthreads();
    const float* src = xb + ch * 1024 * 3;
#pragma unroll
    for (int q = 0; q < 6; ++q) spts[q * 512 + t] = src[q * 512 + t];
    __syncthreads();
#pragma unroll
    for (int j = 0; j < 16; ++j) {
      int p = lane + j * 64;
      float dx = __fsub_rn(cx, spts[p * 3 + 0]);
      float dy = __fsub_rn(cy, spts[p * 3 + 1]);
      float dz = __fsub_rn(cz, spts[p * 3 + 2]);
      float d = __fadd_rn(__fadd_rn(__fmul_rn(dx, dx), __fmul_rn(dy, dy)), __fmul_rn(dz, dz));
      if (d <= tf) {
        int pos = atomicAdd(&ccnt[w], 1);
        if (pos < 192) cand[w][pos] = ((u64)__float_as_uint(d) << 32) | (u64)(u32)(ch * 1024 + p);
      }
    }
  }
  __syncthreads();
  int cnt = ccnt[w];
  u32 myn = 0u;  // lane r (<32) keeps r-th nearest neighbor's index
  if (cnt <= 192) {
    u64 c0 = (lane < cnt) ? cand[w][lane] : ~0ull;
    u64 c1 = (64 + lane < cnt) ? cand[w][64 + lane] : ~0ull;
    u64 c2 = (128 + lane < cnt) ? cand[w][128 + lane] : ~0ull;
    csw(c0, c1); csw(c1, c2); csw(c0, c1);  // c0<=c1<=c2
    for (int r = 0; r < 32; ++r) {
      u64 wm = c0;
      for (int s = 32; s; s >>= 1) {
        u64 o = shflx64(wm, s);
        wm = o < wm ? o : wm;
      }
      if (c0 == wm) { c0 = c1; c1 = c2; c2 = ~0ull; }
      if (lane == r) myn = (u32)wm;
    }
  } else {
    // exact slow fallback (astronomically rare): ascending extraction
    u64 last = 0ull;
    for (int r = 0; r < 32; ++r) {
      u64 bb = ~0ull;
      for (int j = 0; j < 256; ++j) {
        int p = lane + j * 64;
        float dx = __fsub_rn(cx, xb[p * 3 + 0]);
        float dy = __fsub_rn(cy, xb[p * 3 + 1]);
        float dz = __fsub_rn(cz, xb[p * 3 + 2]);
        float d = __fadd_rn(__fadd_rn(__fmul_rn(dx, dx), __fmul_rn(dy, dy)), __fmul_rn(dz, dz));
        u64 kk = ((u64)__float_as_uint(d) << 32) | (u64)(u32)p;
        if (r == 0 || kk > last)
          if (kk < bb) bb = kk;
      }
      for (int s = 32; s; s >>= 1) {
        u64 o = shflx64(bb, s);
        bb = o < bb ? o : bb;
      }
      last = bb;
      if (lane == r) myn = (u32)bb;
    }
  }
  if (lane < 32) {
    const float nx = xb[(size_t)myn * 3 + 0];
    const float ny = xb[(size_t)myn * 3 + 1];
    const float nz = xb[(size_t)myn * 3 + 2];
    float* gp = grouped + ((size_t)cg * 32 + lane) * 3;
    gp[0] = __fsub_rn(nx, cx);
    gp[1] = __fsub_rn(ny, cy);
    gp[2] = __fsub_rn(nz, cz);
  }
}

// ---------------------------------------------------------------------------
// Weight prep: fold eval-BN into weights, bf16 + MFMA-fragment-swizzled
// layouts for W2/W3 so the MLP kernel stages LDS with a linear copy.
// ---------------------------------------------------------------------------
__global__ __launch_bounds__(256) void prep_kernel(
    const float* __restrict__ W1, const float* __restrict__ b1,
    const float* __restrict__ g1, const float* __restrict__ be1,
    const float* __restrict__ m1, const float* __restrict__ v1,
    const float* __restrict__ W2, const float* __restrict__ b2,
    const float* __restrict__ g2, const float* __restrict__ be2,
    const float* __restrict__ m2, const float* __restrict__ v2,
    const float* __restrict__ W3,
    float* __restrict__ w1eff, u16* __restrict__ w2L,
    float* __restrict__ t2, u16* __restrict__ w3L) {
  const int tid = blockIdx.x * 256 + threadIdx.x;  // 128 blocks -> 32768
  if (tid < 64) {
    float s = g1[tid] / sqrtf(v1[tid] + 1e-5f);
    w1eff[tid * 4 + 0] = W1[tid * 3 + 0] * s;
    w1eff[tid * 4 + 1] = W1[tid * 3 + 1] * s;
    w1eff[tid * 4 + 2] = W1[tid * 3 + 2] * s;
    w1eff[tid * 4 + 3] = (b1[tid] - m1[tid]) * s + be1[tid];
  }
  if (tid < 128) {
    float s = g2[tid] / sqrtf(v2[tid] + 1e-5f);
    t2[tid] = (b2[tid] - m2[tid]) * s + be2[tid];
  }
  if (tid < 8192) {  // W2eff (128 out x 64 in), bn-scaled, as B-fragments
    int i = tid & 63, o = tid >> 6;
    float s = g2[o] / sqrtf(v2[o] + 1e-5f);
    int kg = i >> 3, j = i & 7;
    w2L[((((kg * 128) + o) * 8) ^ ((kg & 7) * 8)) + j] = bf16rne(W2[o * 64 + i] * s);
  }
  if (tid < 32768) {  // W3 (256 out x 128 in) as B-fragments, split in col-halves
    int i = tid & 127, o = tid >> 7;
    int kg = i >> 3, j = i & 7;
    int h = o >> 7, colh = o & 127;
    w3L[h * 16384 + ((((kg * 128) + colh) * 8) ^ ((kg & 7) * 8)) + j] = bf16rne(W3[o * 128 + i]);
  }
}

// ---------------------------------------------------------------------------
// MLP: 4 centers (128 rows) per 256-thread block; wave = one center.
// L1 on VALU (K=3), L2/L3 as bf16 MFMA GEMMs; fused max-pool + pos epilogue.
// LDS (64KB): [0,16K)=W2 (later W3 half over [0,32K)); [16K,32K)=H1; [32K,64K)=H2.
// ---------------------------------------------------------------------------
__global__ __launch_bounds__(256) void mlp_kernel(
    const float* __restrict__ grouped, const u16* __restrict__ w2L,
    const u16* __restrict__ w3L, const float* __restrict__ w1eff,
    const float* __restrict__ t2, const float* __restrict__ b3,
    const float* __restrict__ Wp, const float* __restrict__ bp,
    const float* __restrict__ centers, float* __restrict__ tokens) {
  __shared__ char lds[65536];
  const int t = threadIdx.x;
  const int lane = t & 63;
  const int w = t >> 6;
  const int l15 = lane & 15;
  const int lg = lane >> 4;
  const int c0 = blockIdx.x * 4;
  {  // stage W2 -> [0,16K)
    const u32* s = (const u32*)w2L;
    u32* d = (u32*)lds;
#pragma unroll
    for (int q = 0; q < 16; ++q) d[q * 256 + t] = s[q * 256 + t];
  }
  {  // H1 = relu(X @ W1eff^T + b1eff), bf16, swizzled -> [16K,32K)
    const int row = t & 127;
    const int oh = (t >> 7) * 32;
    const int cg = c0 + (row >> 5);
    const float* gp = grouped + ((size_t)cg * 32 + (row & 31)) * 3;
    const float gx = gp[0], gy = gp[1], gz = gp[2];
    u16 hv[32];
#pragma unroll
    for (int o = 0; o < 32; ++o) {
      const float4 wvv = ((const float4*)w1eff)[oh + o];
      float h = fmaxf(0.f, gx * wvv.x + gy * wvv.y + gz * wvv.z + wvv.w);
      hv[o] = bf16rne(h);
    }
#pragma unroll
    for (int c4 = 0; c4 < 4; ++c4) {
      uint4 pk;
      pk.x = (u32)hv[c4 * 8 + 0] | ((u32)hv[c4 * 8 + 1] << 16);
      pk.y = (u32)hv[c4 * 8 + 2] | ((u32)hv[c4 * 8 + 3] << 16);
      pk.z = (u32)hv[c4 * 8 + 4] | ((u32)hv[c4 * 8 + 5] << 16);
      pk.w = (u32)hv[c4 * 8 + 6] | ((u32)hv[c4 * 8 + 7] << 16);
      int byte = row * 128 + oh * 2 + c4 * 16;
      *reinterpret_cast<uint4*>(lds + 16384 + (byte ^ ((row & 7) << 4))) = pk;
    }
  }
  __syncthreads();
  // GEMM2: H2(32x128) = H1(32x64) @ W2eff^T, per wave
  f32x4 acc2[2][8];
#pragma unroll
  for (int m = 0; m < 2; ++m)
#pragma unroll
    for (int n = 0; n < 8; ++n) acc2[m][n] = (f32x4){0.f, 0.f, 0.f, 0.f};
#pragma unroll
  for (int ks = 0; ks < 2; ++ks) {
    bf16x8 a[2];
#pragma unroll
    for (int m = 0; m < 2; ++m) {
      int row = w * 32 + m * 16 + l15;
      int byte = row * 128 + (ks * 32 + lg * 8) * 2;
      a[m] = *reinterpret_cast<const bf16x8*>(lds + 16384 + (byte ^ ((row & 7) << 4)));
    }
    const int kg = ks * 4 + lg;
#pragma unroll
    for (int n = 0; n < 8; ++n) {
      int idx = (((kg * 128) + (n * 16 + l15)) * 8) ^ ((kg & 7) * 8);
      bf16x8 bb = *reinterpret_cast<const bf16x8*>((const u16*)lds + idx);
      acc2[0][n] = MFMA16(a[0], bb, acc2[0][n]);
      acc2[1][n] = MFMA16(a[1], bb, acc2[1][n]);
    }
  }
#pragma unroll
  for (int n = 0; n < 8; ++n) {  // relu(acc + t2) -> H2 bf16 swizzled
    const int col = n * 16 + l15;
    const float t2v = t2[col];
#pragma unroll
    for (int m = 0; m < 2; ++m)
#pragma unroll
      for (int r = 0; r < 4; ++r) {
        float vv = fmaxf(0.f, acc2[m][n][r] + t2v);
        int row = w * 32 + m * 16 + lg * 4 + r;
        int byte = row * 256 + col * 2;
        *reinterpret_cast<u16*>(lds + 32768 + (byte ^ ((row & 7) << 4))) = bf16rne(vv);
      }
  }
  __syncthreads();
  const float ccx = centers[(c0 + w) * 3 + 0];
  const float ccy = centers[(c0 + w) * 3 + 1];
  const float ccz = centers[(c0 + w) * 3 + 2];
  float* tok = tokens + (size_t)(c0 + w) * 256;
  for (int h = 0; h < 2; ++h) {
    {  // stage W3 col-half (32KB) -> [0,32K); H2 at [32K,64K) untouched
      const u32* s = (const u32*)w3L + h * 8192;
      u32* d = (u32*)lds;
#pragma unroll
      for (int q = 0; q < 32; ++q) d[q * 256 + t] = s[q * 256 + t];
    }
    __syncthreads();
    f32x4 acc3[2][8];
#pragma unroll
    for (int m = 0; m < 2; ++m)
#pragma unroll
      for (int n = 0; n < 8; ++n) acc3[m][n] = (f32x4){0.f, 0.f, 0.f, 0.f};
#pragma unroll
    for (int ks = 0; ks < 4; ++ks) {
      bf16x8 a[2];
#pragma unroll
      for (int m = 0; m < 2; ++m) {
        int row = w * 32 + m * 16 + l15;
        int byte = row * 256 + (ks * 32 + lg * 8) * 2;
        a[m] = *reinterpret_cast<const bf16x8*>(lds + 32768 + (byte ^ ((row & 7) << 4)));
      }
      const int kg = ks * 4 + lg;
#pragma unroll
      for (int n = 0; n < 8; ++n) {
        int idx = (((kg * 128) + (n * 16 + l15)) * 8) ^ ((kg & 7) * 8);
        bf16x8 bb = *reinterpret_cast<const bf16x8*>((const u16*)lds + idx);
        acc3[0][n] = MFMA16(a[0], bb, acc3[0][n]);
        acc3[1][n] = MFMA16(a[1], bb, acc3[1][n]);
      }
    }
#pragma unroll
    for (int n = 0; n < 8; ++n) {  // max over 32 neighbors + b3 + pos
      float vmx = acc3[0][n][0];
#pragma unroll
      for (int m = 0; m < 2; ++m)
#pragma unroll
        for (int r = 0; r < 4; ++r) vmx = fmaxf(vmx, acc3[m][n][r]);
      vmx = fmaxf(vmx, __shfl_xor(vmx, 16, 64));
      vmx = fmaxf(vmx, __shfl_xor(vmx, 32, 64));
      const int col = h * 128 + n * 16 + l15;
      if (lane < 16) {
        float pos = Wp[col * 3 + 0] * ccx + Wp[col * 3 + 1] * ccy +
                    Wp[col * 3 + 2] * ccz + bp[col] + b3[col];
        tok[col] = vmx + pos;
      }
    }
    __syncthreads();
  }
}

// ---------------------------------------------------------------------------
extern "C" void kernel_launch(void* const* d_in, const int* in_sizes, int n_in,
                              void* d_out, int out_size, void* d_ws, size_t ws_size,
                              hipStream_t stream) {
  const float* xyz = (const float*)d_in[0];
  const float* W1 = (const float*)d_in[1];
  const float* b1 = (const float*)d_in[2];
  const float* g1 = (const float*)d_in[3];
  const float* be1 = (const float*)d_in[4];
  const float* m1 = (const float*)d_in[5];
  const float* v1 = (const float*)d_in[6];
  const float* W2 = (const float*)d_in[7];
  const float* b2 = (const float*)d_in[8];
  const float* g2 = (const float*)d_in[9];
  const float* be2 = (const float*)d_in[10];
  const float* m2 = (const float*)d_in[11];
  const float* v2 = (const float*)d_in[12];
  const float* W3 = (const float*)d_in[13];
  const float* b3 = (const float*)d_in[14];
  const float* Wp = (const float*)d_in[15];
  const float* bp = (const float*)d_in[16];

  char* ws = (char*)d_ws;
  // fps scratch ws4 (2MB) overlaps `grouped` (1.5MB): disjoint in time
  // (fps finishes before knn writes grouped). Weight buffers live above 2MB.
  float4* ws4 = (float4*)ws;                        // 8*16384*16B = 2097152 B
  float* grouped = (float*)ws;                      // 4096*32*3 f32 = 1572864 B
  float* w1eff = (float*)(ws + 2097152);            // 64*4 f32     = 1024 B
  u16* w2L = (u16*)(ws + 2098176);                  // 8192 u16     = 16384 B
  float* t2 = (float*)(ws + 2114560);               // 128 f32      = 512 B
  u16* w3L = (u16*)(ws + 2115072);                  // 32768 u16    = 65536 B

  float* centers = (float*)d_out;                   // (8,512,3)
  float* tokens = (float*)d_out + 8 * 512 * 3;      // (8,512,256)

  prep_kernel<<<dim3(128), dim3(256), 0, stream>>>(W1, b1, g1, be1, m1, v1,
                                                   W2, b2, g2, be2, m2, v2, W3,
                                                   w1eff, w2L, t2, w3L);
  fps_kernel<<<dim3(8), dim3(1024), 0, stream>>>(xyz, centers, ws4);
  knn_kernel<<<dim3(512), dim3(512), 0, stream>>>(xyz, centers, grouped);
  mlp_kernel<<<dim3(1024), dim3(256), 0, stream>>>(grouped, w2L, w3L, w1eff, t2,
                                                   b3, Wp, bp, centers, tokens);
}

// Round 13
// 827.141 us; speedup vs baseline: 1.8128x; 1.0066x over previous
//
#include <hip/hip_runtime.h>

typedef unsigned int u32;
typedef unsigned long long u64;
typedef unsigned short u16;

#define DEVFN static __device__ __forceinline__

constexpr int NPTS = 16384;  // points per batch
constexpr int NC = 512;      // centers per batch
// B=8, K=32, FEAT=256

typedef __attribute__((ext_vector_type(8))) short bf16x8;
typedef __attribute__((ext_vector_type(4))) float f32x4;

#define MFMA16(a, b, c) __builtin_amdgcn_mfma_f32_16x16x32_bf16(a, b, c, 0, 0, 0)

DEVFN u16 bf16rne(float f) {
  u32 b = __float_as_uint(f);
  u32 r = (b + 0x7FFFu + ((b >> 16) & 1u)) >> 16;
  return (u16)r;
}

DEVFN u64 shflx64(u64 v, int m) {
  u32 lo = __shfl_xor((u32)v, m, 64);
  u32 hi = __shfl_xor((u32)(v >> 32), m, 64);
  return ((u64)hi << 32) | lo;
}
DEVFN u64 shfl64(u64 v, int src) {
  u32 lo = __shfl((u32)v, src, 64);
  u32 hi = __shfl((u32)(v >> 32), src, 64);
  return ((u64)hi << 32) | lo;
}

DEVFN void csw(u64& a, u64& b) {
  u64 lo = a < b ? a : b;
  u64 hi = a < b ? b : a;
  a = lo; b = hi;
}

DEVFN u32 spread3(u32 v) {  // 4 bits -> bits 0,3,6,9
  return (v & 1u) | ((v & 2u) << 2) | ((v & 4u) << 4) | ((v & 8u) << 6);
}

// All FPS keys are < 2^63 with sign bit 0: positive-f64 ordering == u64
// ordering (high word = positive-f32 md bits -> f64 exponent in [0x000,0x501],
// never NaN/Inf; f64 denormals compare correctly, never flushed on CDNA).
DEVFN u64 maxf64u(u64 a, u64 b) {
  double x = __longlong_as_double((long long)a);
  double y = __longlong_as_double((long long)b);
  return (u64)__double_as_longlong(fmax(x, y));
}
template <int CTRL, int RM>
DEVFN u64 dppmaxf(u64 k) {
  u32 lo = (u32)k, hi = (u32)(k >> 32);
  u32 lo2 = (u32)__builtin_amdgcn_update_dpp((int)lo, (int)lo, CTRL, RM, 0xF, false);
  u32 hi2 = (u32)__builtin_amdgcn_update_dpp((int)hi, (int)hi, CTRL, RM, 0xF, false);
  return maxf64u(k, ((u64)hi2 << 32) | lo2);
}
// full 64-lane max -> lane 63 holds result
DEVFN u64 wavemaxf(u64 k) {
  k = dppmaxf<0x121, 0xF>(k);  // ror1
  k = dppmaxf<0x122, 0xF>(k);  // ror2
  k = dppmaxf<0x124, 0xF>(k);  // ror4
  k = dppmaxf<0x128, 0xF>(k);  // ror8 -> row max
  k = dppmaxf<0x142, 0xA>(k);  // row_bcast15 -> rows 1,3
  k = dppmaxf<0x143, 0xC>(k);  // row_bcast31 -> rows 2,3; lane63 = wave max
  return k;
}

// ---------------------------------------------------------------------------
// FPS v13: issue-diet on the v12 worklist structure. Per iteration:
//   seg1 (waves 0-3 only; 4 distinct SIMDs -> no issue contention):
//     C' = global argmax over ckey[256] for the PREVIOUS iteration's update
//     (redundant x4), center -> cxyzL + global; Phase A prune via ballot +
//     mbcnt + 1 atomicAdd per wave (no same-address serialization).
//     Wave 4 resets the other wcnt slot.  [bar1]
//   seg2 (all 16 waves): read center from cxyzL; Phase B: 1 active cluster
//   per wave-entry, 1 pt/lane, f64-max DPP reduce, winner via lo-compare
//   (lo bits unique), winner lane writes ckey+ccoord.  [bar2]
// Epilogue computes center 511. 2 barriers/iter, Phase C issue cost /4.
// Exactness: key = md_bits<<32 | ((16383-oidx)<<8|cluster); u64 max ==
// numpy argmax (max md, tie -> lowest oidx). Prune = monotone-rounding bbox
// lower bound (skips only provably no-op updates).
// ---------------------------------------------------------------------------
__global__ __launch_bounds__(1024) void fps_kernel(const float* __restrict__ xyz,
                                                   float* __restrict__ centers,
                                                   float4* __restrict__ ws4) {
  const int b = blockIdx.x;
  const int t = threadIdx.x;
  const int lane = t & 63;
  const int w = t >> 6;
  const float* xb = xyz + (size_t)b * NPTS * 3;
  const int bo = b * NPTS;

  __shared__ char smem[78352];
  float* mdL = (float*)smem;                 // [0, 64K)  md per sorted point
  u64* ckeyL = (u64*)(smem + 65536);         // u64[256]
  float* bboxT = (float*)(smem + 67584);     // f32[6][256]
  float* ccoordL = (float*)(smem + 73728);   // f32[256*3] per-cluster argmax coords
  u16* wl = (u16*)(smem + 76800);            // u16[2][256] worklist
  u32* wcnt = (u32*)(smem + 77824);          // u32[2]
  float* redB = (float*)(smem + 77832);      // 104 f32 (setup)
  u32* redW = (u32*)(smem + 78248);          // 16 u32 (setup)
  float* cxyzL = (float*)(smem + 78336);     // f32[3] current center broadcast
  u32* hist = (u32*)smem;                    // setup alias [0, 8K)
  u16* soidx = (u16*)(smem + 8192);          // setup alias [8K, 40K)

  const u32 inf10 = __float_as_uint(1e10f);

  // ---- setup: global bbox + morton codes ----
  u32 mcode[16];
  {
    float ox[16], oy[16], oz[16];
    float lx = 1e30f, ly = 1e30f, lz = 1e30f;
    float hx = -1e30f, hy = -1e30f, hz = -1e30f;
#pragma unroll
    for (int j = 0; j < 16; ++j) {
      int p = t + j * 1024;
      ox[j] = xb[p * 3 + 0];
      oy[j] = xb[p * 3 + 1];
      oz[j] = xb[p * 3 + 2];
      lx = fminf(lx, ox[j]); hx = fmaxf(hx, ox[j]);
      ly = fminf(ly, oy[j]); hy = fmaxf(hy, oy[j]);
      lz = fminf(lz, oz[j]); hz = fmaxf(hz, oz[j]);
    }
#pragma unroll
    for (int s = 32; s; s >>= 1) {
      lx = fminf(lx, __shfl_xor(lx, s, 64)); hx = fmaxf(hx, __shfl_xor(hx, s, 64));
      ly = fminf(ly, __shfl_xor(ly, s, 64)); hy = fmaxf(hy, __shfl_xor(hy, s, 64));
      lz = fminf(lz, __shfl_xor(lz, s, 64)); hz = fmaxf(hz, __shfl_xor(hz, s, 64));
    }
    if (lane == 0) {
      redB[w * 6 + 0] = lx; redB[w * 6 + 1] = hx;
      redB[w * 6 + 2] = ly; redB[w * 6 + 3] = hy;
      redB[w * 6 + 4] = lz; redB[w * 6 + 5] = hz;
    }
    hist[t] = 0; hist[t + 1024] = 0;
    if (t < 2) wcnt[t] = 0;
    __syncthreads();
    if (t == 0) {
      float a0 = redB[0], a1 = redB[1], a2 = redB[2], a3 = redB[3], a4 = redB[4], a5 = redB[5];
      for (int q = 1; q < 16; ++q) {
        a0 = fminf(a0, redB[q * 6 + 0]); a1 = fmaxf(a1, redB[q * 6 + 1]);
        a2 = fminf(a2, redB[q * 6 + 2]); a3 = fmaxf(a3, redB[q * 6 + 3]);
        a4 = fminf(a4, redB[q * 6 + 4]); a5 = fmaxf(a5, redB[q * 6 + 5]);
      }
      redB[96] = a0; redB[97] = a1; redB[98] = a2;
      redB[99] = a3; redB[100] = a4; redB[101] = a5;
    }
    __syncthreads();
    const float glx = redB[96], ghx = redB[97];
    const float gly = redB[98], ghy = redB[99];
    const float glz = redB[100], ghz = redB[101];
    const float sx = 15.999f / fmaxf(ghx - glx, 1e-9f);
    const float sy = 15.999f / fmaxf(ghy - gly, 1e-9f);
    const float sz = 7.999f / fmaxf(ghz - glz, 1e-9f);
#pragma unroll
    for (int j = 0; j < 16; ++j) {
      int ix = min(15, max(0, (int)((ox[j] - glx) * sx)));
      int iy = min(15, max(0, (int)((oy[j] - gly) * sy)));
      int iz = min(7, max(0, (int)((oz[j] - glz) * sz)));
      mcode[j] = spread3((u32)ix) | (spread3((u32)iy) << 1) | (spread3((u32)iz) << 2);
    }
  }
  // ---- histogram (2048 bins) ----
#pragma unroll
  for (int j = 0; j < 16; ++j) atomicAdd(&hist[mcode[j]], 1u);
  __syncthreads();
  // ---- exclusive scan over 2048 bins ----
  {
    u32 h0 = hist[t * 2 + 0], h1 = hist[t * 2 + 1];
    u32 s = h0 + h1;
    u32 incl = s;
#pragma unroll
    for (int d = 1; d < 64; d <<= 1) {
      u32 n = __shfl_up(incl, d, 64);
      if (lane >= d) incl += n;
    }
    if (lane == 63) redW[w] = incl;
    __syncthreads();
    if (t == 0) {
      u32 run = 0;
      for (int q = 0; q < 16; ++q) { u32 tmp = redW[q]; redW[q] = run; run += tmp; }
    }
    __syncthreads();
    u32 exc = incl - s + redW[w];
    hist[t * 2 + 0] = exc;
    hist[t * 2 + 1] = exc + h0;
    __syncthreads();
  }
  // ---- scatter: sorted position -> original index ----
#pragma unroll
  for (int j = 0; j < 16; ++j) {
    u32 p = (u32)(t + j * 1024);
    u32 pos = atomicAdd(&hist[mcode[j]], 1u);
    soidx[pos] = (u16)p;
  }
  __syncthreads();
  // ---- gather: pack float4 {x,y,z,lo}, bbox + ckey + ccoord init ----
  {
    const int c = t >> 2;          // cluster 0..255
    const int q = t & 3;           // quarter
    float bxl = 1e30f, bxh = -1e30f, byl = 1e30f, byh = -1e30f, bzl = 1e30f, bzh = -1e30f;
    u32 lomax = 0;
    float axc = 0.f, ayc = 0.f, azc = 0.f;
#pragma unroll
    for (int j = 0; j < 16; ++j) {
      int sp = c * 64 + q * 16 + j;
      u32 oidx = (u32)soidx[sp];
      float X = xb[oidx * 3 + 0];
      float Y = xb[oidx * 3 + 1];
      float Z = xb[oidx * 3 + 2];
      u32 lo = ((16383u - oidx) << 8) | (u32)c;
      float4 pk; pk.x = X; pk.y = Y; pk.z = Z; pk.w = __uint_as_float(lo);
      ws4[bo + sp] = pk;
      if (lo > lomax) { lomax = lo; axc = X; ayc = Y; azc = Z; }
      bxl = fminf(bxl, X); bxh = fmaxf(bxh, X);
      byl = fminf(byl, Y); byh = fmaxf(byh, Y);
      bzl = fminf(bzl, Z); bzh = fmaxf(bzh, Z);
    }
    u32 gl = lomax;
#pragma unroll
    for (int s = 1; s <= 2; s <<= 1) {
      bxl = fminf(bxl, __shfl_xor(bxl, s, 64)); bxh = fmaxf(bxh, __shfl_xor(bxh, s, 64));
      byl = fminf(byl, __shfl_xor(byl, s, 64)); byh = fmaxf(byh, __shfl_xor(byh, s, 64));
      bzl = fminf(bzl, __shfl_xor(bzl, s, 64)); bzh = fmaxf(bzh, __shfl_xor(bzh, s, 64));
      gl = max(gl, (u32)__shfl_xor(gl, s, 64));
    }
    if (lomax == gl) {  // exactly one of the 4 threads (lo unique)
      ccoordL[c * 3 + 0] = axc; ccoordL[c * 3 + 1] = ayc; ccoordL[c * 3 + 2] = azc;
    }
    if (q == 0) {
      bboxT[0 * 256 + c] = bxl; bboxT[1 * 256 + c] = bxh;
      bboxT[2 * 256 + c] = byl; bboxT[3 * 256 + c] = byh;
      bboxT[4 * 256 + c] = bzl; bboxT[5 * 256 + c] = bzh;
      ckeyL[c] = ((u64)inf10 << 32) | gl;
    }
  }
  __syncthreads();  // gather done; hist/soidx region now dead
  // ---- init md (overwrites setup aliases) ----
#pragma unroll
  for (int j = 0; j < 16; ++j) mdL[t + j * 1024] = 1e10f;

  float cx = xb[0], cy = xb[1], cz = xb[2];
  if (t == 0) {
    centers[(b * NC) * 3 + 0] = cx;
    centers[(b * NC) * 3 + 1] = cy;
    centers[(b * NC) * 3 + 2] = cz;
    cxyzL[0] = cx; cxyzL[1] = cy; cxyzL[2] = cz;
  }

  // ---- main loop: 2 barriers per iteration ----
  for (int i = 1; i < NC; ++i) {
    // seg1 (waves 0-3): C' for previous update + Phase A prune/compact
    if (t < 256) {
      if (i > 1) {  // compute center_{i-1} from ckeyL (post-B state of i-1)
        u64 g0 = ckeyL[lane];
        u64 g1 = ckeyL[lane + 64];
        u64 g2 = ckeyL[lane + 128];
        u64 g3 = ckeyL[lane + 192];
        u64 g = maxf64u(maxf64u(g0, g1), maxf64u(g2, g3));
        g = wavemaxf(g);
        u32 glo = (u32)__builtin_amdgcn_readlane((int)(u32)g, 63);
        u32 widx = glo & 255u;  // winner cluster
        cx = ccoordL[widx * 3 + 0];
        cy = ccoordL[widx * 3 + 1];
        cz = ccoordL[widx * 3 + 2];
        if (t == 0) {
          centers[(b * NC + i - 1) * 3 + 0] = cx;
          centers[(b * NC + i - 1) * 3 + 1] = cy;
          centers[(b * NC + i - 1) * 3 + 2] = cz;
          cxyzL[0] = cx; cxyzL[1] = cy; cxyzL[2] = cz;
        }
      }
      // Phase A: prune cluster t vs center_{i-1}; ballot compaction
      float mdm = __uint_as_float((u32)(ckeyL[t] >> 32));
      float ax = fmaxf(0.f, fmaxf(__fsub_rn(bboxT[0 * 256 + t], cx), __fsub_rn(cx, bboxT[1 * 256 + t])));
      float ay = fmaxf(0.f, fmaxf(__fsub_rn(bboxT[2 * 256 + t], cy), __fsub_rn(cy, bboxT[3 * 256 + t])));
      float az = fmaxf(0.f, fmaxf(__fsub_rn(bboxT[4 * 256 + t], cz), __fsub_rn(cz, bboxT[5 * 256 + t])));
      float dlb = __fadd_rn(__fadd_rn(__fmul_rn(ax, ax), __fmul_rn(ay, ay)), __fmul_rn(az, az));
      bool act = dlb < mdm;
      u64 bal = __ballot(act);
      u32 cnt = (u32)__popcll(bal);
      u32 base = 0;
      if (lane == 0) base = atomicAdd(&wcnt[i & 1], cnt);
      base = (u32)__builtin_amdgcn_readlane((int)base, 0);
      u32 below = __builtin_amdgcn_mbcnt_hi((u32)(bal >> 32),
                  __builtin_amdgcn_mbcnt_lo((u32)bal, 0));
      if (act) wl[(i & 1) * 256 + base + below] = (u16)t;
    } else if (t == 256) {
      wcnt[(i + 1) & 1] = 0u;  // reset the other slot, used 2 barriers later
    }
    __syncthreads();  // bar1: worklist + center broadcast ready
    // seg2 (all 16 waves): Phase B over active clusters
    {
      cx = cxyzL[0]; cy = cxyzL[1]; cz = cxyzL[2];
      const int A = (int)wcnt[i & 1];
      const u16* wlp = wl + (i & 1) * 256;
      for (int e = w; e < A; e += 16) {
        const int c = (int)wlp[e];
        const int sp = c * 64 + lane;
        float4 p = ws4[bo + sp];
        float dx = __fsub_rn(p.x, cx);
        float dy = __fsub_rn(p.y, cy);
        float dz = __fsub_rn(p.z, cz);
        float d = __fadd_rn(__fadd_rn(__fmul_rn(dx, dx), __fmul_rn(dy, dy)), __fmul_rn(dz, dz));
        float nm = fminf(mdL[sp], d);
        mdL[sp] = nm;
        u64 key = ((u64)__float_as_uint(nm) << 32) | (u64)__float_as_uint(p.w);
        u64 r = wavemaxf(key);
        u32 rlo = (u32)__builtin_amdgcn_readlane((int)(u32)r, 63);
        if ((u32)key == rlo) {  // winner lane (lo bits unique per point)
          ckeyL[c] = key;
          ccoordL[c * 3 + 0] = p.x; ccoordL[c * 3 + 1] = p.y; ccoordL[c * 3 + 2] = p.z;
        }
      }
    }
    __syncthreads();  // bar2: md/ckey/ccoord updates visible
  }
  // epilogue: center NC-1 from the final ckey state
  if (w == 0) {
    u64 g0 = ckeyL[lane];
    u64 g1 = ckeyL[lane + 64];
    u64 g2 = ckeyL[lane + 128];
    u64 g3 = ckeyL[lane + 192];
    u64 g = maxf64u(maxf64u(g0, g1), maxf64u(g2, g3));
    g = wavemaxf(g);
    u32 glo = (u32)__builtin_amdgcn_readlane((int)(u32)g, 63);
    u32 widx = glo & 255u;
    if (t == 0) {
      centers[(b * NC + NC - 1) * 3 + 0] = ccoordL[widx * 3 + 0];
      centers[(b * NC + NC - 1) * 3 + 1] = ccoordL[widx * 3 + 1];
      centers[(b * NC + NC - 1) * 3 + 2] = ccoordL[widx * 3 + 2];
    }
  }
}

// ---------------------------------------------------------------------------
// KNN: 8 waves/block, wave = one center. Exact top-32 set by (d, idx).
// ---------------------------------------------------------------------------
__global__ __launch_bounds__(512) void knn_kernel(const float* __restrict__ xyz,
                                                  const float* __restrict__ centers,
                                                  float* __restrict__ grouped) {
  __shared__ float spts[1024 * 3];
  __shared__ u64 cand[8][192];
  __shared__ int ccnt[8];
  const int t = threadIdx.x;
  const int lane = t & 63;
  const int w = t >> 6;
  const int cg = blockIdx.x * 8 + w;   // global center id
  const int b = cg >> 9;               // / 512
  const float* xb = xyz + (size_t)b * NPTS * 3;
  const float cx = centers[cg * 3 + 0];
  const float cy = centers[cg * 3 + 1];
  const float cz = centers[cg * 3 + 2];
  if (lane == 0) ccnt[w] = 0;

  // phase 1: per-lane min (packed (d,idx))
  u64 lmin = ~0ull;
  for (int ch = 0; ch < 16; ++ch) {
    __syncthreads();
    const float* src = xb + ch * 1024 * 3;
#pragma unroll
    for (int q = 0; q < 6; ++q) spts[q * 512 + t] = src[q * 512 + t];
    __syncthreads();
#pragma unroll
    for (int j = 0; j < 16; ++j) {
      int p = lane + j * 64;
      float dx = __fsub_rn(cx, spts[p * 3 + 0]);
      float dy = __fsub_rn(cy, spts[p * 3 + 1]);
      float dz = __fsub_rn(cz, spts[p * 3 + 2]);
      float d = __fadd_rn(__fadd_rn(__fmul_rn(dx, dx), __fmul_rn(dy, dy)), __fmul_rn(dz, dz));
      u64 kk = ((u64)__float_as_uint(d) << 32) | (u64)(u32)(ch * 1024 + p);
      lmin = kk < lmin ? kk : lmin;
    }
  }
  // bitonic sort (ascending) of 64 lane-minima; tau = 32nd smallest
  u64 v = lmin;
  for (int k = 2; k <= 64; k <<= 1)
    for (int j = k >> 1; j > 0; j >>= 1) {
      u64 o = shflx64(v, j);
      bool up = ((lane & k) == 0);
      bool lowr = ((lane & j) == 0);
      u64 mn = v < o ? v : o;
      u64 mx = v < o ? o : v;
      v = (lowr == up) ? mn : mx;
    }
  u64 tau = shfl64(v, 31);
  float tf = __uint_as_float((u32)(tau >> 32));

  // phase 2: collect candidates d <= tf  (guaranteed >= 32 of them)
  for (int ch = 0; ch < 16; ++ch) {
    __syncthreads();
    const float* src = xb + ch * 1024 * 3;
#pragma unroll
    for (int q = 0; q < 6; ++q) spts[q * 512 + t] = src[q * 512 + t];
    __syncthreads();
#pragma unroll
    for (int j = 0; j < 16; ++j) {
      int p = lane + j * 64;
      float dx = __fsub_rn(cx, spts[p * 3 + 0]);
      float dy = __fsub_rn(cy, spts[p * 3 + 1]);
      float dz = __fsub_rn(cz, spts[p * 3 + 2]);
      float d = __fadd_rn(__fadd_rn(__fmul_rn(dx, dx), __fmul_rn(dy, dy)), __fmul_rn(dz, dz));
      if (d <= tf) {
        int pos = atomicAdd(&ccnt[w], 1);
        if (pos < 192) cand[w][pos] = ((u64)__float_as_uint(d) << 32) | (u64)(u32)(ch * 1024 + p);
      }
    }
  }
  __syncthreads();
  int cnt = ccnt[w];
  u32 myn = 0u;  // lane r (<32) keeps r-th nearest neighbor's index
  if (cnt <= 192) {
    u64 c0 = (lane < cnt) ? cand[w][lane] : ~0ull;
    u64 c1 = (64 + lane < cnt) ? cand[w][64 + lane] : ~0ull;
    u64 c2 = (128 + lane < cnt) ? cand[w][128 + lane] : ~0ull;
    csw(c0, c1); csw(c1, c2); csw(c0, c1);  // c0<=c1<=c2
    for (int r = 0; r < 32; ++r) {
      u64 wm = c0;
      for (int s = 32; s; s >>= 1) {
        u64 o = shflx64(wm, s);
        wm = o < wm ? o : wm;
      }
      if (c0 == wm) { c0 = c1; c1 = c2; c2 = ~0ull; }
      if (lane == r) myn = (u32)wm;
    }
  } else {
    // exact slow fallback (astronomically rare): ascending extraction
    u64 last = 0ull;
    for (int r = 0; r < 32; ++r) {
      u64 bb = ~0ull;
      for (int j = 0; j < 256; ++j) {
        int p = lane + j * 64;
        float dx = __fsub_rn(cx, xb[p * 3 + 0]);
        float dy = __fsub_rn(cy, xb[p * 3 + 1]);
        float dz = __fsub_rn(cz, xb[p * 3 + 2]);
        float d = __fadd_rn(__fadd_rn(__fmul_rn(dx, dx), __fmul_rn(dy, dy)), __fmul_rn(dz, dz));
        u64 kk = ((u64)__float_as_uint(d) << 32) | (u64)(u32)p;
        if (r == 0 || kk > last)
          if (kk < bb) bb = kk;
      }
      for (int s = 32; s; s >>= 1) {
        u64 o = shflx64(bb, s);
        bb = o < bb ? o : bb;
      }
      last = bb;
      if (lane == r) myn = (u32)bb;
    }
  }
  if (lane < 32) {
    const float nx = xb[(size_t)myn * 3 + 0];
    const float ny = xb[(size_t)myn * 3 + 1];
    const float nz = xb[(size_t)myn * 3 + 2];
    float* gp = grouped + ((size_t)cg * 32 + lane) * 3;
    gp[0] = __fsub_rn(nx, cx);
    gp[1] = __fsub_rn(ny, cy);
    gp[2] = __fsub_rn(nz, cz);
  }
}

// ---------------------------------------------------------------------------
// Weight prep: fold eval-BN into weights, bf16 + MFMA-fragment-swizzled
// layouts for W2/W3 so the MLP kernel stages LDS with a linear copy.
// ---------------------------------------------------------------------------
__global__ __launch_bounds__(256) void prep_kernel(
    const float* __restrict__ W1, const float* __restrict__ b1,
    const float* __restrict__ g1, const float* __restrict__ be1,
    const float* __restrict__ m1, const float* __restrict__ v1,
    const float* __restrict__ W2, const float* __restrict__ b2,
    const float* __restrict__ g2, const float* __restrict__ be2,
    const float* __restrict__ m2, const float* __restrict__ v2,
    const float* __restrict__ W3,
    float* __restrict__ w1eff, u16* __restrict__ w2L,
    float* __restrict__ t2, u16* __restrict__ w3L) {
  const int tid = blockIdx.x * 256 + threadIdx.x;  // 128 blocks -> 32768
  if (tid < 64) {
    float s = g1[tid] / sqrtf(v1[tid] + 1e-5f);
    w1eff[tid * 4 + 0] = W1[tid * 3 + 0] * s;
    w1eff[tid * 4 + 1] = W1[tid * 3 + 1] * s;
    w1eff[tid * 4 + 2] = W1[tid * 3 + 2] * s;
    w1eff[tid * 4 + 3] = (b1[tid] - m1[tid]) * s + be1[tid];
  }
  if (tid < 128) {
    float s = g2[tid] / sqrtf(v2[tid] + 1e-5f);
    t2[tid] = (b2[tid] - m2[tid]) * s + be2[tid];
  }
  if (tid < 8192) {  // W2eff (128 out x 64 in), bn-scaled, as B-fragments
    int i = tid & 63, o = tid >> 6;
    float s = g2[o] / sqrtf(v2[o] + 1e-5f);
    int kg = i >> 3, j = i & 7;
    w2L[((((kg * 128) + o) * 8) ^ ((kg & 7) * 8)) + j] = bf16rne(W2[o * 64 + i] * s);
  }
  if (tid < 32768) {  // W3 (256 out x 128 in) as B-fragments, split in col-halves
    int i = tid & 127, o = tid >> 7;
    int kg = i >> 3, j = i & 7;
    int h = o >> 7, colh = o & 127;
    w3L[h * 16384 + ((((kg * 128) + colh) * 8) ^ ((kg & 7) * 8)) + j] = bf16rne(W3[o * 128 + i]);
  }
}

// ---------------------------------------------------------------------------
// MLP: 4 centers (128 rows) per 256-thread block; wave = one center.
// L1 on VALU (K=3), L2/L3 as bf16 MFMA GEMMs; fused max-pool + pos epilogue.
// LDS (64KB): [0,16K)=W2 (later W3 half over [0,32K)); [16K,32K)=H1; [32K,64K)=H2.
// ---------------------------------------------------------------------------
__global__ __launch_bounds__(256) void mlp_kernel(
    const float* __restrict__ grouped, const u16* __restrict__ w2L,
    const u16* __restrict__ w3L, const float* __restrict__ w1eff,
    const float* __restrict__ t2, const float* __restrict__ b3,
    const float* __restrict__ Wp, const float* __restrict__ bp,
    const float* __restrict__ centers, float* __restrict__ tokens) {
  __shared__ char lds[65536];
  const int t = threadIdx.x;
  const int lane = t & 63;
  const int w = t >> 6;
  const int l15 = lane & 15;
  const int lg = lane >> 4;
  const int c0 = blockIdx.x * 4;
  {  // stage W2 -> [0,16K)
    const u32* s = (const u32*)w2L;
    u32* d = (u32*)lds;
#pragma unroll
    for (int q = 0; q < 16; ++q) d[q * 256 + t] = s[q * 256 + t];
  }
  {  // H1 = relu(X @ W1eff^T + b1eff), bf16, swizzled -> [16K,32K)
    const int row = t & 127;
    const int oh = (t >> 7) * 32;
    const int cg = c0 + (row >> 5);
    const float* gp = grouped + ((size_t)cg * 32 + (row & 31)) * 3;
    const float gx = gp[0], gy = gp[1], gz = gp[2];
    u16 hv[32];
#pragma unroll
    for (int o = 0; o < 32; ++o) {
      const float4 wvv = ((const float4*)w1eff)[oh + o];
      float h = fmaxf(0.f, gx * wvv.x + gy * wvv.y + gz * wvv.z + wvv.w);
      hv[o] = bf16rne(h);
    }
#pragma unroll
    for (int c4 = 0; c4 < 4; ++c4) {
      uint4 pk;
      pk.x = (u32)hv[c4 * 8 + 0] | ((u32)hv[c4 * 8 + 1] << 16);
      pk.y = (u32)hv[c4 * 8 + 2] | ((u32)hv[c4 * 8 + 3] << 16);
      pk.z = (u32)hv[c4 * 8 + 4] | ((u32)hv[c4 * 8 + 5] << 16);
      pk.w = (u32)hv[c4 * 8 + 6] | ((u32)hv[c4 * 8 + 7] << 16);
      int byte = row * 128 + oh * 2 + c4 * 16;
      *reinterpret_cast<uint4*>(lds + 16384 + (byte ^ ((row & 7) << 4))) = pk;
    }
  }
  __syncthreads();
  // GEMM2: H2(32x128) = H1(32x64) @ W2eff^T, per wave
  f32x4 acc2[2][8];
#pragma unroll
  for (int m = 0; m < 2; ++m)
#pragma unroll
    for (int n = 0; n < 8; ++n) acc2[m][n] = (f32x4){0.f, 0.f, 0.f, 0.f};
#pragma unroll
  for (int ks = 0; ks < 2; ++ks) {
    bf16x8 a[2];
#pragma unroll
    for (int m = 0; m < 2; ++m) {
      int row = w * 32 + m * 16 + l15;
      int byte = row * 128 + (ks * 32 + lg * 8) * 2;
      a[m] = *reinterpret_cast<const bf16x8*>(lds + 16384 + (byte ^ ((row & 7) << 4)));
    }
    const int kg = ks * 4 + lg;
#pragma unroll
    for (int n = 0; n < 8; ++n) {
      int idx = (((kg * 128) + (n * 16 + l15)) * 8) ^ ((kg & 7) * 8);
      bf16x8 bb = *reinterpret_cast<const bf16x8*>((const u16*)lds + idx);
      acc2[0][n] = MFMA16(a[0], bb, acc2[0][n]);
      acc2[1][n] = MFMA16(a[1], bb, acc2[1][n]);
    }
  }
#pragma unroll
  for (int n = 0; n < 8; ++n) {  // relu(acc + t2) -> H2 bf16 swizzled
    const int col = n * 16 + l15;
    const float t2v = t2[col];
#pragma unroll
    for (int m = 0; m < 2; ++m)
#pragma unroll
      for (int r = 0; r < 4; ++r) {
        float vv = fmaxf(0.f, acc2[m][n][r] + t2v);
        int row = w * 32 + m * 16 + lg * 4 + r;
        int byte = row * 256 + col * 2;
        *reinterpret_cast<u16*>(lds + 32768 + (byte ^ ((row & 7) << 4))) = bf16rne(vv);
      }
  }
  __syncthreads();
  const float ccx = centers[(c0 + w) * 3 + 0];
  const float ccy = centers[(c0 + w) * 3 + 1];
  const float ccz = centers[(c0 + w) * 3 + 2];
  float* tok = tokens + (size_t)(c0 + w) * 256;
  for (int h = 0; h < 2; ++h) {
    {  // stage W3 col-half (32KB) -> [0,32K); H2 at [32K,64K) untouched
      const u32* s = (const u32*)w3L + h * 8192;
      u32* d = (u32*)lds;
#pragma unroll
      for (int q = 0; q < 32; ++q) d[q * 256 + t] = s[q * 256 + t];
    }
    __syncthreads();
    f32x4 acc3[2][8];
#pragma unroll
    for (int m = 0; m < 2; ++m)
#pragma unroll
      for (int n = 0; n < 8; ++n) acc3[m][n] = (f32x4){0.f, 0.f, 0.f, 0.f};
#pragma unroll
    for (int ks = 0; ks < 4; ++ks) {
      bf16x8 a[2];
#pragma unroll
      for (int m = 0; m < 2; ++m) {
        int row = w * 32 + m * 16 + l15;
        int byte = row * 256 + (ks * 32 + lg * 8) * 2;
        a[m] = *reinterpret_cast<const bf16x8*>(lds + 32768 + (byte ^ ((row & 7) << 4)));
      }
      const int kg = ks * 4 + lg;
#pragma unroll
      for (int n = 0; n < 8; ++n) {
        int idx = (((kg * 128) + (n * 16 + l15)) * 8) ^ ((kg & 7) * 8);
        bf16x8 bb = *reinterpret_cast<const bf16x8*>((const u16*)lds + idx);
        acc3[0][n] = MFMA16(a[0], bb, acc3[0][n]);
        acc3[1][n] = MFMA16(a[1], bb, acc3[1][n]);
      }
    }
#pragma unroll
    for (int n = 0; n < 8; ++n) {  // max over 32 neighbors + b3 + pos
      float vmx = acc3[0][n][0];
#pragma unroll
      for (int m = 0; m < 2; ++m)
#pragma unroll
        for (int r = 0; r < 4; ++r) vmx = fmaxf(vmx, acc3[m][n][r]);
      vmx = fmaxf(vmx, __shfl_xor(vmx, 16, 64));
      vmx = fmaxf(vmx, __shfl_xor(vmx, 32, 64));
      const int col = h * 128 + n * 16 + l15;
      if (lane < 16) {
        float pos = Wp[col * 3 + 0] * ccx + Wp[col * 3 + 1] * ccy +
                    Wp[col * 3 + 2] * ccz + bp[col] + b3[col];
        tok[col] = vmx + pos;
      }
    }
    __syncthreads();
  }
}

// ---------------------------------------------------------------------------
extern "C" void kernel_launch(void* const* d_in, const int* in_sizes, int n_in,
                              void* d_out, int out_size, void* d_ws, size_t ws_size,
                              hipStream_t stream) {
  const float* xyz = (const float*)d_in[0];
  const float* W1 = (const float*)d_in[1];
  const float* b1 = (const float*)d_in[2];
  const float* g1 = (const float*)d_in[3];
  const float* be1 = (const float*)d_in[4];
  const float* m1 = (const float*)d_in[5];
  const float* v1 = (const float*)d_in[6];
  const float* W2 = (const float*)d_in[7];
  const float* b2 = (const float*)d_in[8];
  const float* g2 = (const float*)d_in[9];
  const float* be2 = (const float*)d_in[10];
  const float* m2 = (const float*)d_in[11];
  const float* v2 = (const float*)d_in[12];
  const float* W3 = (const float*)d_in[13];
  const float* b3 = (const float*)d_in[14];
  const float* Wp = (const float*)d_in[15];
  const float* bp = (const float*)d_in[16];

  char* ws = (char*)d_ws;
  // fps scratch ws4 (2MB) overlaps `grouped` (1.5MB): disjoint in time
  // (fps finishes before knn writes grouped). Weight buffers live above 2MB.
  float4* ws4 = (float4*)ws;                        // 8*16384*16B = 2097152 B
  float* grouped = (float*)ws;                      // 4096*32*3 f32 = 1572864 B
  float* w1eff = (float*)(ws + 2097152);            // 64*4 f32     = 1024 B
  u16* w2L = (u16*)(ws + 2098176);                  // 8192 u16     = 16384 B
  float* t2 = (float*)(ws + 2114560);               // 128 f32      = 512 B
  u16* w3L = (u16*)(ws + 2115072);                  // 32768 u16    = 65536 B

  float* centers = (float*)d_out;                   // (8,512,3)
  float* tokens = (float*)d_out + 8 * 512 * 3;      // (8,512,256)

  prep_kernel<<<dim3(128), dim3(256), 0, stream>>>(W1, b1, g1, be1, m1, v1,
                                                   W2, b2, g2, be2, m2, v2, W3,
                                                   w1eff, w2L, t2, w3L);
  fps_kernel<<<dim3(8), dim3(1024), 0, stream>>>(xyz, centers, ws4);
  knn_kernel<<<dim3(512), dim3(512), 0, stream>>>(xyz, centers, grouped);
  mlp_kernel<<<dim3(1024), dim3(256), 0, stream>>>(grouped, w2L, w3L, w1eff, t2,
                                                   b3, Wp, bp, centers, tokens);
}